// Round 5
// baseline (2122.367 us; speedup 1.0000x reference)
//
#include <hip/hip_runtime.h>
#include <math.h>

// ---------------- problem constants ----------------
constexpr int NL  = 4096;   // B*N tokens
constexpr int HH  = 256;    // hidden
constexpr int NE  = 8192;   // edges per batch
constexpr int DIc = 512;    // mamba inner
constexpr int DSc = 8;      // mamba state
constexpr int NCH = 64;     // scan chunks
constexpr int CLc = 64;     // chunk length
constexpr int NOUT = 12416; // 8 * (1+4+3+512+512+512+8)

// ---------------- workspace layout (floats) ----------------
constexpr size_t O_H0    = 0;          // 1048576
constexpr size_t O_H1    = 1048576;    // 1048576
constexpr size_t O_H2    = 2097152;    // 1048576
constexpr size_t O_MBUF  = 3145728;    // 1048576
constexpr size_t O_XZ    = 4194304;    // 4194304
constexpr size_t O_XC2   = 8388608;    // 2097152
constexpr size_t O_DELTA = 10485760;   // 2097152
constexpr size_t O_PROJ  = 12582912;   // 131072
constexpr size_t O_P     = 12713984;   // 262144
constexpr size_t O_HL    = 12976128;   // 262144
constexpr size_t O_HST   = 13238272;   // 262144
constexpr size_t O_CAT   = 13500416;   // 3145728
constexpr size_t O_POOL  = 16646144;   // 2048
constexpr size_t O_DINV  = 16648192;   // 4096
constexpr size_t O_INT   = 16652288;   // int region from here

// ---------------- graph prep ----------------
__global__ void zero_k(int* __restrict__ p) {
    p[blockIdx.x*256 + threadIdx.x] = 0;
}

__global__ void count_k(const int* __restrict__ ei, int* __restrict__ indeg) {
    int i = blockIdx.x*256 + threadIdx.x;       // 0..65535
    int b = i >> 13, e = i & 8191;
    int dst = ei[b*2*NE + NE + e] + (b << 9);
    atomicAdd(&indeg[dst], 1);
}

__global__ __launch_bounds__(1024) void prefix_k(const int* __restrict__ indeg,
                                                 int* __restrict__ row_start,
                                                 int* __restrict__ cursor) {
    __shared__ int part[1024];
    int t = threadIdx.x;
    int v0[4]; int s = 0;
    #pragma unroll
    for (int i = 0; i < 4; i++) { v0[i] = s; s += indeg[t*4 + i]; }
    part[t] = s;
    __syncthreads();
    for (int o = 1; o < 1024; o <<= 1) {
        int x = (t >= o) ? part[t-o] : 0;
        __syncthreads();
        part[t] += x;
        __syncthreads();
    }
    int base = (t > 0) ? part[t-1] : 0;
    #pragma unroll
    for (int i = 0; i < 4; i++) {
        int rs = base + v0[i];
        row_start[t*4+i] = rs; cursor[t*4+i] = rs;
    }
    if (t == 1023) row_start[4096] = part[1023];
}

__global__ void scatter_k(const int* __restrict__ ei, int* __restrict__ cursor,
                          int* __restrict__ csr) {
    int i = blockIdx.x*256 + threadIdx.x;
    int b = i >> 13, e = i & 8191;
    int src = ei[b*2*NE + e]       + (b << 9);
    int dst = ei[b*2*NE + NE + e]  + (b << 9);
    int pos = atomicAdd(&cursor[dst], 1);
    csr[pos] = src;
}

__global__ void dinv_k(const int* __restrict__ indeg, float* __restrict__ dinv) {
    int i = blockIdx.x*256 + threadIdx.x;
    dinv[i] = rsqrtf(1.0f + (float)indeg[i]);   // deg = in-edges + self loop
}

// gather: out[n,c] = relu( m[n,c]*dinv[n]^2 + sum_in m[s,c]*dinv[s]*dinv[n] + bias[c] )
__global__ __launch_bounds__(256) void gather_k(const float* __restrict__ m,
                        const int* __restrict__ csr, const int* __restrict__ row_start,
                        const float* __restrict__ dinv, const float* __restrict__ bias,
                        float* __restrict__ out) {
    int n = blockIdx.x, c = threadIdx.x;
    float dn = dinv[n];
    float acc = m[(size_t)n*HH + c] * dn * dn;
    int e0 = row_start[n], e1 = row_start[n+1];
    for (int e = e0; e < e1; e++) {
        int s = csr[e];
        acc += m[(size_t)s*HH + c] * (dinv[s] * dn);
    }
    out[(size_t)n*HH + c] = fmaxf(acc + bias[c], 0.0f);
}

// ---------------- generic fp32 GEMM ----------------
// C[M,N](ldc) = act(A[M,K](lda) @ W[K,N] + bias) + resid
template<int ACT, int CT>
__global__ __launch_bounds__(256) void gemm_k(const float* __restrict__ A, int lda,
                       const float* __restrict__ W, const float* __restrict__ bias,
                       float* __restrict__ C, int ldc,
                       const float* __restrict__ resid, int ldr,
                       int M, int K, int N)
{
    constexpr int CG  = CT / 4;
    constexpr int RPT = CG / 8;
    __shared__ __align__(16) float As[32][64];
    int t = threadIdx.x;
    int cl = t % CG;
    int rg = t / CG;
    int row0 = blockIdx.x * 32;
    int colbase = blockIdx.y * CT + cl;
    float acc[RPT][4];
    #pragma unroll
    for (int i = 0; i < RPT; i++)
        #pragma unroll
        for (int j = 0; j < 4; j++) acc[i][j] = 0.0f;

    for (int k0 = 0; k0 < K; k0 += 64) {
        int kt = K - k0; if (kt > 64) kt = 64;
        __syncthreads();
        #pragma unroll
        for (int i = 0; i < 8; i++) {
            int idx = t + i*256;
            int r = idx >> 6, kk = idx & 63;
            As[r][kk] = (kk < kt) ? A[(size_t)(row0+r)*lda + k0 + kk] : 0.0f;
        }
        __syncthreads();
        for (int k = 0; k < kt; k += 4) {
            float wv[4][4];
            #pragma unroll
            for (int kk2 = 0; kk2 < 4; kk2++) {
                int kr = k0 + k + kk2;
                bool kok = (k + kk2) < kt;
                if (!kok) kr = K - 1;
                #pragma unroll
                for (int j = 0; j < 4; j++) {
                    int col = colbase + j*CG;
                    if (col >= N) col = N - 1;
                    float w = W[(size_t)kr*N + col];
                    wv[kk2][j] = kok ? w : 0.0f;
                }
            }
            #pragma unroll
            for (int i = 0; i < RPT; i++) {
                float4 a4 = *(const float4*)&As[rg*RPT + i][k];
                float av[4] = {a4.x, a4.y, a4.z, a4.w};
                #pragma unroll
                for (int kk2 = 0; kk2 < 4; kk2++)
                    #pragma unroll
                    for (int j = 0; j < 4; j++)
                        acc[i][j] = fmaf(av[kk2], wv[kk2][j], acc[i][j]);
            }
        }
    }
    #pragma unroll
    for (int j = 0; j < 4; j++) {
        int col = colbase + j*CG;
        if (col >= N) continue;
        float bv = bias ? bias[col] : 0.0f;
        #pragma unroll
        for (int i = 0; i < RPT; i++) {
            int r = row0 + rg*RPT + i;
            float v = acc[i][j] + bv;
            if (ACT == 1) v = fmaxf(v, 0.0f);
            if (ACT == 2) v = (v > 20.0f) ? v : log1pf(expf(v));   // softplus
            if (resid) v += resid[(size_t)r*ldr + col];
            C[(size_t)r*ldc + col] = v;
        }
    }
}

// ---------------- mamba: conv + silu ----------------
__global__ void conv_k(const float* __restrict__ xz, const float* __restrict__ cW,
                       const float* __restrict__ cb, float* __restrict__ xc2) {
    int i = blockIdx.x*256 + threadIdx.x;  // NL*512
    int l = i >> 9, d = i & 511;
    float acc = cb[d];
    #pragma unroll
    for (int k = 0; k < 4; k++) {
        int ls = l - 3 + k;
        if (ls >= 0) acc += xz[(size_t)ls*1024 + d] * cW[d*4 + k];
    }
    xc2[i] = acc / (1.0f + __expf(-acc));   // silu
}

// ---------------- mamba chunked scan ----------------
__global__ __launch_bounds__(256) void scan1_k(const float* __restrict__ delta,
                        const float* __restrict__ xc, const float* __restrict__ proj,
                        const float* __restrict__ Alog,
                        float* __restrict__ P, float* __restrict__ Hl)
{
    int c = blockIdx.x >> 1;
    int d = ((blockIdx.x & 1) << 8) + threadIdx.x;
    float Ac[DSc], pr[DSc], h[DSc];
    #pragma unroll
    for (int s2 = 0; s2 < DSc; s2++) { Ac[s2] = -__expf(Alog[d*DSc+s2]); pr[s2]=1.0f; h[s2]=0.0f; }
    int l0 = c << 6;
    for (int l = l0; l < l0 + CLc; l++) {
        float dl = delta[(size_t)l*DIc + d];
        float dx = dl * xc[(size_t)l*DIc + d];
        const float* pb = proj + l*32 + 16;   // Bm
        #pragma unroll
        for (int s2 = 0; s2 < DSc; s2++) {
            float a = __expf(dl * Ac[s2]);
            h[s2] = a*h[s2] + dx*pb[s2];
            pr[s2] *= a;
        }
    }
    #pragma unroll
    for (int s2 = 0; s2 < DSc; s2++) {
        P [(size_t)(c*DSc+s2)*DIc + d] = pr[s2];
        Hl[(size_t)(c*DSc+s2)*DIc + d] = h[s2];
    }
}

__global__ void scan2_k(const float* __restrict__ P, const float* __restrict__ Hl,
                        float* __restrict__ Hst) {
    int tg = blockIdx.x*256 + threadIdx.x;   // s*512+d
    float hcur = 0.0f;
    for (int c = 0; c < NCH; c++) {
        size_t off = (size_t)c*4096 + tg;
        Hst[off] = hcur;
        hcur = Hl[off] + P[off]*hcur;
    }
}

// rescan with carry-in; fuse y = (y + Dp*xc)*silu(zg), write into xz cols 0..511
__global__ __launch_bounds__(256) void scan3_k(const float* __restrict__ delta,
                        const float* __restrict__ xc, const float* __restrict__ proj,
                        const float* __restrict__ Alog, const float* __restrict__ Hst,
                        const float* __restrict__ Dp, float* __restrict__ xzy)
{
    int c = blockIdx.x >> 1;
    int d = ((blockIdx.x & 1) << 8) + threadIdx.x;
    float Ac[DSc], h[DSc];
    #pragma unroll
    for (int s2 = 0; s2 < DSc; s2++) {
        Ac[s2] = -__expf(Alog[d*DSc+s2]);
        h[s2]  = Hst[(size_t)(c*DSc+s2)*DIc + d];
    }
    float dpv = Dp[d];
    int l0 = c << 6;
    for (int l = l0; l < l0 + CLc; l++) {
        float dl = delta[(size_t)l*DIc + d];
        float xv = xc[(size_t)l*DIc + d];
        float dx = dl * xv;
        const float* pb = proj + l*32 + 16;
        float y = 0.0f;
        #pragma unroll
        for (int s2 = 0; s2 < DSc; s2++) {
            float a = __expf(dl * Ac[s2]);
            h[s2] = a*h[s2] + dx*pb[s2];
            y += h[s2] * pb[8+s2];            // Cm
        }
        float z = xzy[(size_t)l*1024 + 512 + d];
        float sz = z / (1.0f + __expf(-z));
        xzy[(size_t)l*1024 + d] = (y + dpv*xv) * sz;
    }
}

// ---------------- flash attention fp32 (TQ=32, TK=64, hd=64) ----------------
__global__ __launch_bounds__(256) void attn_k(const float* __restrict__ gq,
                       const float* __restrict__ gk, const float* __restrict__ gv,
                       float* __restrict__ go)
{
    __shared__ __align__(16) float Qs[32][68];
    __shared__ __align__(16) float Ks[64][68];
    __shared__ __align__(16) float Vs[64][68];
    __shared__ __align__(16) float Ss[32][68];
    __shared__ float mrow[32], lrow[32], arow[32];
    int t = threadIdx.x;
    int h = blockIdx.y;
    int q0 = blockIdx.x * 32;
    #pragma unroll
    for (int i = 0; i < 2; i++) {
        int idx = t + i*256;
        int r = idx >> 4, d4 = (idx & 15)*4;
        *(float4*)&Qs[r][d4] = *(const float4*)&gq[(size_t)(q0+r)*HH + h*64 + d4];
    }
    if (t < 32) { mrow[t] = -1e30f; lrow[t] = 0.0f; }
    int r0 = (t >> 5) * 4;
    int tk = t & 31;
    int d0 = (t & 31) * 2;
    float oacc[4][2] = {};

    for (int kt_ = 0; kt_ < NL; kt_ += 64) {
        __syncthreads();
        #pragma unroll
        for (int i = 0; i < 4; i++) {
            int idx = t + i*256;
            int r = idx >> 4, d4 = (idx & 15)*4;
            *(float4*)&Ks[r][d4] = *(const float4*)&gk[(size_t)(kt_+r)*HH + h*64 + d4];
            *(float4*)&Vs[r][d4] = *(const float4*)&gv[(size_t)(kt_+r)*HH + h*64 + d4];
        }
        __syncthreads();
        float s[4][2] = {};
        #pragma unroll
        for (int dc = 0; dc < 64; dc += 4) {
            float4 k0v = *(const float4*)&Ks[tk][dc];
            float4 k1v = *(const float4*)&Ks[tk+32][dc];
            #pragma unroll
            for (int i = 0; i < 4; i++) {
                float4 qv = *(const float4*)&Qs[r0+i][dc];
                s[i][0] += qv.x*k0v.x + qv.y*k0v.y + qv.z*k0v.z + qv.w*k0v.w;
                s[i][1] += qv.x*k1v.x + qv.y*k1v.y + qv.z*k1v.z + qv.w*k1v.w;
            }
        }
        #pragma unroll
        for (int i = 0; i < 4; i++) {
            Ss[r0+i][tk]    = s[i][0] * 0.125f;
            Ss[r0+i][tk+32] = s[i][1] * 0.125f;
        }
        __syncthreads();
        if (t < 32) {
            float m_old = mrow[t];
            float mx = m_old;
            #pragma unroll 8
            for (int k = 0; k < 64; k++) mx = fmaxf(mx, Ss[t][k]);
            float alpha = __expf(m_old - mx);
            float sum = 0.0f;
            #pragma unroll 8
            for (int k = 0; k < 64; k++) {
                float p = __expf(Ss[t][k] - mx);
                Ss[t][k] = p;
                sum += p;
            }
            lrow[t] = lrow[t]*alpha + sum;
            mrow[t] = mx;
            arow[t] = alpha;
        }
        __syncthreads();
        #pragma unroll
        for (int i = 0; i < 4; i++) {
            float al = arow[r0+i];
            oacc[i][0] *= al; oacc[i][1] *= al;
        }
        #pragma unroll
        for (int kk = 0; kk < 64; kk += 4) {
            float pa[4][4];
            #pragma unroll
            for (int i = 0; i < 4; i++) {
                float4 pv = *(const float4*)&Ss[r0+i][kk];
                pa[i][0]=pv.x; pa[i][1]=pv.y; pa[i][2]=pv.z; pa[i][3]=pv.w;
            }
            #pragma unroll
            for (int m2 = 0; m2 < 4; m2++) {
                float v0 = Vs[kk+m2][d0];
                float v1 = Vs[kk+m2][d0+1];
                #pragma unroll
                for (int i = 0; i < 4; i++) {
                    oacc[i][0] = fmaf(pa[i][m2], v0, oacc[i][0]);
                    oacc[i][1] = fmaf(pa[i][m2], v1, oacc[i][1]);
                }
            }
        }
    }
    #pragma unroll
    for (int i = 0; i < 4; i++) {
        float invl = 1.0f / lrow[r0+i];
        size_t base = (size_t)(q0+r0+i)*HH + h*64;
        go[base + d0]     = oacc[i][0] * invl;
        go[base + d0 + 1] = oacc[i][1] * invl;
    }
}

// ---------------- pack h into cat cols 0..255 ----------------
__global__ void pack_k(const float* __restrict__ h2, float* __restrict__ cat) {
    int i = blockIdx.x*256 + threadIdx.x;
    int r = i >> 8, c = i & 255;
    cat[(size_t)r*768 + c] = h2[i];
}

// ---------------- layernorm ----------------
__global__ __launch_bounds__(256) void ln_k(const float* __restrict__ X,
                    const float* __restrict__ g, const float* __restrict__ b,
                    float* __restrict__ Y) {
    __shared__ float red[4];
    int r = blockIdx.x, t = threadIdx.x;
    float v = X[(size_t)r*HH + t];
    float s = v;
    #pragma unroll
    for (int o = 32; o > 0; o >>= 1) s += __shfl_down(s, o);
    if ((t & 63) == 0) red[t >> 6] = s;
    __syncthreads();
    float mean = (red[0]+red[1]+red[2]+red[3]) * (1.0f/256.0f);
    float dfv = v - mean;
    float s2 = dfv*dfv;
    #pragma unroll
    for (int o = 32; o > 0; o >>= 1) s2 += __shfl_down(s2, o);
    __syncthreads();
    if ((t & 63) == 0) red[t >> 6] = s2;
    __syncthreads();
    float var = (red[0]+red[1]+red[2]+red[3]) * (1.0f/256.0f);
    Y[(size_t)r*HH + t] = dfv * rsqrtf(var + 1e-5f) * g[t] + b[t];
}

// ---------------- pool (segment mean per batch) ----------------
__global__ void pool_k(const float* __restrict__ hf, float* __restrict__ pooled) {
    int b = blockIdx.x, t = threadIdx.x;
    float s = 0.0f;
    #pragma unroll 8
    for (int i = 0; i < 512; i++) s += hf[(size_t)((b<<9)+i)*HH + t];
    pooled[b*HH + t] = s * (1.0f/512.0f);
}

// ---------------- heads: out (8, 1552) = concat of 7 linear heads ----------------
// widths: cw 1 | hw 4 | tw 3 | p1w 512 | p2w 512 | dw 512 | sw 8   (all (256, nc))
__global__ __launch_bounds__(256) void heads_k(const float* __restrict__ pooled,
        const float* cw, const float* cbh, const float* hw, const float* hb,
        const float* tw, const float* tb, const float* p1w, const float* p1b,
        const float* p2w, const float* p2b, const float* dw, const float* db,
        const float* sw, const float* sb, float* __restrict__ out)
{
    int idx = blockIdx.x*256 + threadIdx.x;
    if (idx >= NOUT) return;
    int b = idx / 1552, j = idx - b*1552;
    const float* w; const float* bi; int col, nc;
    if (j < 1)         { w = cw;  bi = cbh; col = j;        nc = 1;   }
    else if (j < 5)    { w = hw;  bi = hb;  col = j - 1;    nc = 4;   }
    else if (j < 8)    { w = tw;  bi = tb;  col = j - 5;    nc = 3;   }
    else if (j < 520)  { w = p1w; bi = p1b; col = j - 8;    nc = 512; }
    else if (j < 1032) { w = p2w; bi = p2b; col = j - 520;  nc = 512; }
    else if (j < 1544) { w = dw;  bi = db;  col = j - 1032; nc = 512; }
    else               { w = sw;  bi = sb;  col = j - 1544; nc = 8;   }
    float s = bi[col];
    const float* pl = pooled + b*HH;
    #pragma unroll 4
    for (int k = 0; k < 256; k++) s = fmaf(pl[k], w[k*nc + col], s);
    out[idx] = s;
}

// ---------------- launcher ----------------
extern "C" void kernel_launch(void* const* d_in, const int* in_sizes, int n_in,
                              void* d_out, int out_size, void* d_ws, size_t ws_size,
                              hipStream_t stream)
{
    (void)in_sizes; (void)n_in; (void)out_size; (void)ws_size;
    const float* x      = (const float*)d_in[0];
    const int*   ei     = (const int*)  d_in[1];
    const float* W_init = (const float*)d_in[2];
    const float* b_init = (const float*)d_in[3];
    const float* g1W = (const float*)d_in[4];
    const float* g1b = (const float*)d_in[5];
    const float* g2W = (const float*)d_in[6];
    const float* g2b = (const float*)d_in[7];
    const float* inW = (const float*)d_in[8];
    const float* cW  = (const float*)d_in[9];
    const float* cb  = (const float*)d_in[10];
    const float* xpW = (const float*)d_in[11];
    const float* dtW = (const float*)d_in[12];
    const float* dtb = (const float*)d_in[13];
    const float* Alog= (const float*)d_in[14];
    const float* Dp  = (const float*)d_in[15];
    const float* outW= (const float*)d_in[16];
    const float* Wq  = (const float*)d_in[17];
    const float* bq  = (const float*)d_in[18];
    const float* Wk  = (const float*)d_in[19];
    const float* bk  = (const float*)d_in[20];
    const float* Wv  = (const float*)d_in[21];
    const float* bv  = (const float*)d_in[22];
    const float* Wo  = (const float*)d_in[23];
    const float* bo  = (const float*)d_in[24];
    const float* fusW= (const float*)d_in[25];
    const float* fusb= (const float*)d_in[26];
    const float* lng = (const float*)d_in[27];
    const float* lnb = (const float*)d_in[28];
    const float* cwp = (const float*)d_in[29];
    const float* cbp = (const float*)d_in[30];
    const float* hwp = (const float*)d_in[31];
    const float* hbp = (const float*)d_in[32];
    const float* twp = (const float*)d_in[33];
    const float* tbp = (const float*)d_in[34];
    const float* p1w = (const float*)d_in[35];
    const float* p1b = (const float*)d_in[36];
    const float* p2w = (const float*)d_in[37];
    const float* p2b = (const float*)d_in[38];
    const float* dwp = (const float*)d_in[39];
    const float* dbp = (const float*)d_in[40];
    const float* swp = (const float*)d_in[41];
    const float* sbp = (const float*)d_in[42];

    float* fw = (float*)d_ws;
    int* iw = (int*)(fw + O_INT);
    int* indeg = iw;
    int* row_start = iw + 4096;
    int* cursor = iw + 8193;
    int* csr = iw + 12289;
    float* dinv = fw + O_DINV;

    // graph prep
    zero_k<<<16,256,0,stream>>>(indeg);
    count_k<<<256,256,0,stream>>>(ei, indeg);
    prefix_k<<<1,1024,0,stream>>>(indeg, row_start, cursor);
    scatter_k<<<256,256,0,stream>>>(ei, cursor, csr);
    dinv_k<<<16,256,0,stream>>>(indeg, dinv);

    // h0 = relu(x @ W_init + b)
    gemm_k<1,128><<<dim3(128,2),256,0,stream>>>(x,32, W_init,b_init, fw+O_H0,256, nullptr,0, NL,32,256);
    // gcn1
    gemm_k<0,128><<<dim3(128,2),256,0,stream>>>(fw+O_H0,256, g1W,nullptr, fw+O_MBUF,256, nullptr,0, NL,256,256);
    gather_k<<<4096,256,0,stream>>>(fw+O_MBUF, csr, row_start, dinv, g1b, fw+O_H1);
    // gcn2
    gemm_k<0,128><<<dim3(128,2),256,0,stream>>>(fw+O_H1,256, g2W,nullptr, fw+O_MBUF,256, nullptr,0, NL,256,256);
    gather_k<<<4096,256,0,stream>>>(fw+O_MBUF, csr, row_start, dinv, g2b, fw+O_H2);

    // mamba
    gemm_k<0,256><<<dim3(128,4),256,0,stream>>>(fw+O_H2,256, inW,nullptr, fw+O_XZ,1024, nullptr,0, NL,256,1024);
    conv_k<<<8192,256,0,stream>>>(fw+O_XZ, cW, cb, fw+O_XC2);
    gemm_k<0,128><<<dim3(128,1),256,0,stream>>>(fw+O_XC2,512, xpW,nullptr, fw+O_PROJ,32, nullptr,0, NL,512,32);
    gemm_k<2,256><<<dim3(128,2),256,0,stream>>>(fw+O_PROJ,32, dtW,dtb, fw+O_DELTA,512, nullptr,0, NL,16,512);
    scan1_k<<<128,256,0,stream>>>(fw+O_DELTA, fw+O_XC2, fw+O_PROJ, Alog, fw+O_P, fw+O_HL);
    scan2_k<<<16,256,0,stream>>>(fw+O_P, fw+O_HL, fw+O_HST);
    scan3_k<<<128,256,0,stream>>>(fw+O_DELTA, fw+O_XC2, fw+O_PROJ, Alog, fw+O_HST, Dp, fw+O_XZ);
    gemm_k<0,128><<<dim3(128,2),256,0,stream>>>(fw+O_XZ,1024, outW,nullptr, fw+O_CAT+256,768, nullptr,0, NL,512,256);

    // attention (q,k reuse delta; v reuses xc2; out reuses mbuf)
    gemm_k<0,128><<<dim3(128,2),256,0,stream>>>(fw+O_H2,256, Wq,bq, fw+O_DELTA,256, nullptr,0, NL,256,256);
    gemm_k<0,128><<<dim3(128,2),256,0,stream>>>(fw+O_H2,256, Wk,bk, fw+O_DELTA+1048576,256, nullptr,0, NL,256,256);
    gemm_k<0,128><<<dim3(128,2),256,0,stream>>>(fw+O_H2,256, Wv,bv, fw+O_XC2,256, nullptr,0, NL,256,256);
    attn_k<<<dim3(128,4),256,0,stream>>>(fw+O_DELTA, fw+O_DELTA+1048576, fw+O_XC2, fw+O_MBUF);
    gemm_k<0,128><<<dim3(128,2),256,0,stream>>>(fw+O_MBUF,256, Wo,bo, fw+O_CAT+512,768, nullptr,0, NL,256,256);

    // fuse + residual + LN + pool + heads
    pack_k<<<4096,256,0,stream>>>(fw+O_H2, fw+O_CAT);
    gemm_k<1,128><<<dim3(128,2),256,0,stream>>>(fw+O_CAT,768, fusW,fusb, fw+O_H0,256, fw+O_H2,256, NL,768,256);
    ln_k<<<4096,256,0,stream>>>(fw+O_H0, lng, lnb, fw+O_H1);
    pool_k<<<8,256,0,stream>>>(fw+O_H1, fw+O_POOL);
    heads_k<<<(NOUT+255)/256,256,0,stream>>>(fw+O_POOL, cwp,cbp,hwp,hbp,twp,tbp,p1w,p1b,p2w,p2b,
                                             dwp,dbp,swp,sbp, (float*)d_out);
}

// Round 6
// 1045.202 us; speedup vs baseline: 2.0306x; 2.0306x over previous
//
#include <hip/hip_runtime.h>
#include <hip/hip_bf16.h>
#include <math.h>

typedef __hip_bfloat16 hbf;
typedef short bf16x8 __attribute__((ext_vector_type(8)));
typedef float f32x4 __attribute__((ext_vector_type(4)));

// ---------------- problem constants ----------------
constexpr int NL  = 4096;   // B*N tokens
constexpr int HH  = 256;    // hidden
constexpr int NE  = 8192;   // edges per batch
constexpr int DIc = 512;    // mamba inner
constexpr int DSc = 8;      // mamba state
constexpr int NCH = 64;     // scan chunks
constexpr int CLc = 64;     // chunk length
constexpr int NOUT = 12416; // 8 * (1+4+3+512+512+512+8)

// ---------------- workspace layout (float offsets) ----------------
constexpr size_t O_MBUF  = 0;          // 1048576  gcn msgs; later v
constexpr size_t O_H1    = 1048576;    // 1048576  h1; later q
constexpr size_t O_H2    = 2097152;    // 1048576  h2 (live to fus resid)
constexpr size_t O_XZ    = 3145728;    // 4194304  xz; later k@+0, catb(bf16)@+1048576
constexpr size_t O_XC    = 7340032;    // 2097152  xc; later fused@+0
constexpr size_t O_DELTA = 9437184;    // 2097152  delta; later aob(bf16)@+0
constexpr size_t O_PROJ  = 11534336;   // 131072
constexpr size_t O_P     = 11665408;   // 262144
constexpr size_t O_HL    = 11927552;   // 262144
constexpr size_t O_HST   = 12189696;   // 262144
constexpr size_t O_HF    = 12451840;   // 1048576  yb(bf16) early; hf later
constexpr size_t O_POOL  = 13500416;   // 2048
constexpr size_t O_DINV  = 13502464;   // 4096
constexpr size_t O_INT   = 13506560;   // 81928 ints
constexpr size_t O_WT    = 13588496;   // 512000   transposed bf16 weights (1.024M bf16)
constexpr size_t O_XB    = 14100496;   // 65536    x bf16
constexpr size_t O_H0B   = 14166032;   // 524288   h0 bf16; later h1b
constexpr size_t O_H2B   = 14690320;   // 524288
constexpr size_t O_XCB   = 15214608;   // 1048576
constexpr size_t O_DTAB  = 16263184;   // 65536    dt-input bf16 (K padded 16->32)
// total 16328720 floats = 65.3 MB

// ---------------- weight transpose-cast table ----------------
// dst (bf16): Wt[n*Kp + k] = (k<K) ? W[k*N + n] : 0
constexpr int NW = 12;
__device__ __constant__ int wc_cum[NW+1] = {
    0, 8192, 73728, 139264, 401408, 417792, 434176, 565248,
    630784, 696320, 761856, 827392, 1024000 };
__device__ __constant__ int wc_K [NW] = {32,256,256,256,512,16,512,256,256,256,256,768};
__device__ __constant__ int wc_N [NW] = {256,256,256,1024,32,512,256,256,256,256,256,256};
__device__ __constant__ int wc_Kp[NW] = {32,256,256,256,512,32,512,256,256,256,256,768};
struct WSrc { const float* p[NW]; };

__global__ __launch_bounds__(256) void wcast_k(WSrc ws, hbf* __restrict__ dst) {
    int idx = blockIdx.x*256 + threadIdx.x;
    if (idx >= 1024000) return;
    int lo = 0, hi = NW-1;
    while (lo < hi) { int mid = (lo+hi+1)>>1; if (idx >= wc_cum[mid]) lo = mid; else hi = mid-1; }
    int local = idx - wc_cum[lo];
    int Kp = wc_Kp[lo], K = wc_K[lo], N = wc_N[lo];
    int n = local / Kp, k = local - n*Kp;
    float v = (k < K) ? ws.p[lo][(size_t)k*N + n] : 0.0f;
    dst[idx] = __float2bfloat16(v);
}

__global__ void cast_k(const float* __restrict__ s, hbf* __restrict__ d, int n) {
    int i = blockIdx.x*256 + threadIdx.x;
    if (i < n) d[i] = __float2bfloat16(s[i]);
}

// proj (4096x32, cols 0..15 = dt input) -> bf16 4096x32, cols 16..31 zero
__global__ void cast_pad_k(const float* __restrict__ proj, hbf* __restrict__ d) {
    int i = blockIdx.x*256 + threadIdx.x;    // 4096*32
    int r = i >> 5, k = i & 31;
    d[i] = __float2bfloat16((k < 16) ? proj[r*32 + k] : 0.0f);
}

// ---------------- graph prep ----------------
__global__ void zero_k(int* __restrict__ p) { p[blockIdx.x*256 + threadIdx.x] = 0; }

__global__ void count_k(const int* __restrict__ ei, int* __restrict__ indeg) {
    int i = blockIdx.x*256 + threadIdx.x;
    int b = i >> 13, e = i & 8191;
    int dst = ei[b*2*NE + NE + e] + (b << 9);
    atomicAdd(&indeg[dst], 1);
}

__global__ __launch_bounds__(1024) void prefix_k(const int* __restrict__ indeg,
                                                 int* __restrict__ row_start,
                                                 int* __restrict__ cursor) {
    __shared__ int part[1024];
    int t = threadIdx.x;
    int v0[4]; int s = 0;
    #pragma unroll
    for (int i = 0; i < 4; i++) { v0[i] = s; s += indeg[t*4 + i]; }
    part[t] = s;
    __syncthreads();
    for (int o = 1; o < 1024; o <<= 1) {
        int x = (t >= o) ? part[t-o] : 0;
        __syncthreads();
        part[t] += x;
        __syncthreads();
    }
    int base = (t > 0) ? part[t-1] : 0;
    #pragma unroll
    for (int i = 0; i < 4; i++) {
        int rs = base + v0[i];
        row_start[t*4+i] = rs; cursor[t*4+i] = rs;
    }
    if (t == 1023) row_start[4096] = part[1023];
}

__global__ void scatter_k(const int* __restrict__ ei, int* __restrict__ cursor,
                          int* __restrict__ csr) {
    int i = blockIdx.x*256 + threadIdx.x;
    int b = i >> 13, e = i & 8191;
    int src = ei[b*2*NE + e]       + (b << 9);
    int dst = ei[b*2*NE + NE + e]  + (b << 9);
    int pos = atomicAdd(&cursor[dst], 1);
    csr[pos] = src;
}

__global__ void dinv_k(const int* __restrict__ indeg, float* __restrict__ dinv) {
    int i = blockIdx.x*256 + threadIdx.x;
    dinv[i] = rsqrtf(1.0f + (float)indeg[i]);
}

__global__ __launch_bounds__(256) void gather_k(const float* __restrict__ m,
                        const int* __restrict__ csr, const int* __restrict__ row_start,
                        const float* __restrict__ dinv, const float* __restrict__ bias,
                        float* __restrict__ out) {
    int n = blockIdx.x, c = threadIdx.x;
    float dn = dinv[n];
    float acc = m[(size_t)n*HH + c] * dn * dn;
    int e0 = row_start[n], e1 = row_start[n+1];
    for (int e = e0; e < e1; e++) {
        int s = csr[e];
        acc += m[(size_t)s*HH + c] * (dinv[s] * dn);
    }
    out[(size_t)n*HH + c] = fmaxf(acc + bias[c], 0.0f);
}

// ---------------- bf16 MFMA GEMM ----------------
// C[M,N](ldc) = act(A[M,K]bf16 @ B[K,N]bf16 + bias) (+resid)
// A row-major contiguous (lda=K), Bt = B^T row-major (Bt[n*K+k]). K mult of 32.
// block 256 (4 waves as 2x2), tile 64x64; grid (M/64, ceil(N/64)).
template<int ACT, int OUTBF>
__global__ __launch_bounds__(256) void mg_k(const unsigned short* __restrict__ A,
        const unsigned short* __restrict__ Bt, const float* __restrict__ bias,
        void* __restrict__ Cp, int ldc, const float* __restrict__ resid, int ldr,
        int M, int K, int N)
{
    __shared__ __align__(16) unsigned short Asm[64][40];
    __shared__ __align__(16) unsigned short Bsm[64][40];
    int t = threadIdx.x;
    int lane = t & 63, w = t >> 6;
    int wm = w & 1, wn = w >> 1;
    int row0 = blockIdx.x * 64, col0 = blockIdx.y * 64;
    int sr = t >> 2;             // staging row/col 0..63
    int sk = (t & 3) * 8;        // staging k offset
    f32x4 acc[2][2] = {};

    int fr = lane & 15, fq = (lane >> 4) * 8;
    for (int k0 = 0; k0 < K; k0 += 32) {
        __syncthreads();
        *(uint4*)&Asm[sr][sk] = *(const uint4*)&A[(size_t)(row0 + sr)*K + k0 + sk];
        uint4 bv = make_uint4(0u,0u,0u,0u);
        int bn = col0 + sr;
        if (bn < N) bv = *(const uint4*)&Bt[(size_t)bn*K + k0 + sk];
        *(uint4*)&Bsm[sr][sk] = bv;
        __syncthreads();
        bf16x8 a0 = *(bf16x8*)&Asm[wm*32 + fr][fq];
        bf16x8 a1 = *(bf16x8*)&Asm[wm*32 + 16 + fr][fq];
        bf16x8 b0 = *(bf16x8*)&Bsm[wn*32 + fr][fq];
        bf16x8 b1 = *(bf16x8*)&Bsm[wn*32 + 16 + fr][fq];
        acc[0][0] = __builtin_amdgcn_mfma_f32_16x16x32_bf16(a0, b0, acc[0][0], 0, 0, 0);
        acc[0][1] = __builtin_amdgcn_mfma_f32_16x16x32_bf16(a0, b1, acc[0][1], 0, 0, 0);
        acc[1][0] = __builtin_amdgcn_mfma_f32_16x16x32_bf16(a1, b0, acc[1][0], 0, 0, 0);
        acc[1][1] = __builtin_amdgcn_mfma_f32_16x16x32_bf16(a1, b1, acc[1][1], 0, 0, 0);
    }

    int fc = lane & 15, frq = (lane >> 4) * 4;
    #pragma unroll
    for (int mt = 0; mt < 2; mt++) {
        #pragma unroll
        for (int nt = 0; nt < 2; nt++) {
            int col = col0 + wn*32 + nt*16 + fc;
            if (col >= N) continue;
            float bvv = bias ? bias[col] : 0.0f;
            #pragma unroll
            for (int i = 0; i < 4; i++) {
                int row = row0 + wm*32 + mt*16 + frq + i;
                float v = acc[mt][nt][i] + bvv;
                if (ACT == 1) v = fmaxf(v, 0.0f);
                if (ACT == 2) v = (v > 20.0f) ? v : log1pf(expf(v));   // softplus
                if (resid) v += resid[(size_t)row*ldr + col];
                if (OUTBF) ((hbf*)Cp)[(size_t)row*ldc + col] = __float2bfloat16(v);
                else       ((float*)Cp)[(size_t)row*ldc + col] = v;
            }
        }
    }
}

// ---------------- mamba: conv + silu ----------------
__global__ void conv_k(const float* __restrict__ xz, const float* __restrict__ cW,
                       const float* __restrict__ cb, float* __restrict__ xc2) {
    int i = blockIdx.x*256 + threadIdx.x;  // NL*512
    int l = i >> 9, d = i & 511;
    float acc = cb[d];
    #pragma unroll
    for (int k = 0; k < 4; k++) {
        int ls = l - 3 + k;
        if (ls >= 0) acc += xz[(size_t)ls*1024 + d] * cW[d*4 + k];
    }
    xc2[i] = acc / (1.0f + __expf(-acc));   // silu
}

// ---------------- mamba chunked scan ----------------
__global__ __launch_bounds__(256) void scan1_k(const float* __restrict__ delta,
                        const float* __restrict__ xc, const float* __restrict__ proj,
                        const float* __restrict__ Alog,
                        float* __restrict__ P, float* __restrict__ Hl)
{
    int c = blockIdx.x >> 1;
    int d = ((blockIdx.x & 1) << 8) + threadIdx.x;
    float Ac[DSc], pr[DSc], h[DSc];
    #pragma unroll
    for (int s2 = 0; s2 < DSc; s2++) { Ac[s2] = -__expf(Alog[d*DSc+s2]); pr[s2]=1.0f; h[s2]=0.0f; }
    int l0 = c << 6;
    for (int l = l0; l < l0 + CLc; l++) {
        float dl = delta[(size_t)l*DIc + d];
        float dx = dl * xc[(size_t)l*DIc + d];
        const float* pb = proj + l*32 + 16;
        #pragma unroll
        for (int s2 = 0; s2 < DSc; s2++) {
            float a = __expf(dl * Ac[s2]);
            h[s2] = a*h[s2] + dx*pb[s2];
            pr[s2] *= a;
        }
    }
    #pragma unroll
    for (int s2 = 0; s2 < DSc; s2++) {
        P [(size_t)(c*DSc+s2)*DIc + d] = pr[s2];
        Hl[(size_t)(c*DSc+s2)*DIc + d] = h[s2];
    }
}

__global__ void scan2_k(const float* __restrict__ P, const float* __restrict__ Hl,
                        float* __restrict__ Hst) {
    int tg = blockIdx.x*256 + threadIdx.x;
    float hcur = 0.0f;
    for (int c = 0; c < NCH; c++) {
        size_t off = (size_t)c*4096 + tg;
        Hst[off] = hcur;
        hcur = Hl[off] + P[off]*hcur;
    }
}

// rescan with carry-in; y=(y+Dp*xc)*silu(zg) -> bf16 Y (4096x512)
__global__ __launch_bounds__(256) void scan3_k(const float* __restrict__ delta,
                        const float* __restrict__ xc, const float* __restrict__ proj,
                        const float* __restrict__ Alog, const float* __restrict__ Hst,
                        const float* __restrict__ Dp, const float* __restrict__ xz,
                        hbf* __restrict__ Y)
{
    int c = blockIdx.x >> 1;
    int d = ((blockIdx.x & 1) << 8) + threadIdx.x;
    float Ac[DSc], h[DSc];
    #pragma unroll
    for (int s2 = 0; s2 < DSc; s2++) {
        Ac[s2] = -__expf(Alog[d*DSc+s2]);
        h[s2]  = Hst[(size_t)(c*DSc+s2)*DIc + d];
    }
    float dpv = Dp[d];
    int l0 = c << 6;
    for (int l = l0; l < l0 + CLc; l++) {
        float dl = delta[(size_t)l*DIc + d];
        float xv = xc[(size_t)l*DIc + d];
        float dx = dl * xv;
        const float* pb = proj + l*32 + 16;
        float y = 0.0f;
        #pragma unroll
        for (int s2 = 0; s2 < DSc; s2++) {
            float a = __expf(dl * Ac[s2]);
            h[s2] = a*h[s2] + dx*pb[s2];
            y += h[s2] * pb[8+s2];
        }
        float z = xz[(size_t)l*1024 + 512 + d];
        float sz = z / (1.0f + __expf(-z));
        Y[(size_t)l*DIc + d] = __float2bfloat16((y + dpv*xv) * sz);
    }
}

// ---------------- flash attention fp32 (TQ=32, TK=64, hd=64), bf16 out ----------------
__global__ __launch_bounds__(256) void attn_k(const float* __restrict__ gq,
                       const float* __restrict__ gk, const float* __restrict__ gv,
                       hbf* __restrict__ go)
{
    __shared__ __align__(16) float Qs[32][68];
    __shared__ __align__(16) float Ks[64][68];
    __shared__ __align__(16) float Vs[64][68];
    __shared__ __align__(16) float Ss[32][68];
    __shared__ float mrow[32], lrow[32], arow[32];
    int t = threadIdx.x;
    int h = blockIdx.y;
    int q0 = blockIdx.x * 32;
    #pragma unroll
    for (int i = 0; i < 2; i++) {
        int idx = t + i*256;
        int r = idx >> 4, d4 = (idx & 15)*4;
        *(float4*)&Qs[r][d4] = *(const float4*)&gq[(size_t)(q0+r)*HH + h*64 + d4];
    }
    if (t < 32) { mrow[t] = -1e30f; lrow[t] = 0.0f; }
    int r0 = (t >> 5) * 4;
    int tk = t & 31;
    int d0 = (t & 31) * 2;
    float oacc[4][2] = {};

    for (int kt_ = 0; kt_ < NL; kt_ += 64) {
        __syncthreads();
        #pragma unroll
        for (int i = 0; i < 4; i++) {
            int idx = t + i*256;
            int r = idx >> 4, d4 = (idx & 15)*4;
            *(float4*)&Ks[r][d4] = *(const float4*)&gk[(size_t)(kt_+r)*HH + h*64 + d4];
            *(float4*)&Vs[r][d4] = *(const float4*)&gv[(size_t)(kt_+r)*HH + h*64 + d4];
        }
        __syncthreads();
        float s[4][2] = {};
        #pragma unroll
        for (int dc = 0; dc < 64; dc += 4) {
            float4 k0v = *(const float4*)&Ks[tk][dc];
            float4 k1v = *(const float4*)&Ks[tk+32][dc];
            #pragma unroll
            for (int i = 0; i < 4; i++) {
                float4 qv = *(const float4*)&Qs[r0+i][dc];
                s[i][0] += qv.x*k0v.x + qv.y*k0v.y + qv.z*k0v.z + qv.w*k0v.w;
                s[i][1] += qv.x*k1v.x + qv.y*k1v.y + qv.z*k1v.z + qv.w*k1v.w;
            }
        }
        #pragma unroll
        for (int i = 0; i < 4; i++) {
            Ss[r0+i][tk]    = s[i][0] * 0.125f;
            Ss[r0+i][tk+32] = s[i][1] * 0.125f;
        }
        __syncthreads();
        if (t < 32) {
            float m_old = mrow[t];
            float mx = m_old;
            #pragma unroll 8
            for (int k = 0; k < 64; k++) mx = fmaxf(mx, Ss[t][k]);
            float alpha = __expf(m_old - mx);
            float sum = 0.0f;
            #pragma unroll 8
            for (int k = 0; k < 64; k++) {
                float p = __expf(Ss[t][k] - mx);
                Ss[t][k] = p;
                sum += p;
            }
            lrow[t] = lrow[t]*alpha + sum;
            mrow[t] = mx;
            arow[t] = alpha;
        }
        __syncthreads();
        #pragma unroll
        for (int i = 0; i < 4; i++) {
            float al = arow[r0+i];
            oacc[i][0] *= al; oacc[i][1] *= al;
        }
        #pragma unroll
        for (int kk = 0; kk < 64; kk += 4) {
            float pa[4][4];
            #pragma unroll
            for (int i = 0; i < 4; i++) {
                float4 pv = *(const float4*)&Ss[r0+i][kk];
                pa[i][0]=pv.x; pa[i][1]=pv.y; pa[i][2]=pv.z; pa[i][3]=pv.w;
            }
            #pragma unroll
            for (int m2 = 0; m2 < 4; m2++) {
                float v0 = Vs[kk+m2][d0];
                float v1 = Vs[kk+m2][d0+1];
                #pragma unroll
                for (int i = 0; i < 4; i++) {
                    oacc[i][0] = fmaf(pa[i][m2], v0, oacc[i][0]);
                    oacc[i][1] = fmaf(pa[i][m2], v1, oacc[i][1]);
                }
            }
        }
    }
    #pragma unroll
    for (int i = 0; i < 4; i++) {
        float invl = 1.0f / lrow[r0+i];
        size_t base = (size_t)(q0+r0+i)*HH + h*64;
        go[base + d0]     = __float2bfloat16(oacc[i][0] * invl);
        go[base + d0 + 1] = __float2bfloat16(oacc[i][1] * invl);
    }
}

// ---------------- pack h (fp32) into catb cols 0..255 (bf16) ----------------
__global__ void pack_k(const float* __restrict__ h2, hbf* __restrict__ cat) {
    int i = blockIdx.x*256 + threadIdx.x;
    int r = i >> 8, c = i & 255;
    cat[(size_t)r*768 + c] = __float2bfloat16(h2[i]);
}

// ---------------- layernorm ----------------
__global__ __launch_bounds__(256) void ln_k(const float* __restrict__ X,
                    const float* __restrict__ g, const float* __restrict__ b,
                    float* __restrict__ Y) {
    __shared__ float red[4];
    int r = blockIdx.x, t = threadIdx.x;
    float v = X[(size_t)r*HH + t];
    float s = v;
    #pragma unroll
    for (int o = 32; o > 0; o >>= 1) s += __shfl_down(s, o);
    if ((t & 63) == 0) red[t >> 6] = s;
    __syncthreads();
    float mean = (red[0]+red[1]+red[2]+red[3]) * (1.0f/256.0f);
    float dfv = v - mean;
    float s2 = dfv*dfv;
    #pragma unroll
    for (int o = 32; o > 0; o >>= 1) s2 += __shfl_down(s2, o);
    __syncthreads();
    if ((t & 63) == 0) red[t >> 6] = s2;
    __syncthreads();
    float var = (red[0]+red[1]+red[2]+red[3]) * (1.0f/256.0f);
    Y[(size_t)r*HH + t] = dfv * rsqrtf(var + 1e-5f) * g[t] + b[t];
}

// ---------------- pool ----------------
__global__ void pool_k(const float* __restrict__ hf, float* __restrict__ pooled) {
    int b = blockIdx.x, t = threadIdx.x;
    float s = 0.0f;
    #pragma unroll 8
    for (int i = 0; i < 512; i++) s += hf[(size_t)((b<<9)+i)*HH + t];
    pooled[b*HH + t] = s * (1.0f/512.0f);
}

// ---------------- heads: out (8, 1552) ----------------
__global__ __launch_bounds__(256) void heads_k(const float* __restrict__ pooled,
        const float* cw, const float* cbh, const float* hw, const float* hb,
        const float* tw, const float* tb, const float* p1w, const float* p1b,
        const float* p2w, const float* p2b, const float* dw, const float* db,
        const float* sw, const float* sb, float* __restrict__ out)
{
    int idx = blockIdx.x*256 + threadIdx.x;
    if (idx >= NOUT) return;
    int b = idx / 1552, j = idx - b*1552;
    const float* w; const float* bi; int col, nc;
    if (j < 1)         { w = cw;  bi = cbh; col = j;        nc = 1;   }
    else if (j < 5)    { w = hw;  bi = hb;  col = j - 1;    nc = 4;   }
    else if (j < 8)    { w = tw;  bi = tb;  col = j - 5;    nc = 3;   }
    else if (j < 520)  { w = p1w; bi = p1b; col = j - 8;    nc = 512; }
    else if (j < 1032) { w = p2w; bi = p2b; col = j - 520;  nc = 512; }
    else if (j < 1544) { w = dw;  bi = db;  col = j - 1032; nc = 512; }
    else               { w = sw;  bi = sb;  col = j - 1544; nc = 8;   }
    float s = bi[col];
    const float* pl = pooled + b*HH;
    #pragma unroll 4
    for (int k = 0; k < 256; k++) s = fmaf(pl[k], w[k*nc + col], s);
    out[idx] = s;
}

// ---------------- launcher ----------------
extern "C" void kernel_launch(void* const* d_in, const int* in_sizes, int n_in,
                              void* d_out, int out_size, void* d_ws, size_t ws_size,
                              hipStream_t stream)
{
    (void)in_sizes; (void)n_in; (void)out_size; (void)ws_size;
    const float* x      = (const float*)d_in[0];
    const int*   ei     = (const int*)  d_in[1];
    const float* W_init = (const float*)d_in[2];
    const float* b_init = (const float*)d_in[3];
    const float* g1W = (const float*)d_in[4];
    const float* g1b = (const float*)d_in[5];
    const float* g2W = (const float*)d_in[6];
    const float* g2b = (const float*)d_in[7];
    const float* inW = (const float*)d_in[8];
    const float* cW  = (const float*)d_in[9];
    const float* cb  = (const float*)d_in[10];
    const float* xpW = (const float*)d_in[11];
    const float* dtW = (const float*)d_in[12];
    const float* dtb = (const float*)d_in[13];
    const float* Alog= (const float*)d_in[14];
    const float* Dp  = (const float*)d_in[15];
    const float* outW= (const float*)d_in[16];
    const float* Wq  = (const float*)d_in[17];
    const float* bq  = (const float*)d_in[18];
    const float* Wk  = (const float*)d_in[19];
    const float* bk  = (const float*)d_in[20];
    const float* Wv  = (const float*)d_in[21];
    const float* bv  = (const float*)d_in[22];
    const float* Wo  = (const float*)d_in[23];
    const float* bo  = (const float*)d_in[24];
    const float* fusW= (const float*)d_in[25];
    const float* fusb= (const float*)d_in[26];
    const float* lng = (const float*)d_in[27];
    const float* lnb = (const float*)d_in[28];
    const float* cwp = (const float*)d_in[29];
    const float* cbp = (const float*)d_in[30];
    const float* hwp = (const float*)d_in[31];
    const float* hbp = (const float*)d_in[32];
    const float* twp = (const float*)d_in[33];
    const float* tbp = (const float*)d_in[34];
    const float* p1w = (const float*)d_in[35];
    const float* p1b = (const float*)d_in[36];
    const float* p2w = (const float*)d_in[37];
    const float* p2b = (const float*)d_in[38];
    const float* dwp = (const float*)d_in[39];
    const float* dbp = (const float*)d_in[40];
    const float* swp = (const float*)d_in[41];
    const float* sbp = (const float*)d_in[42];

    float* fw = (float*)d_ws;
    int* iw = (int*)(fw + O_INT);
    int* indeg = iw;
    int* row_start = iw + 4096;
    int* cursor = iw + 8193;
    int* csr = iw + 12289;
    float* dinv = fw + O_DINV;

    // bf16 regions
    hbf* wt   = (hbf*)(fw + O_WT);
    hbf* xb   = (hbf*)(fw + O_XB);
    hbf* h0b  = (hbf*)(fw + O_H0B);   // also h1b later
    hbf* h2b  = (hbf*)(fw + O_H2B);
    hbf* xcb  = (hbf*)(fw + O_XCB);
    hbf* dtab = (hbf*)(fw + O_DTAB);
    hbf* yb   = (hbf*)(fw + O_HF);            // dead before hf is written
    hbf* aob  = (hbf*)(fw + O_DELTA);         // delta dead after scan3
    hbf* catb = (hbf*)(fw + O_XZ + 1048576);  // xz dead after scan3
    // fp32 aliases
    float* qb = fw + O_H1;       // h1 dead after cast
    float* kb = fw + O_XZ;       // first 1M of xz region
    float* vb = fw + O_MBUF;
    float* fused = fw + O_XC;    // xc dead after scan3
    float* hf = fw + O_HF;       // yb dead after out-GEMM

    // transposed-bf16 weight pointers (offsets per wc_cum)
    hbf* WtInit = wt + 0;
    hbf* WtG1   = wt + 8192;
    hbf* WtG2   = wt + 73728;
    hbf* WtIn   = wt + 139264;
    hbf* WtXp   = wt + 401408;
    hbf* WtDt   = wt + 417792;
    hbf* WtOut  = wt + 434176;
    hbf* WtQ    = wt + 565248;
    hbf* WtK    = wt + 630784;
    hbf* WtV    = wt + 696320;
    hbf* WtO    = wt + 761856;
    hbf* WtFus  = wt + 827392;

    // weight casts (once per launch)
    WSrc wsrc;
    wsrc.p[0]=W_init; wsrc.p[1]=g1W; wsrc.p[2]=g2W; wsrc.p[3]=inW; wsrc.p[4]=xpW;
    wsrc.p[5]=dtW; wsrc.p[6]=outW; wsrc.p[7]=Wq; wsrc.p[8]=Wk; wsrc.p[9]=Wv;
    wsrc.p[10]=Wo; wsrc.p[11]=fusW;
    wcast_k<<<4000,256,0,stream>>>(wsrc, wt);
    cast_k<<<512,256,0,stream>>>(x, xb, 131072);

    // graph prep
    zero_k<<<16,256,0,stream>>>(indeg);
    count_k<<<256,256,0,stream>>>(ei, indeg);
    prefix_k<<<1,1024,0,stream>>>(indeg, row_start, cursor);
    scatter_k<<<256,256,0,stream>>>(ei, cursor, csr);
    dinv_k<<<16,256,0,stream>>>(indeg, dinv);

    // h0 = relu(x @ W_init + b_init)  -> bf16 h0b
    mg_k<1,1><<<dim3(64,4),256,0,stream>>>((const unsigned short*)xb, (const unsigned short*)WtInit,
        b_init, h0b, 256, nullptr, 0, NL, 32, 256);
    // gcn1
    mg_k<0,0><<<dim3(64,4),256,0,stream>>>((const unsigned short*)h0b, (const unsigned short*)WtG1,
        nullptr, fw+O_MBUF, 256, nullptr, 0, NL, 256, 256);
    gather_k<<<4096,256,0,stream>>>(fw+O_MBUF, csr, row_start, dinv, g1b, fw+O_H1);
    cast_k<<<4096,256,0,stream>>>(fw+O_H1, h0b, 1048576);   // h1b reuses h0b region
    // gcn2
    mg_k<0,0><<<dim3(64,4),256,0,stream>>>((const unsigned short*)h0b, (const unsigned short*)WtG2,
        nullptr, fw+O_MBUF, 256, nullptr, 0, NL, 256, 256);
    gather_k<<<4096,256,0,stream>>>(fw+O_MBUF, csr, row_start, dinv, g2b, fw+O_H2);
    cast_k<<<4096,256,0,stream>>>(fw+O_H2, h2b, 1048576);

    // mamba
    mg_k<0,0><<<dim3(64,16),256,0,stream>>>((const unsigned short*)h2b, (const unsigned short*)WtIn,
        nullptr, fw+O_XZ, 1024, nullptr, 0, NL, 256, 1024);
    conv_k<<<8192,256,0,stream>>>(fw+O_XZ, cW, cb, fw+O_XC);
    cast_k<<<8192,256,0,stream>>>(fw+O_XC, xcb, 2097152);
    mg_k<0,0><<<dim3(64,1),256,0,stream>>>((const unsigned short*)xcb, (const unsigned short*)WtXp,
        nullptr, fw+O_PROJ, 32, nullptr, 0, NL, 512, 32);
    cast_pad_k<<<512,256,0,stream>>>(fw+O_PROJ, dtab);
    mg_k<2,0><<<dim3(64,8),256,0,stream>>>((const unsigned short*)dtab, (const unsigned short*)WtDt,
        dtb, fw+O_DELTA, 512, nullptr, 0, NL, 32, 512);
    scan1_k<<<128,256,0,stream>>>(fw+O_DELTA, fw+O_XC, fw+O_PROJ, Alog, fw+O_P, fw+O_HL);
    scan2_k<<<16,256,0,stream>>>(fw+O_P, fw+O_HL, fw+O_HST);
    scan3_k<<<128,256,0,stream>>>(fw+O_DELTA, fw+O_XC, fw+O_PROJ, Alog, fw+O_HST, Dp, fw+O_XZ, yb);
    mg_k<0,1><<<dim3(64,4),256,0,stream>>>((const unsigned short*)yb, (const unsigned short*)WtOut,
        nullptr, catb + 256, 768, nullptr, 0, NL, 512, 256);

    // attention
    mg_k<0,0><<<dim3(64,4),256,0,stream>>>((const unsigned short*)h2b, (const unsigned short*)WtQ,
        bq, qb, 256, nullptr, 0, NL, 256, 256);
    mg_k<0,0><<<dim3(64,4),256,0,stream>>>((const unsigned short*)h2b, (const unsigned short*)WtK,
        bk, kb, 256, nullptr, 0, NL, 256, 256);
    mg_k<0,0><<<dim3(64,4),256,0,stream>>>((const unsigned short*)h2b, (const unsigned short*)WtV,
        bv, vb, 256, nullptr, 0, NL, 256, 256);
    attn_k<<<dim3(128,4),256,0,stream>>>(qb, kb, vb, aob);
    mg_k<0,1><<<dim3(64,4),256,0,stream>>>((const unsigned short*)aob, (const unsigned short*)WtO,
        bo, catb + 512, 768, nullptr, 0, NL, 256, 256);

    // fuse + residual + LN + pool + heads
    pack_k<<<4096,256,0,stream>>>(fw+O_H2, catb);
    mg_k<1,0><<<dim3(64,4),256,0,stream>>>((const unsigned short*)catb, (const unsigned short*)WtFus,
        fusb, fused, 256, fw+O_H2, 256, NL, 768, 256);
    ln_k<<<4096,256,0,stream>>>(fused, lng, lnb, hf);
    pool_k<<<8,256,0,stream>>>(hf, fw+O_POOL);
    heads_k<<<(NOUT+255)/256,256,0,stream>>>(fw+O_POOL, cwp,cbp,hwp,hbp,twp,tbp,p1w,p1b,p2w,p2b,
                                             dwp,dbp,swp,sbp, (float*)d_out);
}

// Round 7
// 588.755 us; speedup vs baseline: 3.6048x; 1.7753x over previous
//
#include <hip/hip_runtime.h>
#include <hip/hip_bf16.h>
#include <math.h>

typedef __hip_bfloat16 hbf;
typedef short bf16x8 __attribute__((ext_vector_type(8)));
typedef float f32x4 __attribute__((ext_vector_type(4)));

// ---------------- problem constants ----------------
constexpr int NL  = 4096;   // B*N tokens
constexpr int HH  = 256;    // hidden
constexpr int NE  = 8192;   // edges per batch
constexpr int DIc = 512;    // mamba inner
constexpr int DSc = 8;      // mamba state
constexpr int NCH = 64;     // scan chunks
constexpr int CLc = 64;     // chunk length
constexpr int NOUT = 12416; // 8 * (1+4+3+512+512+512+8)

// ---------------- workspace layout (float offsets) ----------------
constexpr size_t O_MBUF  = 0;          // 1048576  gcn msgs
constexpr size_t O_H1    = 1048576;    // 1048576  h1 fp32; later qB(bf16)
constexpr size_t O_H2    = 2097152;    // 1048576  h2 (live to fus resid)
constexpr size_t O_XZ    = 3145728;    // 4194304  xz; later kB(bf16)@+0, catb(bf16)@+1048576
constexpr size_t O_XC    = 7340032;    // 2097152  xc; later vtB(bf16)@+0, fused fp32@+0 (after attn)
constexpr size_t O_DELTA = 9437184;    // 2097152  delta; later aob(bf16)@+0
constexpr size_t O_PROJ  = 11534336;   // 131072
constexpr size_t O_P     = 11665408;   // 262144
constexpr size_t O_HL    = 11927552;   // 262144
constexpr size_t O_HST   = 12189696;   // 262144
constexpr size_t O_HF    = 12451840;   // 1048576  yb(bf16) early; hf later
constexpr size_t O_POOL  = 13500416;   // 2048
constexpr size_t O_DINV  = 13502464;   // 4096
constexpr size_t O_INT   = 13506560;   // 81928 ints
constexpr size_t O_WT    = 13588496;   // transposed bf16 weights (1.024M bf16)
constexpr size_t O_XB    = 14100496;   // x bf16
constexpr size_t O_H0B   = 14166032;   // h0 bf16; later h1b
constexpr size_t O_H2B   = 14690320;
constexpr size_t O_XCB   = 15214608;
constexpr size_t O_DTAB  = 16263184;
// total ~16.3M floats = 65.3 MB

// ---------------- weight transpose-cast table ----------------
constexpr int NW = 12;
__device__ __constant__ int wc_cum[NW+1] = {
    0, 8192, 73728, 139264, 401408, 417792, 434176, 565248,
    630784, 696320, 761856, 827392, 1024000 };
__device__ __constant__ int wc_K [NW] = {32,256,256,256,512,16,512,256,256,256,256,768};
__device__ __constant__ int wc_N [NW] = {256,256,256,1024,32,512,256,256,256,256,256,256};
__device__ __constant__ int wc_Kp[NW] = {32,256,256,256,512,32,512,256,256,256,256,768};
struct WSrc { const float* p[NW]; };

__global__ __launch_bounds__(256) void wcast_k(WSrc ws, hbf* __restrict__ dst) {
    int idx = blockIdx.x*256 + threadIdx.x;
    if (idx >= 1024000) return;
    int lo = 0, hi = NW-1;
    while (lo < hi) { int mid = (lo+hi+1)>>1; if (idx >= wc_cum[mid]) lo = mid; else hi = mid-1; }
    int local = idx - wc_cum[lo];
    int Kp = wc_Kp[lo], K = wc_K[lo], N = wc_N[lo];
    int n = local / Kp, k = local - n*Kp;
    float v = (k < K) ? ws.p[lo][(size_t)k*N + n] : 0.0f;
    dst[idx] = __float2bfloat16(v);
}

__global__ void cast_k(const float* __restrict__ s, hbf* __restrict__ d, int n) {
    int i = blockIdx.x*256 + threadIdx.x;
    if (i < n) d[i] = __float2bfloat16(s[i]);
}

__global__ void cast_pad_k(const float* __restrict__ proj, hbf* __restrict__ d) {
    int i = blockIdx.x*256 + threadIdx.x;    // 4096*32
    int r = i >> 5, k = i & 31;
    d[i] = __float2bfloat16((k < 16) ? proj[r*32 + k] : 0.0f);
}

// ---------------- graph prep ----------------
__global__ void zero_k(int* __restrict__ p) { p[blockIdx.x*256 + threadIdx.x] = 0; }

__global__ void count_k(const int* __restrict__ ei, int* __restrict__ indeg) {
    int i = blockIdx.x*256 + threadIdx.x;
    int b = i >> 13, e = i & 8191;
    int dst = ei[b*2*NE + NE + e] + (b << 9);
    atomicAdd(&indeg[dst], 1);
}

__global__ __launch_bounds__(1024) void prefix_k(const int* __restrict__ indeg,
                                                 int* __restrict__ row_start,
                                                 int* __restrict__ cursor) {
    __shared__ int part[1024];
    int t = threadIdx.x;
    int v0[4]; int s = 0;
    #pragma unroll
    for (int i = 0; i < 4; i++) { v0[i] = s; s += indeg[t*4 + i]; }
    part[t] = s;
    __syncthreads();
    for (int o = 1; o < 1024; o <<= 1) {
        int x = (t >= o) ? part[t-o] : 0;
        __syncthreads();
        part[t] += x;
        __syncthreads();
    }
    int base = (t > 0) ? part[t-1] : 0;
    #pragma unroll
    for (int i = 0; i < 4; i++) {
        int rs = base + v0[i];
        row_start[t*4+i] = rs; cursor[t*4+i] = rs;
    }
    if (t == 1023) row_start[4096] = part[1023];
}

__global__ void scatter_k(const int* __restrict__ ei, int* __restrict__ cursor,
                          int* __restrict__ csr) {
    int i = blockIdx.x*256 + threadIdx.x;
    int b = i >> 13, e = i & 8191;
    int src = ei[b*2*NE + e]       + (b << 9);
    int dst = ei[b*2*NE + NE + e]  + (b << 9);
    int pos = atomicAdd(&cursor[dst], 1);
    csr[pos] = src;
}

__global__ void dinv_k(const int* __restrict__ indeg, float* __restrict__ dinv) {
    int i = blockIdx.x*256 + threadIdx.x;
    dinv[i] = rsqrtf(1.0f + (float)indeg[i]);
}

__global__ __launch_bounds__(256) void gather_k(const float* __restrict__ m,
                        const int* __restrict__ csr, const int* __restrict__ row_start,
                        const float* __restrict__ dinv, const float* __restrict__ bias,
                        float* __restrict__ out) {
    int n = blockIdx.x, c = threadIdx.x;
    float dn = dinv[n];
    float acc = m[(size_t)n*HH + c] * dn * dn;
    int e0 = row_start[n], e1 = row_start[n+1];
    for (int e = e0; e < e1; e++) {
        int s = csr[e];
        acc += m[(size_t)s*HH + c] * (dinv[s] * dn);
    }
    out[(size_t)n*HH + c] = fmaxf(acc + bias[c], 0.0f);
}

// ---------------- bf16 MFMA GEMM ----------------
// OUTM: 0 = fp32 C[row*ldc+col], 1 = bf16 C[row*ldc+col], 2 = bf16 transposed C[col*ldc+row]
template<int ACT, int OUTM>
__global__ __launch_bounds__(256) void mg_k(const unsigned short* __restrict__ A,
        const unsigned short* __restrict__ Bt, const float* __restrict__ bias,
        void* __restrict__ Cp, int ldc, const float* __restrict__ resid, int ldr,
        int M, int K, int N)
{
    __shared__ __align__(16) unsigned short Asm[64][40];
    __shared__ __align__(16) unsigned short Bsm[64][40];
    int t = threadIdx.x;
    int lane = t & 63, w = t >> 6;
    int wm = w & 1, wn = w >> 1;
    int row0 = blockIdx.x * 64, col0 = blockIdx.y * 64;
    int sr = t >> 2;
    int sk = (t & 3) * 8;
    f32x4 acc[2][2] = {};

    int fr = lane & 15, fq = (lane >> 4) * 8;
    for (int k0 = 0; k0 < K; k0 += 32) {
        __syncthreads();
        *(uint4*)&Asm[sr][sk] = *(const uint4*)&A[(size_t)(row0 + sr)*K + k0 + sk];
        uint4 bv = make_uint4(0u,0u,0u,0u);
        int bn = col0 + sr;
        if (bn < N) bv = *(const uint4*)&Bt[(size_t)bn*K + k0 + sk];
        *(uint4*)&Bsm[sr][sk] = bv;
        __syncthreads();
        bf16x8 a0 = *(bf16x8*)&Asm[wm*32 + fr][fq];
        bf16x8 a1 = *(bf16x8*)&Asm[wm*32 + 16 + fr][fq];
        bf16x8 b0 = *(bf16x8*)&Bsm[wn*32 + fr][fq];
        bf16x8 b1 = *(bf16x8*)&Bsm[wn*32 + 16 + fr][fq];
        acc[0][0] = __builtin_amdgcn_mfma_f32_16x16x32_bf16(a0, b0, acc[0][0], 0, 0, 0);
        acc[0][1] = __builtin_amdgcn_mfma_f32_16x16x32_bf16(a0, b1, acc[0][1], 0, 0, 0);
        acc[1][0] = __builtin_amdgcn_mfma_f32_16x16x32_bf16(a1, b0, acc[1][0], 0, 0, 0);
        acc[1][1] = __builtin_amdgcn_mfma_f32_16x16x32_bf16(a1, b1, acc[1][1], 0, 0, 0);
    }

    int fc = lane & 15, frq = (lane >> 4) * 4;
    #pragma unroll
    for (int mt = 0; mt < 2; mt++) {
        #pragma unroll
        for (int nt = 0; nt < 2; nt++) {
            int col = col0 + wn*32 + nt*16 + fc;
            if (col >= N) continue;
            float bvv = bias ? bias[col] : 0.0f;
            #pragma unroll
            for (int i = 0; i < 4; i++) {
                int row = row0 + wm*32 + mt*16 + frq + i;
                float v = acc[mt][nt][i] + bvv;
                if (ACT == 1) v = fmaxf(v, 0.0f);
                if (ACT == 2) v = (v > 20.0f) ? v : log1pf(expf(v));   // softplus
                if (resid) v += resid[(size_t)row*ldr + col];
                if (OUTM == 0)      ((float*)Cp)[(size_t)row*ldc + col] = v;
                else if (OUTM == 1) ((hbf*)Cp)[(size_t)row*ldc + col] = __float2bfloat16(v);
                else                ((hbf*)Cp)[(size_t)col*ldc + row] = __float2bfloat16(v);
            }
        }
    }
}

// ---------------- mamba: conv + silu ----------------
__global__ void conv_k(const float* __restrict__ xz, const float* __restrict__ cW,
                       const float* __restrict__ cb, float* __restrict__ xc2) {
    int i = blockIdx.x*256 + threadIdx.x;  // NL*512
    int l = i >> 9, d = i & 511;
    float acc = cb[d];
    #pragma unroll
    for (int k = 0; k < 4; k++) {
        int ls = l - 3 + k;
        if (ls >= 0) acc += xz[(size_t)ls*1024 + d] * cW[d*4 + k];
    }
    xc2[i] = acc / (1.0f + __expf(-acc));   // silu
}

// ---------------- mamba chunked scan ----------------
__global__ __launch_bounds__(256) void scan1_k(const float* __restrict__ delta,
                        const float* __restrict__ xc, const float* __restrict__ proj,
                        const float* __restrict__ Alog,
                        float* __restrict__ P, float* __restrict__ Hl)
{
    int c = blockIdx.x >> 1;
    int d = ((blockIdx.x & 1) << 8) + threadIdx.x;
    float Ac[DSc], pr[DSc], h[DSc];
    #pragma unroll
    for (int s2 = 0; s2 < DSc; s2++) { Ac[s2] = -__expf(Alog[d*DSc+s2]); pr[s2]=1.0f; h[s2]=0.0f; }
    int l0 = c << 6;
    for (int l = l0; l < l0 + CLc; l++) {
        float dl = delta[(size_t)l*DIc + d];
        float dx = dl * xc[(size_t)l*DIc + d];
        const float* pb = proj + l*32 + 16;
        #pragma unroll
        for (int s2 = 0; s2 < DSc; s2++) {
            float a = __expf(dl * Ac[s2]);
            h[s2] = a*h[s2] + dx*pb[s2];
            pr[s2] *= a;
        }
    }
    #pragma unroll
    for (int s2 = 0; s2 < DSc; s2++) {
        P [(size_t)(c*DSc+s2)*DIc + d] = pr[s2];
        Hl[(size_t)(c*DSc+s2)*DIc + d] = h[s2];
    }
}

__global__ void scan2_k(const float* __restrict__ P, const float* __restrict__ Hl,
                        float* __restrict__ Hst) {
    int tg = blockIdx.x*256 + threadIdx.x;
    float hcur = 0.0f;
    for (int c = 0; c < NCH; c++) {
        size_t off = (size_t)c*4096 + tg;
        Hst[off] = hcur;
        hcur = Hl[off] + P[off]*hcur;
    }
}

__global__ __launch_bounds__(256) void scan3_k(const float* __restrict__ delta,
                        const float* __restrict__ xc, const float* __restrict__ proj,
                        const float* __restrict__ Alog, const float* __restrict__ Hst,
                        const float* __restrict__ Dp, const float* __restrict__ xz,
                        hbf* __restrict__ Y)
{
    int c = blockIdx.x >> 1;
    int d = ((blockIdx.x & 1) << 8) + threadIdx.x;
    float Ac[DSc], h[DSc];
    #pragma unroll
    for (int s2 = 0; s2 < DSc; s2++) {
        Ac[s2] = -__expf(Alog[d*DSc+s2]);
        h[s2]  = Hst[(size_t)(c*DSc+s2)*DIc + d];
    }
    float dpv = Dp[d];
    int l0 = c << 6;
    for (int l = l0; l < l0 + CLc; l++) {
        float dl = delta[(size_t)l*DIc + d];
        float xv = xc[(size_t)l*DIc + d];
        float dx = dl * xv;
        const float* pb = proj + l*32 + 16;
        float y = 0.0f;
        #pragma unroll
        for (int s2 = 0; s2 < DSc; s2++) {
            float a = __expf(dl * Ac[s2]);
            h[s2] = a*h[s2] + dx*pb[s2];
            y += h[s2] * pb[8+s2];
        }
        float z = xz[(size_t)l*1024 + 512 + d];
        float sz = z / (1.0f + __expf(-z));
        Y[(size_t)l*DIc + d] = __float2bfloat16((y + dpv*xv) * sz);
    }
}

// ---------------- MFMA flash attention (bf16 in/out, fp32 softmax/acc) ----------------
// grid (NL/64, 4). block 256 = 4 waves; wave w owns S/O rows [w*16, w*16+16).
// Q,K bf16 [NL][256] (head offset h*64); Vt bf16 [256][NL] (row = h*64+d).
__global__ __launch_bounds__(256) void attn_k(const unsigned short* __restrict__ Q,
                       const unsigned short* __restrict__ K,
                       const unsigned short* __restrict__ Vt,
                       hbf* __restrict__ O)
{
    __shared__ __align__(16) unsigned short Qs[64][72];
    __shared__ __align__(16) unsigned short Ks[64][72];
    __shared__ __align__(16) unsigned short Vs[64][72];
    __shared__ __align__(16) unsigned short Ps[64][72];
    __shared__ float mrow[64], lrow[64];
    int t = threadIdx.x, lane = t & 63, w = t >> 6;
    int h = blockIdx.y, q0 = blockIdx.x * 64;
    int sr = t >> 2, sk = (t & 3) * 16;
    int fm = lane & 15, fq = lane >> 4;

    // stage Q tile (64 rows x 64 dims)
    *(uint4*)&Qs[sr][sk]     = *(const uint4*)&Q[(size_t)(q0+sr)*HH + h*64 + sk];
    *(uint4*)&Qs[sr][sk + 8] = *(const uint4*)&Q[(size_t)(q0+sr)*HH + h*64 + sk + 8];
    if (t < 64) { mrow[t] = -1e30f; lrow[t] = 0.0f; }

    f32x4 o[4] = {};
    for (int kt = 0; kt < NL; kt += 64) {
        __syncthreads();
        *(uint4*)&Ks[sr][sk]     = *(const uint4*)&K[(size_t)(kt+sr)*HH + h*64 + sk];
        *(uint4*)&Ks[sr][sk + 8] = *(const uint4*)&K[(size_t)(kt+sr)*HH + h*64 + sk + 8];
        *(uint4*)&Vs[sr][sk]     = *(const uint4*)&Vt[(size_t)(h*64+sr)*NL + kt + sk];
        *(uint4*)&Vs[sr][sk + 8] = *(const uint4*)&Vt[(size_t)(h*64+sr)*NL + kt + sk + 8];
        __syncthreads();

        // S strip = Q[w*16..+16) x K^T  (4 col-frags x K=64)
        f32x4 s[4] = {};
        #pragma unroll
        for (int ks = 0; ks < 2; ks++) {
            bf16x8 a = *(bf16x8*)&Qs[w*16 + fm][ks*32 + fq*8];
            #pragma unroll
            for (int nt = 0; nt < 4; nt++) {
                bf16x8 b = *(bf16x8*)&Ks[nt*16 + fm][ks*32 + fq*8];
                s[nt] = __builtin_amdgcn_mfma_f32_16x16x32_bf16(a, b, s[nt], 0, 0, 0);
            }
        }
        // online softmax in C-layout registers: row = fq*4+i, col = nt*16+fm
        #pragma unroll
        for (int i = 0; i < 4; i++) {
            int row = w*16 + fq*4 + i;
            float s0 = s[0][i]*0.125f, s1 = s[1][i]*0.125f,
                  s2 = s[2][i]*0.125f, s3 = s[3][i]*0.125f;
            float mx = fmaxf(fmaxf(s0, s1), fmaxf(s2, s3));
            #pragma unroll
            for (int off = 1; off < 16; off <<= 1) mx = fmaxf(mx, __shfl_xor(mx, off));
            float mold = mrow[row];
            float mnew = fmaxf(mold, mx);
            float alpha = __expf(mold - mnew);
            float p0 = __expf(s0 - mnew), p1 = __expf(s1 - mnew),
                  p2 = __expf(s2 - mnew), p3 = __expf(s3 - mnew);
            float ps = p0 + p1 + p2 + p3;
            #pragma unroll
            for (int off = 1; off < 16; off <<= 1) ps += __shfl_xor(ps, off);
            if (fm == 0) { lrow[row] = lrow[row]*alpha + ps; mrow[row] = mnew; }
            o[0][i] *= alpha; o[1][i] *= alpha; o[2][i] *= alpha; o[3][i] *= alpha;
            *(hbf*)&Ps[row][ 0 + fm] = __float2bfloat16(p0);
            *(hbf*)&Ps[row][16 + fm] = __float2bfloat16(p1);
            *(hbf*)&Ps[row][32 + fm] = __float2bfloat16(p2);
            *(hbf*)&Ps[row][48 + fm] = __float2bfloat16(p3);
        }
        // O += P x V  (A = own P rows, B = Vt frags)
        #pragma unroll
        for (int ks = 0; ks < 2; ks++) {
            bf16x8 a = *(bf16x8*)&Ps[w*16 + fm][ks*32 + fq*8];
            #pragma unroll
            for (int nt = 0; nt < 4; nt++) {
                bf16x8 b = *(bf16x8*)&Vs[nt*16 + fm][ks*32 + fq*8];
                o[nt] = __builtin_amdgcn_mfma_f32_16x16x32_bf16(a, b, o[nt], 0, 0, 0);
            }
        }
    }
    #pragma unroll
    for (int i = 0; i < 4; i++) {
        int row = w*16 + fq*4 + i;
        float inv = 1.0f / lrow[row];
        #pragma unroll
        for (int nt = 0; nt < 4; nt++) {
            O[(size_t)(q0 + row)*HH + h*64 + nt*16 + fm] = __float2bfloat16(o[nt][i] * inv);
        }
    }
}

// ---------------- pack h (fp32) into catb cols 0..255 (bf16) ----------------
__global__ void pack_k(const float* __restrict__ h2, hbf* __restrict__ cat) {
    int i = blockIdx.x*256 + threadIdx.x;
    int r = i >> 8, c = i & 255;
    cat[(size_t)r*768 + c] = __float2bfloat16(h2[i]);
}

// ---------------- layernorm ----------------
__global__ __launch_bounds__(256) void ln_k(const float* __restrict__ X,
                    const float* __restrict__ g, const float* __restrict__ b,
                    float* __restrict__ Y) {
    __shared__ float red[4];
    int r = blockIdx.x, t = threadIdx.x;
    float v = X[(size_t)r*HH + t];
    float s = v;
    #pragma unroll
    for (int o = 32; o > 0; o >>= 1) s += __shfl_down(s, o);
    if ((t & 63) == 0) red[t >> 6] = s;
    __syncthreads();
    float mean = (red[0]+red[1]+red[2]+red[3]) * (1.0f/256.0f);
    float dfv = v - mean;
    float s2 = dfv*dfv;
    #pragma unroll
    for (int o = 32; o > 0; o >>= 1) s2 += __shfl_down(s2, o);
    __syncthreads();
    if ((t & 63) == 0) red[t >> 6] = s2;
    __syncthreads();
    float var = (red[0]+red[1]+red[2]+red[3]) * (1.0f/256.0f);
    Y[(size_t)r*HH + t] = dfv * rsqrtf(var + 1e-5f) * g[t] + b[t];
}

// ---------------- pool ----------------
__global__ void pool_k(const float* __restrict__ hf, float* __restrict__ pooled) {
    int b = blockIdx.x, t = threadIdx.x;
    float s = 0.0f;
    #pragma unroll 8
    for (int i = 0; i < 512; i++) s += hf[(size_t)((b<<9)+i)*HH + t];
    pooled[b*HH + t] = s * (1.0f/512.0f);
}

// ---------------- heads: out (8, 1552) ----------------
__global__ __launch_bounds__(256) void heads_k(const float* __restrict__ pooled,
        const float* cw, const float* cbh, const float* hw, const float* hb,
        const float* tw, const float* tb, const float* p1w, const float* p1b,
        const float* p2w, const float* p2b, const float* dw, const float* db,
        const float* sw, const float* sb, float* __restrict__ out)
{
    int idx = blockIdx.x*256 + threadIdx.x;
    if (idx >= NOUT) return;
    int b = idx / 1552, j = idx - b*1552;
    const float* w; const float* bi; int col, nc;
    if (j < 1)         { w = cw;  bi = cbh; col = j;        nc = 1;   }
    else if (j < 5)    { w = hw;  bi = hb;  col = j - 1;    nc = 4;   }
    else if (j < 8)    { w = tw;  bi = tb;  col = j - 5;    nc = 3;   }
    else if (j < 520)  { w = p1w; bi = p1b; col = j - 8;    nc = 512; }
    else if (j < 1032) { w = p2w; bi = p2b; col = j - 520;  nc = 512; }
    else if (j < 1544) { w = dw;  bi = db;  col = j - 1032; nc = 512; }
    else               { w = sw;  bi = sb;  col = j - 1544; nc = 8;   }
    float s = bi[col];
    const float* pl = pooled + b*HH;
    #pragma unroll 4
    for (int k = 0; k < 256; k++) s = fmaf(pl[k], w[k*nc + col], s);
    out[idx] = s;
}

// ---------------- launcher ----------------
extern "C" void kernel_launch(void* const* d_in, const int* in_sizes, int n_in,
                              void* d_out, int out_size, void* d_ws, size_t ws_size,
                              hipStream_t stream)
{
    (void)in_sizes; (void)n_in; (void)out_size; (void)ws_size;
    const float* x      = (const float*)d_in[0];
    const int*   ei     = (const int*)  d_in[1];
    const float* W_init = (const float*)d_in[2];
    const float* b_init = (const float*)d_in[3];
    const float* g1W = (const float*)d_in[4];
    const float* g1b = (const float*)d_in[5];
    const float* g2W = (const float*)d_in[6];
    const float* g2b = (const float*)d_in[7];
    const float* inW = (const float*)d_in[8];
    const float* cW  = (const float*)d_in[9];
    const float* cb  = (const float*)d_in[10];
    const float* xpW = (const float*)d_in[11];
    const float* dtW = (const float*)d_in[12];
    const float* dtb = (const float*)d_in[13];
    const float* Alog= (const float*)d_in[14];
    const float* Dp  = (const float*)d_in[15];
    const float* outW= (const float*)d_in[16];
    const float* Wq  = (const float*)d_in[17];
    const float* bq  = (const float*)d_in[18];
    const float* Wk  = (const float*)d_in[19];
    const float* bk  = (const float*)d_in[20];
    const float* Wv  = (const float*)d_in[21];
    const float* bv  = (const float*)d_in[22];
    const float* Wo  = (const float*)d_in[23];
    const float* bo  = (const float*)d_in[24];
    const float* fusW= (const float*)d_in[25];
    const float* fusb= (const float*)d_in[26];
    const float* lng = (const float*)d_in[27];
    const float* lnb = (const float*)d_in[28];
    const float* cwp = (const float*)d_in[29];
    const float* cbp = (const float*)d_in[30];
    const float* hwp = (const float*)d_in[31];
    const float* hbp = (const float*)d_in[32];
    const float* twp = (const float*)d_in[33];
    const float* tbp = (const float*)d_in[34];
    const float* p1w = (const float*)d_in[35];
    const float* p1b = (const float*)d_in[36];
    const float* p2w = (const float*)d_in[37];
    const float* p2b = (const float*)d_in[38];
    const float* dwp = (const float*)d_in[39];
    const float* dbp = (const float*)d_in[40];
    const float* swp = (const float*)d_in[41];
    const float* sbp = (const float*)d_in[42];

    float* fw = (float*)d_ws;
    int* iw = (int*)(fw + O_INT);
    int* indeg = iw;
    int* row_start = iw + 4096;
    int* cursor = iw + 8193;
    int* csr = iw + 12289;
    float* dinv = fw + O_DINV;

    // bf16 regions
    hbf* wt   = (hbf*)(fw + O_WT);
    hbf* xb   = (hbf*)(fw + O_XB);
    hbf* h0b  = (hbf*)(fw + O_H0B);
    hbf* h2b  = (hbf*)(fw + O_H2B);
    hbf* xcb  = (hbf*)(fw + O_XCB);
    hbf* dtab = (hbf*)(fw + O_DTAB);
    hbf* yb   = (hbf*)(fw + O_HF);
    hbf* aob  = (hbf*)(fw + O_DELTA);
    hbf* catb = (hbf*)(fw + O_XZ + 1048576);
    hbf* qbB  = (hbf*)(fw + O_H1);     // h1 fp32 dead after cast
    hbf* kbB  = (hbf*)(fw + O_XZ);     // xz dead after scan3
    hbf* vtB  = (hbf*)(fw + O_XC);     // xc dead after scan3; fused written after attn
    float* fused = fw + O_XC;
    float* hf = fw + O_HF;

    hbf* WtInit = wt + 0;
    hbf* WtG1   = wt + 8192;
    hbf* WtG2   = wt + 73728;
    hbf* WtIn   = wt + 139264;
    hbf* WtXp   = wt + 401408;
    hbf* WtDt   = wt + 417792;
    hbf* WtOut  = wt + 434176;
    hbf* WtQ    = wt + 565248;
    hbf* WtK    = wt + 630784;
    hbf* WtV    = wt + 696320;
    hbf* WtO    = wt + 761856;
    hbf* WtFus  = wt + 827392;

    WSrc wsrc;
    wsrc.p[0]=W_init; wsrc.p[1]=g1W; wsrc.p[2]=g2W; wsrc.p[3]=inW; wsrc.p[4]=xpW;
    wsrc.p[5]=dtW; wsrc.p[6]=outW; wsrc.p[7]=Wq; wsrc.p[8]=Wk; wsrc.p[9]=Wv;
    wsrc.p[10]=Wo; wsrc.p[11]=fusW;
    wcast_k<<<4000,256,0,stream>>>(wsrc, wt);
    cast_k<<<512,256,0,stream>>>(x, xb, 131072);

    // graph prep
    zero_k<<<16,256,0,stream>>>(indeg);
    count_k<<<256,256,0,stream>>>(ei, indeg);
    prefix_k<<<1,1024,0,stream>>>(indeg, row_start, cursor);
    scatter_k<<<256,256,0,stream>>>(ei, cursor, csr);
    dinv_k<<<16,256,0,stream>>>(indeg, dinv);

    // h0 = relu(x @ W_init + b_init)  -> bf16
    mg_k<1,1><<<dim3(64,4),256,0,stream>>>((const unsigned short*)xb, (const unsigned short*)WtInit,
        b_init, h0b, 256, nullptr, 0, NL, 32, 256);
    // gcn1
    mg_k<0,0><<<dim3(64,4),256,0,stream>>>((const unsigned short*)h0b, (const unsigned short*)WtG1,
        nullptr, fw+O_MBUF, 256, nullptr, 0, NL, 256, 256);
    gather_k<<<4096,256,0,stream>>>(fw+O_MBUF, csr, row_start, dinv, g1b, fw+O_H1);
    cast_k<<<4096,256,0,stream>>>(fw+O_H1, h0b, 1048576);
    // gcn2
    mg_k<0,0><<<dim3(64,4),256,0,stream>>>((const unsigned short*)h0b, (const unsigned short*)WtG2,
        nullptr, fw+O_MBUF, 256, nullptr, 0, NL, 256, 256);
    gather_k<<<4096,256,0,stream>>>(fw+O_MBUF, csr, row_start, dinv, g2b, fw+O_H2);
    cast_k<<<4096,256,0,stream>>>(fw+O_H2, h2b, 1048576);

    // mamba
    mg_k<0,0><<<dim3(64,16),256,0,stream>>>((const unsigned short*)h2b, (const unsigned short*)WtIn,
        nullptr, fw+O_XZ, 1024, nullptr, 0, NL, 256, 1024);
    conv_k<<<8192,256,0,stream>>>(fw+O_XZ, cW, cb, fw+O_XC);
    cast_k<<<8192,256,0,stream>>>(fw+O_XC, xcb, 2097152);
    mg_k<0,0><<<dim3(64,1),256,0,stream>>>((const unsigned short*)xcb, (const unsigned short*)WtXp,
        nullptr, fw+O_PROJ, 32, nullptr, 0, NL, 512, 32);
    cast_pad_k<<<512,256,0,stream>>>(fw+O_PROJ, dtab);
    mg_k<2,0><<<dim3(64,8),256,0,stream>>>((const unsigned short*)dtab, (const unsigned short*)WtDt,
        dtb, fw+O_DELTA, 512, nullptr, 0, NL, 32, 512);
    scan1_k<<<128,256,0,stream>>>(fw+O_DELTA, fw+O_XC, fw+O_PROJ, Alog, fw+O_P, fw+O_HL);
    scan2_k<<<16,256,0,stream>>>(fw+O_P, fw+O_HL, fw+O_HST);
    scan3_k<<<128,256,0,stream>>>(fw+O_DELTA, fw+O_XC, fw+O_PROJ, Alog, fw+O_HST, Dp, fw+O_XZ, yb);
    mg_k<0,1><<<dim3(64,4),256,0,stream>>>((const unsigned short*)yb, (const unsigned short*)WtOut,
        nullptr, catb + 256, 768, nullptr, 0, NL, 512, 256);

    // attention: Q,K bf16 normal; V bf16 transposed [256][NL]
    mg_k<0,1><<<dim3(64,4),256,0,stream>>>((const unsigned short*)h2b, (const unsigned short*)WtQ,
        bq, qbB, 256, nullptr, 0, NL, 256, 256);
    mg_k<0,1><<<dim3(64,4),256,0,stream>>>((const unsigned short*)h2b, (const unsigned short*)WtK,
        bk, kbB, 256, nullptr, 0, NL, 256, 256);
    mg_k<0,2><<<dim3(64,4),256,0,stream>>>((const unsigned short*)h2b, (const unsigned short*)WtV,
        bv, vtB, NL, nullptr, 0, NL, 256, 256);
    attn_k<<<dim3(64,4),256,0,stream>>>((const unsigned short*)qbB, (const unsigned short*)kbB,
        (const unsigned short*)vtB, aob);
    mg_k<0,1><<<dim3(64,4),256,0,stream>>>((const unsigned short*)aob, (const unsigned short*)WtO,
        bo, catb + 512, 768, nullptr, 0, NL, 256, 256);

    // fuse + residual + LN + pool + heads
    pack_k<<<4096,256,0,stream>>>(fw+O_H2, catb);
    mg_k<1,0><<<dim3(64,4),256,0,stream>>>((const unsigned short*)catb, (const unsigned short*)WtFus,
        fusb, fused, 256, fw+O_H2, 256, NL, 768, 256);
    ln_k<<<4096,256,0,stream>>>(fused, lng, lnb, hf);
    pool_k<<<8,256,0,stream>>>(hf, fw+O_POOL);
    heads_k<<<(NOUT+255)/256,256,0,stream>>>(fw+O_POOL, cwp,cbp,hwp,hbp,twp,tbp,p1w,p1b,p2w,p2b,
                                             dwp,dbp,swp,sbp, (float*)d_out);
}

// Round 8
// 503.650 us; speedup vs baseline: 4.2140x; 1.1690x over previous
//
#include <hip/hip_runtime.h>
#include <hip/hip_bf16.h>
#include <math.h>

typedef __hip_bfloat16 hbf;
typedef short bf16x8 __attribute__((ext_vector_type(8)));
typedef float f32x4 __attribute__((ext_vector_type(4)));

// ---------------- problem constants ----------------
constexpr int NL  = 4096;
constexpr int HH  = 256;
constexpr int NE  = 8192;
constexpr int DIc = 512;
constexpr int DSc = 8;
constexpr int NCH = 64;
constexpr int CLc = 64;
constexpr int NOUT = 12416;

// ---------------- workspace layout (float offsets) ----------------
constexpr size_t O_MBUF  = 0;          // 1048576  gcn msgs; attn partial c0
constexpr size_t O_H1    = 1048576;    // 1048576  qB(bf16)
constexpr size_t O_H2    = 2097152;    // 1048576  h2 fp32 (live to fus resid)
constexpr size_t O_XZ    = 3145728;    // 4194304  xz; later kB(bf16)@+0, catb(bf16)@+1048576
constexpr size_t O_XC    = 7340032;    // 2097152  xc; later vtB(bf16)@+0, partial c3@+524288, fused@+0
constexpr size_t O_DELTA = 9437184;    // 2097152  delta; later aob(bf16)@+0, partial c2@+524288
constexpr size_t O_PROJ  = 11534336;   // 131072
constexpr size_t O_P     = 11665408;   // 262144   scan P; later attn ml (131072)
constexpr size_t O_HL    = 11927552;   // 262144
constexpr size_t O_HST   = 12189696;   // 262144
constexpr size_t O_HF    = 12451840;   // 1048576  yb(bf16) early; attn partial c1; hf later
constexpr size_t O_POOL  = 13500416;   // 2048
constexpr size_t O_DINV  = 13502464;   // 4096
constexpr size_t O_INT   = 13506560;   // 81928 ints
constexpr size_t O_WT    = 13588496;   // transposed bf16 weights
constexpr size_t O_XB    = 14100496;
constexpr size_t O_H0B   = 14166032;   // h0 bf16; later h1b
constexpr size_t O_H2B   = 14690320;
constexpr size_t O_XCB   = 15214608;
constexpr size_t O_DTAB  = 16263184;

// ---------------- weight transpose-cast table ----------------
constexpr int NW = 12;
__device__ __constant__ int wc_cum[NW+1] = {
    0, 8192, 73728, 139264, 401408, 417792, 434176, 565248,
    630784, 696320, 761856, 827392, 1024000 };
__device__ __constant__ int wc_K [NW] = {32,256,256,256,512,16,512,256,256,256,256,768};
__device__ __constant__ int wc_N [NW] = {256,256,256,1024,32,512,256,256,256,256,256,256};
__device__ __constant__ int wc_Kp[NW] = {32,256,256,256,512,32,512,256,256,256,256,768};
struct WSrc { const float* p[NW]; };
struct OPtrs { float* p[4]; };

__global__ __launch_bounds__(256) void wcast_k(WSrc ws, hbf* __restrict__ dst) {
    int idx = blockIdx.x*256 + threadIdx.x;
    if (idx >= 1024000) return;
    int lo = 0, hi = NW-1;
    while (lo < hi) { int mid = (lo+hi+1)>>1; if (idx >= wc_cum[mid]) lo = mid; else hi = mid-1; }
    int local = idx - wc_cum[lo];
    int Kp = wc_Kp[lo], K = wc_K[lo], N = wc_N[lo];
    int n = local / Kp, k = local - n*Kp;
    float v = (k < K) ? ws.p[lo][(size_t)k*N + n] : 0.0f;
    dst[idx] = __float2bfloat16(v);
}

__global__ void cast_k(const float* __restrict__ s, hbf* __restrict__ d, int n) {
    int i = blockIdx.x*256 + threadIdx.x;
    if (i < n) d[i] = __float2bfloat16(s[i]);
}

__global__ void cast_pad_k(const float* __restrict__ proj, hbf* __restrict__ d) {
    int i = blockIdx.x*256 + threadIdx.x;
    int r = i >> 5, k = i & 31;
    d[i] = __float2bfloat16((k < 16) ? proj[r*32 + k] : 0.0f);
}

// ---------------- graph prep ----------------
__global__ void zero_k(int* __restrict__ p) { p[blockIdx.x*256 + threadIdx.x] = 0; }

__global__ void count_k(const int* __restrict__ ei, int* __restrict__ indeg) {
    int i = blockIdx.x*256 + threadIdx.x;
    int b = i >> 13, e = i & 8191;
    int dst = ei[b*2*NE + NE + e] + (b << 9);
    atomicAdd(&indeg[dst], 1);
}

__global__ __launch_bounds__(1024) void prefix_k(const int* __restrict__ indeg,
                                                 int* __restrict__ row_start,
                                                 int* __restrict__ cursor) {
    __shared__ int part[1024];
    int t = threadIdx.x;
    int v0[4]; int s = 0;
    #pragma unroll
    for (int i = 0; i < 4; i++) { v0[i] = s; s += indeg[t*4 + i]; }
    part[t] = s;
    __syncthreads();
    for (int o = 1; o < 1024; o <<= 1) {
        int x = (t >= o) ? part[t-o] : 0;
        __syncthreads();
        part[t] += x;
        __syncthreads();
    }
    int base = (t > 0) ? part[t-1] : 0;
    #pragma unroll
    for (int i = 0; i < 4; i++) {
        int rs = base + v0[i];
        row_start[t*4+i] = rs; cursor[t*4+i] = rs;
    }
    if (t == 1023) row_start[4096] = part[1023];
}

__global__ void scatter_k(const int* __restrict__ ei, int* __restrict__ cursor,
                          int* __restrict__ csr) {
    int i = blockIdx.x*256 + threadIdx.x;
    int b = i >> 13, e = i & 8191;
    int src = ei[b*2*NE + e]       + (b << 9);
    int dst = ei[b*2*NE + NE + e]  + (b << 9);
    int pos = atomicAdd(&cursor[dst], 1);
    csr[pos] = src;
}

__global__ void dinv_k(const int* __restrict__ indeg, float* __restrict__ dinv) {
    int i = blockIdx.x*256 + threadIdx.x;
    dinv[i] = rsqrtf(1.0f + (float)indeg[i]);
}

// gather with fused bf16 output; WF32 selects extra fp32 output
template<int WF32>
__global__ __launch_bounds__(256) void gather_k(const float* __restrict__ m,
                        const int* __restrict__ csr, const int* __restrict__ row_start,
                        const float* __restrict__ dinv, const float* __restrict__ bias,
                        float* __restrict__ out, hbf* __restrict__ outb) {
    int n = blockIdx.x, c = threadIdx.x;
    float dn = dinv[n];
    float acc = m[(size_t)n*HH + c] * dn * dn;
    int e0 = row_start[n], e1 = row_start[n+1];
    for (int e = e0; e < e1; e++) {
        int s = csr[e];
        acc += m[(size_t)s*HH + c] * (dinv[s] * dn);
    }
    float r = fmaxf(acc + bias[c], 0.0f);
    if (WF32) out[(size_t)n*HH + c] = r;
    outb[(size_t)n*HH + c] = __float2bfloat16(r);
}

// ---------------- bf16 MFMA GEMM ----------------
// OUTM: 0 = fp32, 1 = bf16, 2 = bf16 transposed C[col*ldc+row] (coalesced via LDS)
template<int ACT, int OUTM>
__global__ __launch_bounds__(256) void mg_k(const unsigned short* __restrict__ A,
        const unsigned short* __restrict__ Bt, const float* __restrict__ bias,
        void* __restrict__ Cp, int ldc, const float* __restrict__ resid, int ldr,
        int M, int K, int N)
{
    __shared__ __align__(16) unsigned short Asm[64][40];
    __shared__ __align__(16) unsigned short Bsm[64][40];
    int t = threadIdx.x;
    int lane = t & 63, w = t >> 6;
    int wm = w & 1, wn = w >> 1;
    int row0 = blockIdx.x * 64, col0 = blockIdx.y * 64;
    int sr = t >> 2;
    int sk = (t & 3) * 8;
    f32x4 acc[2][2] = {};

    int fr = lane & 15, fq = (lane >> 4) * 8;
    for (int k0 = 0; k0 < K; k0 += 32) {
        __syncthreads();
        *(uint4*)&Asm[sr][sk] = *(const uint4*)&A[(size_t)(row0 + sr)*K + k0 + sk];
        uint4 bv = make_uint4(0u,0u,0u,0u);
        int bn = col0 + sr;
        if (bn < N) bv = *(const uint4*)&Bt[(size_t)bn*K + k0 + sk];
        *(uint4*)&Bsm[sr][sk] = bv;
        __syncthreads();
        bf16x8 a0 = *(bf16x8*)&Asm[wm*32 + fr][fq];
        bf16x8 a1 = *(bf16x8*)&Asm[wm*32 + 16 + fr][fq];
        bf16x8 b0 = *(bf16x8*)&Bsm[wn*32 + fr][fq];
        bf16x8 b1 = *(bf16x8*)&Bsm[wn*32 + 16 + fr][fq];
        acc[0][0] = __builtin_amdgcn_mfma_f32_16x16x32_bf16(a0, b0, acc[0][0], 0, 0, 0);
        acc[0][1] = __builtin_amdgcn_mfma_f32_16x16x32_bf16(a0, b1, acc[0][1], 0, 0, 0);
        acc[1][0] = __builtin_amdgcn_mfma_f32_16x16x32_bf16(a1, b0, acc[1][0], 0, 0, 0);
        acc[1][1] = __builtin_amdgcn_mfma_f32_16x16x32_bf16(a1, b1, acc[1][1], 0, 0, 0);
    }

    int fc = lane & 15, frq = (lane >> 4) * 4;
    if constexpr (OUTM == 2) {
        __shared__ __align__(16) unsigned short Ts[64][72];
        #pragma unroll
        for (int mt = 0; mt < 2; mt++)
            #pragma unroll
            for (int nt = 0; nt < 2; nt++) {
                int col = col0 + wn*32 + nt*16 + fc;
                float bvv = bias ? bias[col] : 0.0f;
                #pragma unroll
                for (int i = 0; i < 4; i++) {
                    float v = acc[mt][nt][i] + bvv;
                    *(hbf*)&Ts[wn*32 + nt*16 + fc][wm*32 + mt*16 + frq + i] = __float2bfloat16(v);
                }
            }
        __syncthreads();
        int c = t >> 2, rs = (t & 3) * 16;
        if (col0 + c < N) {
            hbf* outp = (hbf*)Cp + (size_t)(col0 + c)*ldc + row0 + rs;
            *(uint4*)outp       = *(uint4*)&Ts[c][rs];
            *(uint4*)(outp + 8) = *(uint4*)&Ts[c][rs + 8];
        }
    } else {
        #pragma unroll
        for (int mt = 0; mt < 2; mt++) {
            #pragma unroll
            for (int nt = 0; nt < 2; nt++) {
                int col = col0 + wn*32 + nt*16 + fc;
                if (col >= N) continue;
                float bvv = bias ? bias[col] : 0.0f;
                #pragma unroll
                for (int i = 0; i < 4; i++) {
                    int row = row0 + wm*32 + mt*16 + frq + i;
                    float v = acc[mt][nt][i] + bvv;
                    if (ACT == 1) v = fmaxf(v, 0.0f);
                    if (ACT == 2) v = (v > 20.0f) ? v : log1pf(expf(v));
                    if (resid) v += resid[(size_t)row*ldr + col];
                    if (OUTM == 0) ((float*)Cp)[(size_t)row*ldc + col] = v;
                    else           ((hbf*)Cp)[(size_t)row*ldc + col] = __float2bfloat16(v);
                }
            }
        }
    }
}

// ---------------- mamba: conv + silu (fused bf16 out) ----------------
__global__ void conv_k(const float* __restrict__ xz, const float* __restrict__ cW,
                       const float* __restrict__ cb, float* __restrict__ xc2,
                       hbf* __restrict__ xcb) {
    int i = blockIdx.x*256 + threadIdx.x;
    int l = i >> 9, d = i & 511;
    float acc = cb[d];
    #pragma unroll
    for (int k = 0; k < 4; k++) {
        int ls = l - 3 + k;
        if (ls >= 0) acc += xz[(size_t)ls*1024 + d] * cW[d*4 + k];
    }
    float r = acc / (1.0f + __expf(-acc));
    xc2[i] = r;
    xcb[i] = __float2bfloat16(r);
}

// ---------------- mamba chunked scan ----------------
__global__ __launch_bounds__(256) void scan1_k(const float* __restrict__ delta,
                        const float* __restrict__ xc, const float* __restrict__ proj,
                        const float* __restrict__ Alog,
                        float* __restrict__ P, float* __restrict__ Hl)
{
    int c = blockIdx.x >> 1;
    int d = ((blockIdx.x & 1) << 8) + threadIdx.x;
    float Ac[DSc], pr[DSc], h[DSc];
    #pragma unroll
    for (int s2 = 0; s2 < DSc; s2++) { Ac[s2] = -__expf(Alog[d*DSc+s2]); pr[s2]=1.0f; h[s2]=0.0f; }
    int l0 = c << 6;
    for (int l = l0; l < l0 + CLc; l++) {
        float dl = delta[(size_t)l*DIc + d];
        float dx = dl * xc[(size_t)l*DIc + d];
        const float* pb = proj + l*32 + 16;
        #pragma unroll
        for (int s2 = 0; s2 < DSc; s2++) {
            float a = __expf(dl * Ac[s2]);
            h[s2] = a*h[s2] + dx*pb[s2];
            pr[s2] *= a;
        }
    }
    #pragma unroll
    for (int s2 = 0; s2 < DSc; s2++) {
        P [(size_t)(c*DSc+s2)*DIc + d] = pr[s2];
        Hl[(size_t)(c*DSc+s2)*DIc + d] = h[s2];
    }
}

__global__ void scan2_k(const float* __restrict__ P, const float* __restrict__ Hl,
                        float* __restrict__ Hst) {
    int tg = blockIdx.x*256 + threadIdx.x;
    float hcur = 0.0f;
    for (int c = 0; c < NCH; c++) {
        size_t off = (size_t)c*4096 + tg;
        Hst[off] = hcur;
        hcur = Hl[off] + P[off]*hcur;
    }
}

__global__ __launch_bounds__(256) void scan3_k(const float* __restrict__ delta,
                        const float* __restrict__ xc, const float* __restrict__ proj,
                        const float* __restrict__ Alog, const float* __restrict__ Hst,
                        const float* __restrict__ Dp, const float* __restrict__ xz,
                        hbf* __restrict__ Y)
{
    int c = blockIdx.x >> 1;
    int d = ((blockIdx.x & 1) << 8) + threadIdx.x;
    float Ac[DSc], h[DSc];
    #pragma unroll
    for (int s2 = 0; s2 < DSc; s2++) {
        Ac[s2] = -__expf(Alog[d*DSc+s2]);
        h[s2]  = Hst[(size_t)(c*DSc+s2)*DIc + d];
    }
    float dpv = Dp[d];
    int l0 = c << 6;
    for (int l = l0; l < l0 + CLc; l++) {
        float dl = delta[(size_t)l*DIc + d];
        float xv = xc[(size_t)l*DIc + d];
        float dx = dl * xv;
        const float* pb = proj + l*32 + 16;
        float y = 0.0f;
        #pragma unroll
        for (int s2 = 0; s2 < DSc; s2++) {
            float a = __expf(dl * Ac[s2]);
            h[s2] = a*h[s2] + dx*pb[s2];
            y += h[s2] * pb[8+s2];
        }
        float z = xz[(size_t)l*1024 + 512 + d];
        float sz = z / (1.0f + __expf(-z));
        Y[(size_t)l*DIc + d] = __float2bfloat16((y + dpv*xv) * sz);
    }
}

// ---------------- split-K MFMA flash attention ----------------
// grid (NL/64, 4, 4). Partial chunk skc processes keys [skc*1024, skc*1024+1024).
// Writes unnormalized O (fp32) to op.p[skc] and per-row (m,l) to ml.
__global__ __launch_bounds__(256) void attn_part_k(const unsigned short* __restrict__ Q,
                       const unsigned short* __restrict__ K,
                       const unsigned short* __restrict__ Vt,
                       OPtrs op, float* __restrict__ ml)
{
    __shared__ __align__(16) unsigned short Qs[64][72];
    __shared__ __align__(16) unsigned short Ks[64][72];
    __shared__ __align__(16) unsigned short Vs[64][72];
    __shared__ __align__(16) unsigned short Ps[64][72];
    __shared__ float mrow[64], lrow[64];
    int t = threadIdx.x, lane = t & 63, w = t >> 6;
    int h = blockIdx.y, q0 = blockIdx.x * 64, skc = blockIdx.z;
    int sr = t >> 2, sk = (t & 3) * 16;
    int fm = lane & 15, fq = lane >> 4;

    *(uint4*)&Qs[sr][sk]     = *(const uint4*)&Q[(size_t)(q0+sr)*HH + h*64 + sk];
    *(uint4*)&Qs[sr][sk + 8] = *(const uint4*)&Q[(size_t)(q0+sr)*HH + h*64 + sk + 8];
    if (t < 64) { mrow[t] = -1e30f; lrow[t] = 0.0f; }

    f32x4 o[4] = {};
    int kbeg = skc * 1024, kend = kbeg + 1024;
    for (int kt = kbeg; kt < kend; kt += 64) {
        __syncthreads();
        *(uint4*)&Ks[sr][sk]     = *(const uint4*)&K[(size_t)(kt+sr)*HH + h*64 + sk];
        *(uint4*)&Ks[sr][sk + 8] = *(const uint4*)&K[(size_t)(kt+sr)*HH + h*64 + sk + 8];
        *(uint4*)&Vs[sr][sk]     = *(const uint4*)&Vt[(size_t)(h*64+sr)*NL + kt + sk];
        *(uint4*)&Vs[sr][sk + 8] = *(const uint4*)&Vt[(size_t)(h*64+sr)*NL + kt + sk + 8];
        __syncthreads();

        f32x4 s[4] = {};
        #pragma unroll
        for (int ks = 0; ks < 2; ks++) {
            bf16x8 a = *(bf16x8*)&Qs[w*16 + fm][ks*32 + fq*8];
            #pragma unroll
            for (int nt = 0; nt < 4; nt++) {
                bf16x8 b = *(bf16x8*)&Ks[nt*16 + fm][ks*32 + fq*8];
                s[nt] = __builtin_amdgcn_mfma_f32_16x16x32_bf16(a, b, s[nt], 0, 0, 0);
            }
        }
        #pragma unroll
        for (int i = 0; i < 4; i++) {
            int row = w*16 + fq*4 + i;
            float s0 = s[0][i]*0.125f, s1 = s[1][i]*0.125f,
                  s2 = s[2][i]*0.125f, s3 = s[3][i]*0.125f;
            float mx = fmaxf(fmaxf(s0, s1), fmaxf(s2, s3));
            #pragma unroll
            for (int off = 1; off < 16; off <<= 1) mx = fmaxf(mx, __shfl_xor(mx, off));
            float mold = mrow[row];
            float mnew = fmaxf(mold, mx);
            float alpha = __expf(mold - mnew);
            float p0 = __expf(s0 - mnew), p1 = __expf(s1 - mnew),
                  p2 = __expf(s2 - mnew), p3 = __expf(s3 - mnew);
            float ps = p0 + p1 + p2 + p3;
            #pragma unroll
            for (int off = 1; off < 16; off <<= 1) ps += __shfl_xor(ps, off);
            if (fm == 0) { lrow[row] = lrow[row]*alpha + ps; mrow[row] = mnew; }
            o[0][i] *= alpha; o[1][i] *= alpha; o[2][i] *= alpha; o[3][i] *= alpha;
            *(hbf*)&Ps[row][ 0 + fm] = __float2bfloat16(p0);
            *(hbf*)&Ps[row][16 + fm] = __float2bfloat16(p1);
            *(hbf*)&Ps[row][32 + fm] = __float2bfloat16(p2);
            *(hbf*)&Ps[row][48 + fm] = __float2bfloat16(p3);
        }
        #pragma unroll
        for (int ks = 0; ks < 2; ks++) {
            bf16x8 a = *(bf16x8*)&Ps[w*16 + fm][ks*32 + fq*8];
            #pragma unroll
            for (int nt = 0; nt < 4; nt++) {
                bf16x8 b = *(bf16x8*)&Vs[nt*16 + fm][ks*32 + fq*8];
                o[nt] = __builtin_amdgcn_mfma_f32_16x16x32_bf16(a, b, o[nt], 0, 0, 0);
            }
        }
    }
    float* Op = op.p[skc];
    #pragma unroll
    for (int i = 0; i < 4; i++) {
        int row = w*16 + fq*4 + i;
        #pragma unroll
        for (int nt = 0; nt < 4; nt++)
            Op[(size_t)(q0 + row)*HH + h*64 + nt*16 + fm] = o[nt][i];
    }
    __syncthreads();
    if (t < 64) {
        int grow = q0 + t;
        size_t base = ((size_t)(skc*NL + grow)*4 + h)*2;
        ml[base]     = mrow[t];
        ml[base + 1] = lrow[t];
    }
}

// exact split-softmax merge: O = sum_c Oc*e^{mc-M} / sum_c lc*e^{mc-M}
__global__ __launch_bounds__(256) void amerge_k(OPtrs op, const float* __restrict__ ml,
                                                hbf* __restrict__ aob) {
    int row = blockIdx.x, t = threadIdx.x, h = t >> 6;
    float m[4], l[4];
    #pragma unroll
    for (int c = 0; c < 4; c++) {
        size_t base = ((size_t)(c*NL + row)*4 + h)*2;
        m[c] = ml[base]; l[c] = ml[base + 1];
    }
    float M = fmaxf(fmaxf(m[0], m[1]), fmaxf(m[2], m[3]));
    float L = 0.0f, s = 0.0f;
    #pragma unroll
    for (int c = 0; c < 4; c++) {
        float e = __expf(m[c] - M);
        L += l[c] * e;
        s += op.p[c][(size_t)row*HH + t] * e;
    }
    aob[(size_t)row*HH + t] = __float2bfloat16(s / L);
}

// ---------------- pack h (fp32) into catb cols 0..255 (bf16) ----------------
__global__ void pack_k(const float* __restrict__ h2, hbf* __restrict__ cat) {
    int i = blockIdx.x*256 + threadIdx.x;
    int r = i >> 8, c = i & 255;
    cat[(size_t)r*768 + c] = __float2bfloat16(h2[i]);
}

// ---------------- layernorm ----------------
__global__ __launch_bounds__(256) void ln_k(const float* __restrict__ X,
                    const float* __restrict__ g, const float* __restrict__ b,
                    float* __restrict__ Y) {
    __shared__ float red[4];
    int r = blockIdx.x, t = threadIdx.x;
    float v = X[(size_t)r*HH + t];
    float s = v;
    #pragma unroll
    for (int o = 32; o > 0; o >>= 1) s += __shfl_down(s, o);
    if ((t & 63) == 0) red[t >> 6] = s;
    __syncthreads();
    float mean = (red[0]+red[1]+red[2]+red[3]) * (1.0f/256.0f);
    float dfv = v - mean;
    float s2 = dfv*dfv;
    #pragma unroll
    for (int o = 32; o > 0; o >>= 1) s2 += __shfl_down(s2, o);
    __syncthreads();
    if ((t & 63) == 0) red[t >> 6] = s2;
    __syncthreads();
    float var = (red[0]+red[1]+red[2]+red[3]) * (1.0f/256.0f);
    Y[(size_t)r*HH + t] = dfv * rsqrtf(var + 1e-5f) * g[t] + b[t];
}

// ---------------- pool ----------------
__global__ void pool_k(const float* __restrict__ hf, float* __restrict__ pooled) {
    int b = blockIdx.x, t = threadIdx.x;
    float s = 0.0f;
    #pragma unroll 8
    for (int i = 0; i < 512; i++) s += hf[(size_t)((b<<9)+i)*HH + t];
    pooled[b*HH + t] = s * (1.0f/512.0f);
}

// ---------------- heads ----------------
__global__ __launch_bounds__(256) void heads_k(const float* __restrict__ pooled,
        const float* cw, const float* cbh, const float* hw, const float* hb,
        const float* tw, const float* tb, const float* p1w, const float* p1b,
        const float* p2w, const float* p2b, const float* dw, const float* db,
        const float* sw, const float* sb, float* __restrict__ out)
{
    int idx = blockIdx.x*256 + threadIdx.x;
    if (idx >= NOUT) return;
    int b = idx / 1552, j = idx - b*1552;
    const float* w; const float* bi; int col, nc;
    if (j < 1)         { w = cw;  bi = cbh; col = j;        nc = 1;   }
    else if (j < 5)    { w = hw;  bi = hb;  col = j - 1;    nc = 4;   }
    else if (j < 8)    { w = tw;  bi = tb;  col = j - 5;    nc = 3;   }
    else if (j < 520)  { w = p1w; bi = p1b; col = j - 8;    nc = 512; }
    else if (j < 1032) { w = p2w; bi = p2b; col = j - 520;  nc = 512; }
    else if (j < 1544) { w = dw;  bi = db;  col = j - 1032; nc = 512; }
    else               { w = sw;  bi = sb;  col = j - 1544; nc = 8;   }
    float s = bi[col];
    const float* pl = pooled + b*HH;
    #pragma unroll 4
    for (int k = 0; k < 256; k++) s = fmaf(pl[k], w[k*nc + col], s);
    out[idx] = s;
}

// ---------------- launcher ----------------
extern "C" void kernel_launch(void* const* d_in, const int* in_sizes, int n_in,
                              void* d_out, int out_size, void* d_ws, size_t ws_size,
                              hipStream_t stream)
{
    (void)in_sizes; (void)n_in; (void)out_size; (void)ws_size;
    const float* x      = (const float*)d_in[0];
    const int*   ei     = (const int*)  d_in[1];
    const float* W_init = (const float*)d_in[2];
    const float* b_init = (const float*)d_in[3];
    const float* g1W = (const float*)d_in[4];
    const float* g1b = (const float*)d_in[5];
    const float* g2W = (const float*)d_in[6];
    const float* g2b = (const float*)d_in[7];
    const float* inW = (const float*)d_in[8];
    const float* cW  = (const float*)d_in[9];
    const float* cb  = (const float*)d_in[10];
    const float* xpW = (const float*)d_in[11];
    const float* dtW = (const float*)d_in[12];
    const float* dtb = (const float*)d_in[13];
    const float* Alog= (const float*)d_in[14];
    const float* Dp  = (const float*)d_in[15];
    const float* outW= (const float*)d_in[16];
    const float* Wq  = (const float*)d_in[17];
    const float* bq  = (const float*)d_in[18];
    const float* Wk  = (const float*)d_in[19];
    const float* bk  = (const float*)d_in[20];
    const float* Wv  = (const float*)d_in[21];
    const float* bv  = (const float*)d_in[22];
    const float* Wo  = (const float*)d_in[23];
    const float* bo  = (const float*)d_in[24];
    const float* fusW= (const float*)d_in[25];
    const float* fusb= (const float*)d_in[26];
    const float* lng = (const float*)d_in[27];
    const float* lnb = (const float*)d_in[28];
    const float* cwp = (const float*)d_in[29];
    const float* cbp = (const float*)d_in[30];
    const float* hwp = (const float*)d_in[31];
    const float* hbp = (const float*)d_in[32];
    const float* twp = (const float*)d_in[33];
    const float* tbp = (const float*)d_in[34];
    const float* p1w = (const float*)d_in[35];
    const float* p1b = (const float*)d_in[36];
    const float* p2w = (const float*)d_in[37];
    const float* p2b = (const float*)d_in[38];
    const float* dwp = (const float*)d_in[39];
    const float* dbp = (const float*)d_in[40];
    const float* swp = (const float*)d_in[41];
    const float* sbp = (const float*)d_in[42];

    float* fw = (float*)d_ws;
    int* iw = (int*)(fw + O_INT);
    int* indeg = iw;
    int* row_start = iw + 4096;
    int* cursor = iw + 8193;
    int* csr = iw + 12289;
    float* dinv = fw + O_DINV;

    hbf* wt   = (hbf*)(fw + O_WT);
    hbf* xb   = (hbf*)(fw + O_XB);
    hbf* h0b  = (hbf*)(fw + O_H0B);
    hbf* h2b  = (hbf*)(fw + O_H2B);
    hbf* xcb  = (hbf*)(fw + O_XCB);
    hbf* dtab = (hbf*)(fw + O_DTAB);
    hbf* yb   = (hbf*)(fw + O_HF);
    hbf* aob  = (hbf*)(fw + O_DELTA);
    hbf* catb = (hbf*)(fw + O_XZ + 1048576);
    hbf* qbB  = (hbf*)(fw + O_H1);
    hbf* kbB  = (hbf*)(fw + O_XZ);
    hbf* vtB  = (hbf*)(fw + O_XC);
    float* fused = fw + O_XC;
    float* hf = fw + O_HF;

    // attention split-K partials (aliased into dead fp32 regions)
    OPtrs op;
    op.p[0] = fw + O_MBUF;
    op.p[1] = fw + O_HF;
    op.p[2] = fw + O_DELTA + 524288;
    op.p[3] = fw + O_XC + 524288;
    float* ml = fw + O_P;

    hbf* WtInit = wt + 0;
    hbf* WtG1   = wt + 8192;
    hbf* WtG2   = wt + 73728;
    hbf* WtIn   = wt + 139264;
    hbf* WtXp   = wt + 401408;
    hbf* WtDt   = wt + 417792;
    hbf* WtOut  = wt + 434176;
    hbf* WtQ    = wt + 565248;
    hbf* WtK    = wt + 630784;
    hbf* WtV    = wt + 696320;
    hbf* WtO    = wt + 761856;
    hbf* WtFus  = wt + 827392;

    WSrc wsrc;
    wsrc.p[0]=W_init; wsrc.p[1]=g1W; wsrc.p[2]=g2W; wsrc.p[3]=inW; wsrc.p[4]=xpW;
    wsrc.p[5]=dtW; wsrc.p[6]=outW; wsrc.p[7]=Wq; wsrc.p[8]=Wk; wsrc.p[9]=Wv;
    wsrc.p[10]=Wo; wsrc.p[11]=fusW;
    wcast_k<<<4000,256,0,stream>>>(wsrc, wt);
    cast_k<<<512,256,0,stream>>>(x, xb, 131072);

    // graph prep
    zero_k<<<16,256,0,stream>>>(indeg);
    count_k<<<256,256,0,stream>>>(ei, indeg);
    prefix_k<<<1,1024,0,stream>>>(indeg, row_start, cursor);
    scatter_k<<<256,256,0,stream>>>(ei, cursor, csr);
    dinv_k<<<16,256,0,stream>>>(indeg, dinv);

    // h0 = relu(x @ W_init + b_init) -> bf16
    mg_k<1,1><<<dim3(64,4),256,0,stream>>>((const unsigned short*)xb, (const unsigned short*)WtInit,
        b_init, h0b, 256, nullptr, 0, NL, 32, 256);
    // gcn1 (bf16 out only)
    mg_k<0,0><<<dim3(64,4),256,0,stream>>>((const unsigned short*)h0b, (const unsigned short*)WtG1,
        nullptr, fw+O_MBUF, 256, nullptr, 0, NL, 256, 256);
    gather_k<0><<<4096,256,0,stream>>>(fw+O_MBUF, csr, row_start, dinv, g1b, nullptr, h0b);
    // gcn2 (fp32 h2 + bf16 h2b)
    mg_k<0,0><<<dim3(64,4),256,0,stream>>>((const unsigned short*)h0b, (const unsigned short*)WtG2,
        nullptr, fw+O_MBUF, 256, nullptr, 0, NL, 256, 256);
    gather_k<1><<<4096,256,0,stream>>>(fw+O_MBUF, csr, row_start, dinv, g2b, fw+O_H2, h2b);

    // mamba
    mg_k<0,0><<<dim3(64,16),256,0,stream>>>((const unsigned short*)h2b, (const unsigned short*)WtIn,
        nullptr, fw+O_XZ, 1024, nullptr, 0, NL, 256, 1024);
    conv_k<<<8192,256,0,stream>>>(fw+O_XZ, cW, cb, fw+O_XC, xcb);
    mg_k<0,0><<<dim3(64,1),256,0,stream>>>((const unsigned short*)xcb, (const unsigned short*)WtXp,
        nullptr, fw+O_PROJ, 32, nullptr, 0, NL, 512, 32);
    cast_pad_k<<<512,256,0,stream>>>(fw+O_PROJ, dtab);
    mg_k<2,0><<<dim3(64,8),256,0,stream>>>((const unsigned short*)dtab, (const unsigned short*)WtDt,
        dtb, fw+O_DELTA, 512, nullptr, 0, NL, 32, 512);
    scan1_k<<<128,256,0,stream>>>(fw+O_DELTA, fw+O_XC, fw+O_PROJ, Alog, fw+O_P, fw+O_HL);
    scan2_k<<<16,256,0,stream>>>(fw+O_P, fw+O_HL, fw+O_HST);
    scan3_k<<<128,256,0,stream>>>(fw+O_DELTA, fw+O_XC, fw+O_PROJ, Alog, fw+O_HST, Dp, fw+O_XZ, yb);
    mg_k<0,1><<<dim3(64,4),256,0,stream>>>((const unsigned short*)yb, (const unsigned short*)WtOut,
        nullptr, catb + 256, 768, nullptr, 0, NL, 512, 256);

    // attention: Q,K bf16 normal; V bf16 transposed [256][NL] via LDS epilogue
    mg_k<0,1><<<dim3(64,4),256,0,stream>>>((const unsigned short*)h2b, (const unsigned short*)WtQ,
        bq, qbB, 256, nullptr, 0, NL, 256, 256);
    mg_k<0,1><<<dim3(64,4),256,0,stream>>>((const unsigned short*)h2b, (const unsigned short*)WtK,
        bk, kbB, 256, nullptr, 0, NL, 256, 256);
    mg_k<0,2><<<dim3(64,4),256,0,stream>>>((const unsigned short*)h2b, (const unsigned short*)WtV,
        bv, vtB, NL, nullptr, 0, NL, 256, 256);
    attn_part_k<<<dim3(64,4,4),256,0,stream>>>((const unsigned short*)qbB,
        (const unsigned short*)kbB, (const unsigned short*)vtB, op, ml);
    amerge_k<<<4096,256,0,stream>>>(op, ml, aob);
    mg_k<0,1><<<dim3(64,4),256,0,stream>>>((const unsigned short*)aob, (const unsigned short*)WtO,
        bo, catb + 512, 768, nullptr, 0, NL, 256, 256);

    // fuse + residual + LN + pool + heads
    pack_k<<<4096,256,0,stream>>>(fw+O_H2, catb);
    mg_k<1,0><<<dim3(64,4),256,0,stream>>>((const unsigned short*)catb, (const unsigned short*)WtFus,
        fusb, fused, 256, fw+O_H2, 256, NL, 768, 256);
    ln_k<<<4096,256,0,stream>>>(fused, lng, lnb, hf);
    pool_k<<<8,256,0,stream>>>(hf, fw+O_POOL);
    heads_k<<<(NOUT+255)/256,256,0,stream>>>(fw+O_POOL, cwp,cbp,hwp,hbp,twp,tbp,p1w,p1b,p2w,p2b,
                                             dwp,dbp,swp,sbp, (float*)d_out);
}

// Round 10
// 464.935 us; speedup vs baseline: 4.5649x; 1.0833x over previous
//
#include <hip/hip_runtime.h>
#include <hip/hip_bf16.h>
#include <math.h>

typedef __hip_bfloat16 hbf;
typedef short bf16x8 __attribute__((ext_vector_type(8)));
typedef float f32x4 __attribute__((ext_vector_type(4)));

// ---------------- problem constants ----------------
constexpr int NL  = 4096;
constexpr int HH  = 256;
constexpr int NE  = 8192;
constexpr int DIc = 512;
constexpr int DSc = 8;
constexpr int NCH = 64;
constexpr int CLc = 64;
constexpr int NOUT = 12416;

// ---------------- workspace layout (float offsets) ----------------
// (round-9 fix: xzb needs 2097152 floats ([4096][1024] bf16), xcb needs 1048576)
constexpr size_t O_MBUF  = 0;         // 1048576  gcn msgs; attn op0
constexpr size_t O_QK    = 1048576;   // 1048576  qkB bf16 [NL][512]
constexpr size_t O_H2    = 2097152;   // 1048576  h2 fp32 (live to fus resid)
constexpr size_t O_CATB  = 3145728;   // 1572864  catb bf16 [NL][768]
constexpr size_t O_XZB   = 4718592;   // 2097152  xzb bf16 [NL][1024]
constexpr size_t O_XC    = 6815744;   // 2097152  xc fp32; vtB@+0, op3@+524288, fused@+0
constexpr size_t O_DELTA = 8912896;   // 2097152  delta; op1@+0, op2@+1048576
constexpr size_t O_PROJ  = 11010048;  // 131072   proj fp32; lsum after
constexpr size_t O_P     = 11141120;  // 262144
constexpr size_t O_HL    = 11403264;  // 262144
constexpr size_t O_HST   = 11665408;  // 262144
constexpr size_t O_Y     = 11927552;  // 1048576  yb bf16; aob; hf
constexpr size_t O_POOL  = 12976128;  // 2048
constexpr size_t O_DINV  = 12978176;  // 4096
constexpr size_t O_B512  = 12982272;  // 512
constexpr size_t O_INT   = 12982784;  // 81928 ints
constexpr size_t O_WT    = 13064712;  // 512000
constexpr size_t O_XB    = 13576712;  // 65536
constexpr size_t O_H0B   = 13642248;  // 524288
constexpr size_t O_H2B   = 14166536;  // 524288
constexpr size_t O_XCB   = 14690824;  // 1048576  xcb bf16 [NL][512]
constexpr size_t O_DTAB  = 15739400;  // 65536
// total 15804936 floats = 63.2 MB

// ---------------- weight transpose-cast table ----------------
constexpr int NW = 12;
__device__ __constant__ int wc_cum[NW+1] = {
    0, 8192, 73728, 139264, 401408, 417792, 434176, 565248,
    630784, 696320, 761856, 827392, 1024000 };
__device__ __constant__ int wc_K [NW] = {32,256,256,256,512,16,512,256,256,256,256,768};
__device__ __constant__ int wc_N [NW] = {256,256,256,1024,32,512,256,256,256,256,256,256};
__device__ __constant__ int wc_Kp[NW] = {32,256,256,256,512,32,512,256,256,256,256,768};
struct WSrc { const float* p[NW]; };
struct OPtrs { float* p[4]; };

__global__ __launch_bounds__(256) void wcast_k(WSrc ws, hbf* __restrict__ dst) {
    int idx = blockIdx.x*256 + threadIdx.x;
    if (idx >= 1024000) return;
    int lo = 0, hi = NW-1;
    while (lo < hi) { int mid = (lo+hi+1)>>1; if (idx >= wc_cum[mid]) lo = mid; else hi = mid-1; }
    int local = idx - wc_cum[lo];
    int Kp = wc_Kp[lo], K = wc_K[lo], N = wc_N[lo];
    int n = local / Kp, k = local - n*Kp;
    float v = (k < K) ? ws.p[lo][(size_t)k*N + n] : 0.0f;
    dst[idx] = __float2bfloat16(v);
}

__global__ void cast_k(const float* __restrict__ s, hbf* __restrict__ d, int n) {
    int i = blockIdx.x*256 + threadIdx.x;
    if (i < n) d[i] = __float2bfloat16(s[i]);
}

__global__ void cast_pad_k(const float* __restrict__ proj, hbf* __restrict__ d) {
    int i = blockIdx.x*256 + threadIdx.x;
    int r = i >> 5, k = i & 31;
    d[i] = __float2bfloat16((k < 16) ? proj[r*32 + k] : 0.0f);
}

__global__ void catb2_k(const float* __restrict__ bq, const float* __restrict__ bk,
                        float* __restrict__ dst) {
    int t = blockIdx.x*256 + threadIdx.x;
    if (t < 512) dst[t] = (t < 256) ? bq[t] : bk[t-256];
}

// ---------------- graph prep ----------------
__global__ void zero_k(int* __restrict__ p) { p[blockIdx.x*256 + threadIdx.x] = 0; }

__global__ void count_k(const int* __restrict__ ei, int* __restrict__ indeg) {
    int i = blockIdx.x*256 + threadIdx.x;
    int b = i >> 13, e = i & 8191;
    int dst = ei[b*2*NE + NE + e] + (b << 9);
    atomicAdd(&indeg[dst], 1);
}

__global__ __launch_bounds__(1024) void prefix_k(const int* __restrict__ indeg,
                                                 int* __restrict__ row_start,
                                                 int* __restrict__ cursor) {
    __shared__ int part[1024];
    int t = threadIdx.x;
    int v0[4]; int s = 0;
    #pragma unroll
    for (int i = 0; i < 4; i++) { v0[i] = s; s += indeg[t*4 + i]; }
    part[t] = s;
    __syncthreads();
    for (int o = 1; o < 1024; o <<= 1) {
        int x = (t >= o) ? part[t-o] : 0;
        __syncthreads();
        part[t] += x;
        __syncthreads();
    }
    int base = (t > 0) ? part[t-1] : 0;
    #pragma unroll
    for (int i = 0; i < 4; i++) {
        int rs = base + v0[i];
        row_start[t*4+i] = rs; cursor[t*4+i] = rs;
    }
    if (t == 1023) row_start[4096] = part[1023];
}

__global__ void scatter_k(const int* __restrict__ ei, int* __restrict__ cursor,
                          int* __restrict__ csr) {
    int i = blockIdx.x*256 + threadIdx.x;
    int b = i >> 13, e = i & 8191;
    int src = ei[b*2*NE + e]       + (b << 9);
    int dst = ei[b*2*NE + NE + e]  + (b << 9);
    int pos = atomicAdd(&cursor[dst], 1);
    csr[pos] = src;
}

__global__ void dinv_k(const int* __restrict__ indeg, float* __restrict__ dinv) {
    int i = blockIdx.x*256 + threadIdx.x;
    dinv[i] = rsqrtf(1.0f + (float)indeg[i]);
}

// gather; MODE 1 adds fp32 out + catb(cols 0..255) write
template<int MODE>
__global__ __launch_bounds__(256) void gather_k(const float* __restrict__ m,
                        const int* __restrict__ csr, const int* __restrict__ row_start,
                        const float* __restrict__ dinv, const float* __restrict__ bias,
                        float* __restrict__ out, hbf* __restrict__ outb,
                        hbf* __restrict__ catb) {
    int n = blockIdx.x, c = threadIdx.x;
    float dn = dinv[n];
    float acc = m[(size_t)n*HH + c] * dn * dn;
    int e0 = row_start[n], e1 = row_start[n+1];
    for (int e = e0; e < e1; e++) {
        int s = csr[e];
        acc += m[(size_t)s*HH + c] * (dinv[s] * dn);
    }
    float r = fmaxf(acc + bias[c], 0.0f);
    if (MODE) {
        out[(size_t)n*HH + c] = r;
        catb[(size_t)n*768 + c] = __float2bfloat16(r);
    }
    outb[(size_t)n*HH + c] = __float2bfloat16(r);
}

// ---------------- bf16 MFMA GEMM ----------------
// OUTM: 0 fp32, 1 bf16, 2 bf16 transposed (via LDS)
// ACT: 0 none, 1 relu, 2 softplus, 3 scale cols<256 by 0.125 (fused QK)
template<int ACT, int OUTM>
__global__ __launch_bounds__(256) void mg_k(const unsigned short* __restrict__ A,
        const unsigned short* __restrict__ Bt, const float* __restrict__ bias,
        void* __restrict__ Cp, int ldc, const float* __restrict__ resid, int ldr,
        int M, int K, int N)
{
    __shared__ __align__(16) unsigned short Asm[64][40];
    __shared__ __align__(16) unsigned short Bsm[64][40];
    int t = threadIdx.x;
    int lane = t & 63, w = t >> 6;
    int wm = w & 1, wn = w >> 1;
    int row0 = blockIdx.x * 64, col0 = blockIdx.y * 64;
    int sr = t >> 2;
    int sk = (t & 3) * 8;
    f32x4 acc[2][2] = {};

    int fr = lane & 15, fq = (lane >> 4) * 8;
    for (int k0 = 0; k0 < K; k0 += 32) {
        __syncthreads();
        *(uint4*)&Asm[sr][sk] = *(const uint4*)&A[(size_t)(row0 + sr)*K + k0 + sk];
        uint4 bv = make_uint4(0u,0u,0u,0u);
        int bn = col0 + sr;
        if (bn < N) bv = *(const uint4*)&Bt[(size_t)bn*K + k0 + sk];
        *(uint4*)&Bsm[sr][sk] = bv;
        __syncthreads();
        bf16x8 a0 = *(bf16x8*)&Asm[wm*32 + fr][fq];
        bf16x8 a1 = *(bf16x8*)&Asm[wm*32 + 16 + fr][fq];
        bf16x8 b0 = *(bf16x8*)&Bsm[wn*32 + fr][fq];
        bf16x8 b1 = *(bf16x8*)&Bsm[wn*32 + 16 + fr][fq];
        acc[0][0] = __builtin_amdgcn_mfma_f32_16x16x32_bf16(a0, b0, acc[0][0], 0, 0, 0);
        acc[0][1] = __builtin_amdgcn_mfma_f32_16x16x32_bf16(a0, b1, acc[0][1], 0, 0, 0);
        acc[1][0] = __builtin_amdgcn_mfma_f32_16x16x32_bf16(a1, b0, acc[1][0], 0, 0, 0);
        acc[1][1] = __builtin_amdgcn_mfma_f32_16x16x32_bf16(a1, b1, acc[1][1], 0, 0, 0);
    }

    int fc = lane & 15, frq = (lane >> 4) * 4;
    if constexpr (OUTM == 2) {
        __shared__ __align__(16) unsigned short Ts[64][72];
        #pragma unroll
        for (int mt = 0; mt < 2; mt++)
            #pragma unroll
            for (int nt = 0; nt < 2; nt++) {
                int col = col0 + wn*32 + nt*16 + fc;
                float bvv = bias ? bias[col] : 0.0f;
                #pragma unroll
                for (int i = 0; i < 4; i++) {
                    float v = acc[mt][nt][i] + bvv;
                    *(hbf*)&Ts[wn*32 + nt*16 + fc][wm*32 + mt*16 + frq + i] = __float2bfloat16(v);
                }
            }
        __syncthreads();
        int c = t >> 2, rs = (t & 3) * 16;
        if (col0 + c < N) {
            hbf* outp = (hbf*)Cp + (size_t)(col0 + c)*ldc + row0 + rs;
            *(uint4*)outp       = *(uint4*)&Ts[c][rs];
            *(uint4*)(outp + 8) = *(uint4*)&Ts[c][rs + 8];
        }
    } else {
        #pragma unroll
        for (int mt = 0; mt < 2; mt++) {
            #pragma unroll
            for (int nt = 0; nt < 2; nt++) {
                int col = col0 + wn*32 + nt*16 + fc;
                if (col >= N) continue;
                float bvv = bias ? bias[col] : 0.0f;
                #pragma unroll
                for (int i = 0; i < 4; i++) {
                    int row = row0 + wm*32 + mt*16 + frq + i;
                    float v = acc[mt][nt][i] + bvv;
                    if (ACT == 1) v = fmaxf(v, 0.0f);
                    if (ACT == 2) v = (v > 20.0f) ? v : log1pf(expf(v));
                    if (ACT == 3) { if (col < 256) v *= 0.125f; }
                    if (resid) v += resid[(size_t)row*ldr + col];
                    if (OUTM == 0) ((float*)Cp)[(size_t)row*ldc + col] = v;
                    else           ((hbf*)Cp)[(size_t)row*ldc + col] = __float2bfloat16(v);
                }
            }
        }
    }
}

// ---------------- mamba: conv + silu (bf16 in, fp32+bf16 out) ----------------
__global__ void conv_k(const hbf* __restrict__ xzb, const float* __restrict__ cW,
                       const float* __restrict__ cb, float* __restrict__ xc2,
                       hbf* __restrict__ xcb) {
    int i = blockIdx.x*256 + threadIdx.x;
    int l = i >> 9, d = i & 511;
    float acc = cb[d];
    #pragma unroll
    for (int k = 0; k < 4; k++) {
        int ls = l - 3 + k;
        if (ls >= 0) acc += __bfloat162float(xzb[(size_t)ls*1024 + d]) * cW[d*4 + k];
    }
    float r = acc / (1.0f + __expf(-acc));
    xc2[i] = r;
    xcb[i] = __float2bfloat16(r);
}

// ---------------- mamba chunked scan ----------------
__global__ __launch_bounds__(256) void scan1_k(const float* __restrict__ delta,
                        const float* __restrict__ xc, const float* __restrict__ proj,
                        const float* __restrict__ Alog,
                        float* __restrict__ P, float* __restrict__ Hl)
{
    int c = blockIdx.x >> 1;
    int d = ((blockIdx.x & 1) << 8) + threadIdx.x;
    float Ac[DSc], pr[DSc], h[DSc];
    #pragma unroll
    for (int s2 = 0; s2 < DSc; s2++) { Ac[s2] = -__expf(Alog[d*DSc+s2]); pr[s2]=1.0f; h[s2]=0.0f; }
    int l0 = c << 6;
    for (int l = l0; l < l0 + CLc; l++) {
        float dl = delta[(size_t)l*DIc + d];
        float dx = dl * xc[(size_t)l*DIc + d];
        const float* pb = proj + l*32 + 16;
        #pragma unroll
        for (int s2 = 0; s2 < DSc; s2++) {
            float a = __expf(dl * Ac[s2]);
            h[s2] = a*h[s2] + dx*pb[s2];
            pr[s2] *= a;
        }
    }
    #pragma unroll
    for (int s2 = 0; s2 < DSc; s2++) {
        P [(size_t)(c*DSc+s2)*DIc + d] = pr[s2];
        Hl[(size_t)(c*DSc+s2)*DIc + d] = h[s2];
    }
}

// parallel log-scan over 64 chunks; 4 series per block, 1024 blocks
__global__ __launch_bounds__(256) void scan2p_k(const float* __restrict__ P,
                        const float* __restrict__ Hl, float* __restrict__ Hst) {
    __shared__ float Psh[4][64], Hsh[4][64];
    int t = threadIdx.x, ts = t >> 6, c = t & 63;
    int gs = blockIdx.x*4 + ts;
    size_t off = (size_t)c*4096 + gs;
    float Pc = P[off], Hc = Hl[off];
    Psh[ts][c] = Pc; Hsh[ts][c] = Hc;
    __syncthreads();
    #pragma unroll
    for (int st = 1; st < 64; st <<= 1) {
        float p1 = 1.0f, h1 = 0.0f;
        if (c >= st) { p1 = Psh[ts][c-st]; h1 = Hsh[ts][c-st]; }
        __syncthreads();
        Hc = Pc*h1 + Hc;
        Pc = Pc*p1;
        Psh[ts][c] = Pc; Hsh[ts][c] = Hc;
        __syncthreads();
    }
    Hst[off] = (c == 0) ? 0.0f : Hsh[ts][c-1];
}

__global__ __launch_bounds__(256) void scan3_k(const float* __restrict__ delta,
                        const float* __restrict__ xc, const float* __restrict__ proj,
                        const float* __restrict__ Alog, const float* __restrict__ Hst,
                        const float* __restrict__ Dp, const hbf* __restrict__ xzb,
                        hbf* __restrict__ Y)
{
    int c = blockIdx.x >> 1;
    int d = ((blockIdx.x & 1) << 8) + threadIdx.x;
    float Ac[DSc], h[DSc];
    #pragma unroll
    for (int s2 = 0; s2 < DSc; s2++) {
        Ac[s2] = -__expf(Alog[d*DSc+s2]);
        h[s2]  = Hst[(size_t)(c*DSc+s2)*DIc + d];
    }
    float dpv = Dp[d];
    int l0 = c << 6;
    for (int l = l0; l < l0 + CLc; l++) {
        float dl = delta[(size_t)l*DIc + d];
        float xv = xc[(size_t)l*DIc + d];
        float dx = dl * xv;
        const float* pb = proj + l*32 + 16;
        float y = 0.0f;
        #pragma unroll
        for (int s2 = 0; s2 < DSc; s2++) {
            float a = __expf(dl * Ac[s2]);
            h[s2] = a*h[s2] + dx*pb[s2];
            y += h[s2] * pb[8+s2];
        }
        float z = __bfloat162float(xzb[(size_t)l*1024 + 512 + d]);
        float sz = z / (1.0f + __expf(-z));
        Y[(size_t)l*DIc + d] = __float2bfloat16((y + dpv*xv) * sz);
    }
}

// ---------------- split-K MFMA flash attention, constant-shift softmax ----------------
// Q pre-scaled by 0.125 (ACT=3 in QK GEMM). p = exp(s - 4); exact up to shift.
// l accumulated via ones-fragment MFMA. No shfl, no running max.
__global__ __launch_bounds__(256) void attn_part_k(const unsigned short* __restrict__ QK,
                       const unsigned short* __restrict__ Vt,
                       OPtrs op, float* __restrict__ lsum)
{
    __shared__ __align__(16) unsigned short Qs[64][72];
    __shared__ __align__(16) unsigned short Ks[64][72];
    __shared__ __align__(16) unsigned short Vs[64][72];
    __shared__ __align__(16) unsigned short Ps[64][72];
    int t = threadIdx.x, lane = t & 63, w = t >> 6;
    int h = blockIdx.y, q0 = blockIdx.x * 64, skc = blockIdx.z;
    int sr = t >> 2, sk = (t & 3) * 16;
    int fm = lane & 15, fq = lane >> 4;

    *(uint4*)&Qs[sr][sk]     = *(const uint4*)&QK[(size_t)(q0+sr)*512 + h*64 + sk];
    *(uint4*)&Qs[sr][sk + 8] = *(const uint4*)&QK[(size_t)(q0+sr)*512 + h*64 + sk + 8];

    const unsigned short* Kb = QK + 256;
    bf16x8 ones;
    #pragma unroll
    for (int j = 0; j < 8; j++) ones[j] = (short)0x3F80;   // bf16 1.0

    f32x4 o[4] = {};
    f32x4 ol = {};
    int kt = skc * 1024;
    uint4 ka  = *(const uint4*)&Kb[(size_t)(kt+sr)*512 + h*64 + sk];
    uint4 kb2 = *(const uint4*)&Kb[(size_t)(kt+sr)*512 + h*64 + sk + 8];
    uint4 va  = *(const uint4*)&Vt[(size_t)(h*64+sr)*NL + kt + sk];
    uint4 vb2 = *(const uint4*)&Vt[(size_t)(h*64+sr)*NL + kt + sk + 8];

    for (int it = 0; it < 16; it++) {
        __syncthreads();
        *(uint4*)&Ks[sr][sk] = ka;  *(uint4*)&Ks[sr][sk+8] = kb2;
        *(uint4*)&Vs[sr][sk] = va;  *(uint4*)&Vs[sr][sk+8] = vb2;
        __syncthreads();
        if (it < 15) {
            int kn = kt + 64;
            ka  = *(const uint4*)&Kb[(size_t)(kn+sr)*512 + h*64 + sk];
            kb2 = *(const uint4*)&Kb[(size_t)(kn+sr)*512 + h*64 + sk + 8];
            va  = *(const uint4*)&Vt[(size_t)(h*64+sr)*NL + kn + sk];
            vb2 = *(const uint4*)&Vt[(size_t)(h*64+sr)*NL + kn + sk + 8];
        }
        f32x4 s[4] = {};
        #pragma unroll
        for (int ks = 0; ks < 2; ks++) {
            bf16x8 a = *(bf16x8*)&Qs[w*16 + fm][ks*32 + fq*8];
            #pragma unroll
            for (int nt = 0; nt < 4; nt++) {
                bf16x8 b = *(bf16x8*)&Ks[nt*16 + fm][ks*32 + fq*8];
                s[nt] = __builtin_amdgcn_mfma_f32_16x16x32_bf16(a, b, s[nt], 0, 0, 0);
            }
        }
        #pragma unroll
        for (int nt = 0; nt < 4; nt++) {
            #pragma unroll
            for (int i = 0; i < 4; i++) {
                float p = __expf(s[nt][i] - 4.0f);
                *(hbf*)&Ps[w*16 + fq*4 + i][nt*16 + fm] = __float2bfloat16(p);
            }
        }
        #pragma unroll
        for (int ks = 0; ks < 2; ks++) {
            bf16x8 a = *(bf16x8*)&Ps[w*16 + fm][ks*32 + fq*8];
            #pragma unroll
            for (int nt = 0; nt < 4; nt++) {
                bf16x8 b = *(bf16x8*)&Vs[nt*16 + fm][ks*32 + fq*8];
                o[nt] = __builtin_amdgcn_mfma_f32_16x16x32_bf16(a, b, o[nt], 0, 0, 0);
            }
            ol = __builtin_amdgcn_mfma_f32_16x16x32_bf16(a, ones, ol, 0, 0, 0);
        }
        kt += 64;
    }
    float* Op = op.p[skc];
    #pragma unroll
    for (int i = 0; i < 4; i++) {
        int row = w*16 + fq*4 + i;
        #pragma unroll
        for (int nt = 0; nt < 4; nt++)
            Op[(size_t)(q0 + row)*HH + h*64 + nt*16 + fm] = o[nt][i];
    }
    if (fm == 0) {
        #pragma unroll
        for (int i = 0; i < 4; i++)
            lsum[(size_t)(skc*4 + h)*NL + q0 + w*16 + fq*4 + i] = ol[i];
    }
}

// exact merge: O = sum_c Oc / sum_c lc (all chunks share the same constant shift)
__global__ __launch_bounds__(256) void amerge_k(OPtrs op, const float* __restrict__ lsum,
                                                hbf* __restrict__ aob) {
    int row = blockIdx.x, t = threadIdx.x, h = t >> 6;
    float L = 0.0f, s = 0.0f;
    #pragma unroll
    for (int c = 0; c < 4; c++) {
        L += lsum[(size_t)(c*4 + h)*NL + row];
        s += op.p[c][(size_t)row*HH + t];
    }
    aob[(size_t)row*HH + t] = __float2bfloat16(s / L);
}

// ---------------- layernorm ----------------
__global__ __launch_bounds__(256) void ln_k(const float* __restrict__ X,
                    const float* __restrict__ g, const float* __restrict__ b,
                    float* __restrict__ Y) {
    __shared__ float red[4];
    int r = blockIdx.x, t = threadIdx.x;
    float v = X[(size_t)r*HH + t];
    float s = v;
    #pragma unroll
    for (int o = 32; o > 0; o >>= 1) s += __shfl_down(s, o);
    if ((t & 63) == 0) red[t >> 6] = s;
    __syncthreads();
    float mean = (red[0]+red[1]+red[2]+red[3]) * (1.0f/256.0f);
    float dfv = v - mean;
    float s2 = dfv*dfv;
    #pragma unroll
    for (int o = 32; o > 0; o >>= 1) s2 += __shfl_down(s2, o);
    __syncthreads();
    if ((t & 63) == 0) red[t >> 6] = s2;
    __syncthreads();
    float var = (red[0]+red[1]+red[2]+red[3]) * (1.0f/256.0f);
    Y[(size_t)r*HH + t] = dfv * rsqrtf(var + 1e-5f) * g[t] + b[t];
}

// ---------------- pool ----------------
__global__ void pool_k(const float* __restrict__ hf, float* __restrict__ pooled) {
    int b = blockIdx.x, t = threadIdx.x;
    float s = 0.0f;
    #pragma unroll 8
    for (int i = 0; i < 512; i++) s += hf[(size_t)((b<<9)+i)*HH + t];
    pooled[b*HH + t] = s * (1.0f/512.0f);
}

// ---------------- heads ----------------
__global__ __launch_bounds__(256) void heads_k(const float* __restrict__ pooled,
        const float* cw, const float* cbh, const float* hw, const float* hb,
        const float* tw, const float* tb, const float* p1w, const float* p1b,
        const float* p2w, const float* p2b, const float* dw, const float* db,
        const float* sw, const float* sb, float* __restrict__ out)
{
    int idx = blockIdx.x*256 + threadIdx.x;
    if (idx >= NOUT) return;
    int b = idx / 1552, j = idx - b*1552;
    const float* w; const float* bi; int col, nc;
    if (j < 1)         { w = cw;  bi = cbh; col = j;        nc = 1;   }
    else if (j < 5)    { w = hw;  bi = hb;  col = j - 1;    nc = 4;   }
    else if (j < 8)    { w = tw;  bi = tb;  col = j - 5;    nc = 3;   }
    else if (j < 520)  { w = p1w; bi = p1b; col = j - 8;    nc = 512; }
    else if (j < 1032) { w = p2w; bi = p2b; col = j - 520;  nc = 512; }
    else if (j < 1544) { w = dw;  bi = db;  col = j - 1032; nc = 512; }
    else               { w = sw;  bi = sb;  col = j - 1544; nc = 8;   }
    float s = bi[col];
    const float* pl = pooled + b*HH;
    #pragma unroll 4
    for (int k = 0; k < 256; k++) s = fmaf(pl[k], w[k*nc + col], s);
    out[idx] = s;
}

// ---------------- launcher ----------------
extern "C" void kernel_launch(void* const* d_in, const int* in_sizes, int n_in,
                              void* d_out, int out_size, void* d_ws, size_t ws_size,
                              hipStream_t stream)
{
    (void)in_sizes; (void)n_in; (void)out_size; (void)ws_size;
    const float* x      = (const float*)d_in[0];
    const int*   ei     = (const int*)  d_in[1];
    const float* W_init = (const float*)d_in[2];
    const float* b_init = (const float*)d_in[3];
    const float* g1W = (const float*)d_in[4];
    const float* g1b = (const float*)d_in[5];
    const float* g2W = (const float*)d_in[6];
    const float* g2b = (const float*)d_in[7];
    const float* inW = (const float*)d_in[8];
    const float* cW  = (const float*)d_in[9];
    const float* cb  = (const float*)d_in[10];
    const float* xpW = (const float*)d_in[11];
    const float* dtW = (const float*)d_in[12];
    const float* dtb = (const float*)d_in[13];
    const float* Alog= (const float*)d_in[14];
    const float* Dp  = (const float*)d_in[15];
    const float* outW= (const float*)d_in[16];
    const float* Wq  = (const float*)d_in[17];
    const float* bq  = (const float*)d_in[18];
    const float* Wk  = (const float*)d_in[19];
    const float* bk  = (const float*)d_in[20];
    const float* Wv  = (const float*)d_in[21];
    const float* bv  = (const float*)d_in[22];
    const float* Wo  = (const float*)d_in[23];
    const float* bo  = (const float*)d_in[24];
    const float* fusW= (const float*)d_in[25];
    const float* fusb= (const float*)d_in[26];
    const float* lng = (const float*)d_in[27];
    const float* lnb = (const float*)d_in[28];
    const float* cwp = (const float*)d_in[29];
    const float* cbp = (const float*)d_in[30];
    const float* hwp = (const float*)d_in[31];
    const float* hbp = (const float*)d_in[32];
    const float* twp = (const float*)d_in[33];
    const float* tbp = (const float*)d_in[34];
    const float* p1w = (const float*)d_in[35];
    const float* p1b = (const float*)d_in[36];
    const float* p2w = (const float*)d_in[37];
    const float* p2b = (const float*)d_in[38];
    const float* dwp = (const float*)d_in[39];
    const float* dbp = (const float*)d_in[40];
    const float* swp = (const float*)d_in[41];
    const float* sbp = (const float*)d_in[42];

    float* fw = (float*)d_ws;
    int* iw = (int*)(fw + O_INT);
    int* indeg = iw;
    int* row_start = iw + 4096;
    int* cursor = iw + 8193;
    int* csr = iw + 12289;
    float* dinv = fw + O_DINV;

    hbf* wt   = (hbf*)(fw + O_WT);
    hbf* xb   = (hbf*)(fw + O_XB);
    hbf* h0b  = (hbf*)(fw + O_H0B);
    hbf* h2b  = (hbf*)(fw + O_H2B);
    hbf* xcb  = (hbf*)(fw + O_XCB);
    hbf* dtab = (hbf*)(fw + O_DTAB);
    hbf* xzb  = (hbf*)(fw + O_XZB);
    hbf* yb   = (hbf*)(fw + O_Y);
    hbf* aob  = (hbf*)(fw + O_Y);        // after yb consumed
    hbf* catb = (hbf*)(fw + O_CATB);
    hbf* qkB  = (hbf*)(fw + O_QK);
    hbf* vtB  = (hbf*)(fw + O_XC);       // xc dead after scan3
    float* fused = fw + O_XC;            // after vtB/op3 dead
    float* hf = fw + O_Y;                // after aob consumed
    float* b512 = fw + O_B512;

    OPtrs op;
    op.p[0] = fw + O_MBUF;
    op.p[1] = fw + O_DELTA;
    op.p[2] = fw + O_DELTA + 1048576;
    op.p[3] = fw + O_XC + 524288;
    float* lsum = fw + O_PROJ;           // proj dead after scan3

    hbf* WtInit = wt + 0;
    hbf* WtG1   = wt + 8192;
    hbf* WtG2   = wt + 73728;
    hbf* WtIn   = wt + 139264;
    hbf* WtXp   = wt + 401408;
    hbf* WtDt   = wt + 417792;
    hbf* WtOut  = wt + 434176;
    hbf* WtQK   = wt + 565248;           // WtQ + WtK contiguous (N=512)
    hbf* WtV    = wt + 696320;
    hbf* WtO    = wt + 761856;
    hbf* WtFus  = wt + 827392;

    WSrc wsrc;
    wsrc.p[0]=W_init; wsrc.p[1]=g1W; wsrc.p[2]=g2W; wsrc.p[3]=inW; wsrc.p[4]=xpW;
    wsrc.p[5]=dtW; wsrc.p[6]=outW; wsrc.p[7]=Wq; wsrc.p[8]=Wk; wsrc.p[9]=Wv;
    wsrc.p[10]=Wo; wsrc.p[11]=fusW;
    wcast_k<<<4000,256,0,stream>>>(wsrc, wt);
    cast_k<<<512,256,0,stream>>>(x, xb, 131072);
    catb2_k<<<2,256,0,stream>>>(bq, bk, b512);

    // graph prep
    zero_k<<<16,256,0,stream>>>(indeg);
    count_k<<<256,256,0,stream>>>(ei, indeg);
    prefix_k<<<1,1024,0,stream>>>(indeg, row_start, cursor);
    scatter_k<<<256,256,0,stream>>>(ei, cursor, csr);
    dinv_k<<<16,256,0,stream>>>(indeg, dinv);

    // h0 = relu(x @ W_init + b_init) -> bf16
    mg_k<1,1><<<dim3(64,4),256,0,stream>>>((const unsigned short*)xb, (const unsigned short*)WtInit,
        b_init, h0b, 256, nullptr, 0, NL, 32, 256);
    // gcn1
    mg_k<0,0><<<dim3(64,4),256,0,stream>>>((const unsigned short*)h0b, (const unsigned short*)WtG1,
        nullptr, fw+O_MBUF, 256, nullptr, 0, NL, 256, 256);
    gather_k<0><<<4096,256,0,stream>>>(fw+O_MBUF, csr, row_start, dinv, g1b, nullptr, h0b, nullptr);
    // gcn2 (fp32 h2 + bf16 h2b + catb cols 0..255)
    mg_k<0,0><<<dim3(64,4),256,0,stream>>>((const unsigned short*)h0b, (const unsigned short*)WtG2,
        nullptr, fw+O_MBUF, 256, nullptr, 0, NL, 256, 256);
    gather_k<1><<<4096,256,0,stream>>>(fw+O_MBUF, csr, row_start, dinv, g2b, fw+O_H2, h2b, catb);

    // mamba
    mg_k<0,1><<<dim3(64,16),256,0,stream>>>((const unsigned short*)h2b, (const unsigned short*)WtIn,
        nullptr, xzb, 1024, nullptr, 0, NL, 256, 1024);
    conv_k<<<8192,256,0,stream>>>(xzb, cW, cb, fw+O_XC, xcb);
    mg_k<0,0><<<dim3(64,1),256,0,stream>>>((const unsigned short*)xcb, (const unsigned short*)WtXp,
        nullptr, fw+O_PROJ, 32, nullptr, 0, NL, 512, 32);
    cast_pad_k<<<512,256,0,stream>>>(fw+O_PROJ, dtab);
    mg_k<2,0><<<dim3(64,8),256,0,stream>>>((const unsigned short*)dtab, (const unsigned short*)WtDt,
        dtb, fw+O_DELTA, 512, nullptr, 0, NL, 32, 512);
    scan1_k<<<128,256,0,stream>>>(fw+O_DELTA, fw+O_XC, fw+O_PROJ, Alog, fw+O_P, fw+O_HL);
    scan2p_k<<<1024,256,0,stream>>>(fw+O_P, fw+O_HL, fw+O_HST);
    scan3_k<<<128,256,0,stream>>>(fw+O_DELTA, fw+O_XC, fw+O_PROJ, Alog, fw+O_HST, Dp, xzb, yb);
    mg_k<0,1><<<dim3(64,4),256,0,stream>>>((const unsigned short*)yb, (const unsigned short*)WtOut,
        nullptr, catb + 256, 768, nullptr, 0, NL, 512, 256);

    // attention: fused QK GEMM (Q scaled 0.125), V transposed
    mg_k<3,1><<<dim3(64,8),256,0,stream>>>((const unsigned short*)h2b, (const unsigned short*)WtQK,
        b512, qkB, 512, nullptr, 0, NL, 256, 512);
    mg_k<0,2><<<dim3(64,4),256,0,stream>>>((const unsigned short*)h2b, (const unsigned short*)WtV,
        bv, vtB, NL, nullptr, 0, NL, 256, 256);
    attn_part_k<<<dim3(64,4,4),256,0,stream>>>((const unsigned short*)qkB,
        (const unsigned short*)vtB, op, lsum);
    amerge_k<<<4096,256,0,stream>>>(op, lsum, aob);
    mg_k<0,1><<<dim3(64,4),256,0,stream>>>((const unsigned short*)aob, (const unsigned short*)WtO,
        bo, catb + 512, 768, nullptr, 0, NL, 256, 256);

    // fuse + residual + LN + pool + heads
    mg_k<1,0><<<dim3(64,4),256,0,stream>>>((const unsigned short*)catb, (const unsigned short*)WtFus,
        fusb, fused, 256, fw+O_H2, 256, NL, 768, 256);
    ln_k<<<4096,256,0,stream>>>(fused, lng, lnb, hf);
    pool_k<<<8,256,0,stream>>>(hf, fw+O_POOL);
    heads_k<<<(NOUT+255)/256,256,0,stream>>>(fw+O_POOL, cwp,cbp,hwp,hbp,twp,tbp,p1w,p1b,p2w,p2b,
                                             dwp,dbp,swp,sbp, (float*)d_out);
}

// Round 11
// 413.178 us; speedup vs baseline: 5.1367x; 1.1253x over previous
//
#include <hip/hip_runtime.h>
#include <hip/hip_bf16.h>
#include <math.h>

typedef __hip_bfloat16 hbf;
typedef short bf16x8 __attribute__((ext_vector_type(8)));
typedef float f32x4 __attribute__((ext_vector_type(4)));

// ---------------- problem constants ----------------
constexpr int NL  = 4096;
constexpr int HH  = 256;
constexpr int NE  = 8192;
constexpr int DIc = 512;
constexpr int DSc = 8;
constexpr int NCH = 256;   // scan chunks (round 11: 64 -> 256)
constexpr int CLc = 16;    // chunk length
constexpr int NOUT = 12416;

// ---------------- workspace layout (float offsets) ----------------
constexpr size_t O_MBUF  = 0;         // 1048576  gcn msgs; scan P; attn op0
constexpr size_t O_QK    = 1048576;   // 1048576  scan Hl; qkB bf16 [NL][512]
constexpr size_t O_H2    = 2097152;   // 1048576  h2 fp32 (live to fus resid)
constexpr size_t O_CATB  = 3145728;   // 1572864  catb bf16 [NL][768]
constexpr size_t O_XZB   = 4718592;   // 2097152  xzb bf16 [NL][1024]; op4@+0, op5@+1048576
constexpr size_t O_XC    = 6815744;   // 2097152  xc fp32; vtB@+0(524288), op3@+524288, fused@+0
constexpr size_t O_DELTA = 8912896;   // 2097152  delta; op1@+0, op2@+1048576
constexpr size_t O_PROJ  = 11010048;  // 131072   proj fp32; lsum (8*4*4096=131072)
constexpr size_t O_HST   = 11141120;  // 1048576  Hst (256*8*512)
constexpr size_t O_Y     = 12189696;  // 1048576  yb bf16; aob bf16
constexpr size_t O_POOL  = 13238272;  // 2048
constexpr size_t O_DINV  = 13240320;  // 4096
constexpr size_t O_B512  = 13244416;  // 512
constexpr size_t O_INT   = 13244928;  // 81928 ints
constexpr size_t O_WT    = 13326856;  // 512000
constexpr size_t O_XB    = 13838856;  // 65536
constexpr size_t O_H0B   = 13904392;  // 524288   (op7 spans H0B+H2B)
constexpr size_t O_H2B   = 14428680;  // 524288
constexpr size_t O_XCB   = 14952968;  // 1048576  xcb bf16; attn op6
constexpr size_t O_DTAB  = 16001544;  // 65536
// total 16067080 floats = 64.3 MB

// ---------------- weight transpose-cast table ----------------
constexpr int NW = 12;
__device__ __constant__ int wc_cum[NW+1] = {
    0, 8192, 73728, 139264, 401408, 417792, 434176, 565248,
    630784, 696320, 761856, 827392, 1024000 };
__device__ __constant__ int wc_K [NW] = {32,256,256,256,512,16,512,256,256,256,256,768};
__device__ __constant__ int wc_N [NW] = {256,256,256,1024,32,512,256,256,256,256,256,256};
__device__ __constant__ int wc_Kp[NW] = {32,256,256,256,512,32,512,256,256,256,256,768};
struct WSrc { const float* p[NW]; };
struct OPtrs { float* p[8]; };

// prep: weight transpose-cast + x cast + b512 + pooled zero + indeg zero
constexpr int PR_W = 1024000;
constexpr int PR_X = PR_W + 131072;    // 1155072
constexpr int PR_B = PR_X + 512;       // 1155584
constexpr int PR_P = PR_B + 2048;      // 1157632
constexpr int PR_I = PR_P + 4096;      // 1161728
__global__ __launch_bounds__(256) void prep_k(WSrc ws, hbf* __restrict__ wt,
        const float* __restrict__ x, hbf* __restrict__ xb,
        const float* __restrict__ bq, const float* __restrict__ bk,
        float* __restrict__ b512, float* __restrict__ pooled, int* __restrict__ indeg) {
    int idx = blockIdx.x*256 + threadIdx.x;
    if (idx < PR_W) {
        int lo = 0, hi = NW-1;
        while (lo < hi) { int mid = (lo+hi+1)>>1; if (idx >= wc_cum[mid]) lo = mid; else hi = mid-1; }
        int local = idx - wc_cum[lo];
        int Kp = wc_Kp[lo], K = wc_K[lo], N = wc_N[lo];
        int n = local / Kp, k = local - n*Kp;
        float v = (k < K) ? ws.p[lo][(size_t)k*N + n] : 0.0f;
        wt[idx] = __float2bfloat16(v);
    } else if (idx < PR_X) {
        int i = idx - PR_W;
        xb[i] = __float2bfloat16(x[i]);
    } else if (idx < PR_B) {
        int i = idx - PR_X;
        b512[i] = (i < 256) ? bq[i] : bk[i-256];
    } else if (idx < PR_P) {
        pooled[idx - PR_B] = 0.0f;
    } else if (idx < PR_I) {
        indeg[idx - PR_P] = 0;
    }
}

__global__ void cast_pad_k(const float* __restrict__ proj, hbf* __restrict__ d) {
    int i = blockIdx.x*256 + threadIdx.x;
    int r = i >> 5, k = i & 31;
    d[i] = __float2bfloat16((k < 16) ? proj[r*32 + k] : 0.0f);
}

// ---------------- graph prep ----------------
__global__ void count_k(const int* __restrict__ ei, int* __restrict__ indeg) {
    int i = blockIdx.x*256 + threadIdx.x;
    int b = i >> 13, e = i & 8191;
    int dst = ei[b*2*NE + NE + e] + (b << 9);
    atomicAdd(&indeg[dst], 1);
}

__global__ __launch_bounds__(1024) void prefix_k(const int* __restrict__ indeg,
                                                 int* __restrict__ row_start,
                                                 int* __restrict__ cursor) {
    __shared__ int part[1024];
    int t = threadIdx.x;
    int v0[4]; int s = 0;
    #pragma unroll
    for (int i = 0; i < 4; i++) { v0[i] = s; s += indeg[t*4 + i]; }
    part[t] = s;
    __syncthreads();
    for (int o = 1; o < 1024; o <<= 1) {
        int x = (t >= o) ? part[t-o] : 0;
        __syncthreads();
        part[t] += x;
        __syncthreads();
    }
    int base = (t > 0) ? part[t-1] : 0;
    #pragma unroll
    for (int i = 0; i < 4; i++) {
        int rs = base + v0[i];
        row_start[t*4+i] = rs; cursor[t*4+i] = rs;
    }
    if (t == 1023) row_start[4096] = part[1023];
}

__global__ void scatter_k(const int* __restrict__ ei, int* __restrict__ cursor,
                          int* __restrict__ csr) {
    int i = blockIdx.x*256 + threadIdx.x;
    int b = i >> 13, e = i & 8191;
    int src = ei[b*2*NE + e]       + (b << 9);
    int dst = ei[b*2*NE + NE + e]  + (b << 9);
    int pos = atomicAdd(&cursor[dst], 1);
    csr[pos] = src;
}

__global__ void dinv_k(const int* __restrict__ indeg, float* __restrict__ dinv) {
    int i = blockIdx.x*256 + threadIdx.x;
    dinv[i] = rsqrtf(1.0f + (float)indeg[i]);
}

// gather; MODE 1 adds fp32 out + catb(cols 0..255) write
template<int MODE>
__global__ __launch_bounds__(256) void gather_k(const float* __restrict__ m,
                        const int* __restrict__ csr, const int* __restrict__ row_start,
                        const float* __restrict__ dinv, const float* __restrict__ bias,
                        float* __restrict__ out, hbf* __restrict__ outb,
                        hbf* __restrict__ catb) {
    int n = blockIdx.x, c = threadIdx.x;
    float dn = dinv[n];
    float acc = m[(size_t)n*HH + c] * dn * dn;
    int e0 = row_start[n], e1 = row_start[n+1];
    for (int e = e0; e < e1; e++) {
        int s = csr[e];
        acc += m[(size_t)s*HH + c] * (dinv[s] * dn);
    }
    float r = fmaxf(acc + bias[c], 0.0f);
    if (MODE) {
        out[(size_t)n*HH + c] = r;
        catb[(size_t)n*768 + c] = __float2bfloat16(r);
    }
    outb[(size_t)n*HH + c] = __float2bfloat16(r);
}

// ---------------- bf16 MFMA GEMM (BK=64, register prefetch) ----------------
// OUTM: 0 fp32, 1 bf16, 2 bf16 transposed (via LDS)
// ACT: 0 none, 1 relu, 2 softplus, 3 scale cols<256 by 0.125 (fused QK)
template<int ACT, int OUTM>
__global__ __launch_bounds__(256) void mg_k(const unsigned short* __restrict__ A,
        const unsigned short* __restrict__ Bt, const float* __restrict__ bias,
        void* __restrict__ Cp, int ldc, const float* __restrict__ resid, int ldr,
        int M, int K, int N)
{
    __shared__ __align__(16) unsigned short Asm[2][64][40];
    __shared__ __align__(16) unsigned short Bsm[2][64][40];
    int t = threadIdx.x;
    int lane = t & 63, w = t >> 6;
    int wm = w & 1, wn = w >> 1;
    int row0 = blockIdx.x * 64, col0 = blockIdx.y * 64;
    int sr = t >> 2;
    int sk = (t & 3) * 16;          // 0,16,32,48 (64-k coverage)
    int su = sk >> 5, so = sk & 31; // sub-tile index / offset
    f32x4 acc[2][2] = {};
    int fr = lane & 15, fq8 = (lane >> 4) * 8;

    uint4 zz = make_uint4(0u,0u,0u,0u);
    uint4 ra0 = zz, ra1 = zz, rb0 = zz, rb1 = zz;
    bool bnv = (col0 + sr) < N;
    if (sk < K) {
        ra0 = *(const uint4*)&A[(size_t)(row0+sr)*K + sk];
        ra1 = *(const uint4*)&A[(size_t)(row0+sr)*K + sk + 8];
        if (bnv) {
            rb0 = *(const uint4*)&Bt[(size_t)(col0+sr)*K + sk];
            rb1 = *(const uint4*)&Bt[(size_t)(col0+sr)*K + sk + 8];
        }
    }

    for (int k0 = 0; k0 < K; k0 += 64) {
        __syncthreads();
        *(uint4*)&Asm[su][sr][so]     = ra0;
        *(uint4*)&Asm[su][sr][so + 8] = ra1;
        *(uint4*)&Bsm[su][sr][so]     = rb0;
        *(uint4*)&Bsm[su][sr][so + 8] = rb1;
        __syncthreads();
        int kn = k0 + 64;
        if (kn < K) {
            ra0 = ra1 = rb0 = rb1 = zz;
            if (kn + sk < K) {
                ra0 = *(const uint4*)&A[(size_t)(row0+sr)*K + kn + sk];
                ra1 = *(const uint4*)&A[(size_t)(row0+sr)*K + kn + sk + 8];
                if (bnv) {
                    rb0 = *(const uint4*)&Bt[(size_t)(col0+sr)*K + kn + sk];
                    rb1 = *(const uint4*)&Bt[(size_t)(col0+sr)*K + kn + sk + 8];
                }
            }
        }
        #pragma unroll
        for (int ks = 0; ks < 2; ks++) {
            bf16x8 a0 = *(bf16x8*)&Asm[ks][wm*32 + fr][fq8];
            bf16x8 a1 = *(bf16x8*)&Asm[ks][wm*32 + 16 + fr][fq8];
            bf16x8 b0 = *(bf16x8*)&Bsm[ks][wn*32 + fr][fq8];
            bf16x8 b1 = *(bf16x8*)&Bsm[ks][wn*32 + 16 + fr][fq8];
            acc[0][0] = __builtin_amdgcn_mfma_f32_16x16x32_bf16(a0, b0, acc[0][0], 0, 0, 0);
            acc[0][1] = __builtin_amdgcn_mfma_f32_16x16x32_bf16(a0, b1, acc[0][1], 0, 0, 0);
            acc[1][0] = __builtin_amdgcn_mfma_f32_16x16x32_bf16(a1, b0, acc[1][0], 0, 0, 0);
            acc[1][1] = __builtin_amdgcn_mfma_f32_16x16x32_bf16(a1, b1, acc[1][1], 0, 0, 0);
        }
    }

    int fc = lane & 15, frq = (lane >> 4) * 4;
    if constexpr (OUTM == 2) {
        __shared__ __align__(16) unsigned short Ts[64][72];
        #pragma unroll
        for (int mt = 0; mt < 2; mt++)
            #pragma unroll
            for (int nt = 0; nt < 2; nt++) {
                int col = col0 + wn*32 + nt*16 + fc;
                float bvv = bias ? bias[col] : 0.0f;
                #pragma unroll
                for (int i = 0; i < 4; i++) {
                    float v = acc[mt][nt][i] + bvv;
                    *(hbf*)&Ts[wn*32 + nt*16 + fc][wm*32 + mt*16 + frq + i] = __float2bfloat16(v);
                }
            }
        __syncthreads();
        int c = t >> 2, rs = (t & 3) * 16;
        if (col0 + c < N) {
            hbf* outp = (hbf*)Cp + (size_t)(col0 + c)*ldc + row0 + rs;
            *(uint4*)outp       = *(uint4*)&Ts[c][rs];
            *(uint4*)(outp + 8) = *(uint4*)&Ts[c][rs + 8];
        }
    } else {
        #pragma unroll
        for (int mt = 0; mt < 2; mt++) {
            #pragma unroll
            for (int nt = 0; nt < 2; nt++) {
                int col = col0 + wn*32 + nt*16 + fc;
                if (col >= N) continue;
                float bvv = bias ? bias[col] : 0.0f;
                #pragma unroll
                for (int i = 0; i < 4; i++) {
                    int row = row0 + wm*32 + mt*16 + frq + i;
                    float v = acc[mt][nt][i] + bvv;
                    if (ACT == 1) v = fmaxf(v, 0.0f);
                    if (ACT == 2) v = (v > 20.0f) ? v : log1pf(expf(v));
                    if (ACT == 3) { if (col < 256) v *= 0.125f; }
                    if (resid) v += resid[(size_t)row*ldr + col];
                    if (OUTM == 0) ((float*)Cp)[(size_t)row*ldc + col] = v;
                    else           ((hbf*)Cp)[(size_t)row*ldc + col] = __float2bfloat16(v);
                }
            }
        }
    }
}

// ---------------- mamba: conv + silu (bf16 in, fp32+bf16 out) ----------------
__global__ void conv_k(const hbf* __restrict__ xzb, const float* __restrict__ cW,
                       const float* __restrict__ cb, float* __restrict__ xc2,
                       hbf* __restrict__ xcb) {
    int i = blockIdx.x*256 + threadIdx.x;
    int l = i >> 9, d = i & 511;
    float acc = cb[d];
    #pragma unroll
    for (int k = 0; k < 4; k++) {
        int ls = l - 3 + k;
        if (ls >= 0) acc += __bfloat162float(xzb[(size_t)ls*1024 + d]) * cW[d*4 + k];
    }
    float r = acc / (1.0f + __expf(-acc));
    xc2[i] = r;
    xcb[i] = __float2bfloat16(r);
}

// ---------------- mamba chunked scan (256 chunks x 16 steps) ----------------
__global__ __launch_bounds__(256) void scan1_k(const float* __restrict__ delta,
                        const float* __restrict__ xc, const float* __restrict__ proj,
                        const float* __restrict__ Alog,
                        float* __restrict__ P, float* __restrict__ Hl)
{
    int c = blockIdx.x >> 1;
    int d = ((blockIdx.x & 1) << 8) + threadIdx.x;
    float Ac[DSc], pr[DSc], h[DSc];
    #pragma unroll
    for (int s2 = 0; s2 < DSc; s2++) { Ac[s2] = -__expf(Alog[d*DSc+s2]); pr[s2]=1.0f; h[s2]=0.0f; }
    int l0 = c * CLc;
    for (int l = l0; l < l0 + CLc; l++) {
        float dl = delta[(size_t)l*DIc + d];
        float dx = dl * xc[(size_t)l*DIc + d];
        const float* pb = proj + l*32 + 16;
        #pragma unroll
        for (int s2 = 0; s2 < DSc; s2++) {
            float a = __expf(dl * Ac[s2]);
            h[s2] = a*h[s2] + dx*pb[s2];
            pr[s2] *= a;
        }
    }
    #pragma unroll
    for (int s2 = 0; s2 < DSc; s2++) {
        P [(size_t)(c*DSc+s2)*DIc + d] = pr[s2];
        Hl[(size_t)(c*DSc+s2)*DIc + d] = h[s2];
    }
}

// log-scan over 256 chunks; one series per block (grid 4096)
__global__ __launch_bounds__(256) void scan2p_k(const float* __restrict__ P,
                        const float* __restrict__ Hl, float* __restrict__ Hst) {
    __shared__ float Psh[256], Hsh[256];
    int t = threadIdx.x, series = blockIdx.x;
    size_t off = (size_t)t*4096 + series;
    float Pc = P[off], Hc = Hl[off];
    Psh[t] = Pc; Hsh[t] = Hc;
    __syncthreads();
    #pragma unroll
    for (int st = 1; st < 256; st <<= 1) {
        float p1 = 1.0f, h1 = 0.0f;
        if (t >= st) { p1 = Psh[t-st]; h1 = Hsh[t-st]; }
        __syncthreads();
        Hc = Pc*h1 + Hc;
        Pc = Pc*p1;
        Psh[t] = Pc; Hsh[t] = Hc;
        __syncthreads();
    }
    Hst[off] = (t == 0) ? 0.0f : Hsh[t-1];
}

__global__ __launch_bounds__(256) void scan3_k(const float* __restrict__ delta,
                        const float* __restrict__ xc, const float* __restrict__ proj,
                        const float* __restrict__ Alog, const float* __restrict__ Hst,
                        const float* __restrict__ Dp, const hbf* __restrict__ xzb,
                        hbf* __restrict__ Y)
{
    int c = blockIdx.x >> 1;
    int d = ((blockIdx.x & 1) << 8) + threadIdx.x;
    float Ac[DSc], h[DSc];
    #pragma unroll
    for (int s2 = 0; s2 < DSc; s2++) {
        Ac[s2] = -__expf(Alog[d*DSc+s2]);
        h[s2]  = Hst[(size_t)(c*DSc+s2)*DIc + d];
    }
    float dpv = Dp[d];
    int l0 = c * CLc;
    for (int l = l0; l < l0 + CLc; l++) {
        float dl = delta[(size_t)l*DIc + d];
        float xv = xc[(size_t)l*DIc + d];
        float dx = dl * xv;
        const float* pb = proj + l*32 + 16;
        float y = 0.0f;
        #pragma unroll
        for (int s2 = 0; s2 < DSc; s2++) {
            float a = __expf(dl * Ac[s2]);
            h[s2] = a*h[s2] + dx*pb[s2];
            y += h[s2] * pb[8+s2];
        }
        float z = __bfloat162float(xzb[(size_t)l*1024 + 512 + d]);
        float sz = z / (1.0f + __expf(-z));
        Y[(size_t)l*DIc + d] = __float2bfloat16((y + dpv*xv) * sz);
    }
}

// ---------------- split-K(8) MFMA flash attention, constant-shift softmax ----------------
// Q pre-scaled 0.125. p = exp(s-4) (exact up to shift). l via ones-MFMA. Q frags hoisted.
__global__ __launch_bounds__(256) void attn_part_k(const unsigned short* __restrict__ QK,
                       const unsigned short* __restrict__ Vt,
                       OPtrs op, float* __restrict__ lsum)
{
    __shared__ __align__(16) unsigned short Qs[64][72];
    __shared__ __align__(16) unsigned short Ks[64][72];
    __shared__ __align__(16) unsigned short Vs[64][72];
    __shared__ __align__(16) unsigned short Ps[64][72];
    int t = threadIdx.x, lane = t & 63, w = t >> 6;
    int h = blockIdx.y, q0 = blockIdx.x * 64, skc = blockIdx.z;
    int sr = t >> 2, sk = (t & 3) * 16;
    int fm = lane & 15, fq = lane >> 4;

    *(uint4*)&Qs[sr][sk]     = *(const uint4*)&QK[(size_t)(q0+sr)*512 + h*64 + sk];
    *(uint4*)&Qs[sr][sk + 8] = *(const uint4*)&QK[(size_t)(q0+sr)*512 + h*64 + sk + 8];
    __syncthreads();
    bf16x8 qa0 = *(bf16x8*)&Qs[w*16 + fm][fq*8];
    bf16x8 qa1 = *(bf16x8*)&Qs[w*16 + fm][32 + fq*8];

    const unsigned short* Kb = QK + 256;
    bf16x8 ones;
    #pragma unroll
    for (int j = 0; j < 8; j++) ones[j] = (short)0x3F80;   // bf16 1.0

    f32x4 o[4] = {};
    f32x4 ol = {};
    int kt = skc * 512;
    uint4 ka  = *(const uint4*)&Kb[(size_t)(kt+sr)*512 + h*64 + sk];
    uint4 kb2 = *(const uint4*)&Kb[(size_t)(kt+sr)*512 + h*64 + sk + 8];
    uint4 va  = *(const uint4*)&Vt[(size_t)(h*64+sr)*NL + kt + sk];
    uint4 vb2 = *(const uint4*)&Vt[(size_t)(h*64+sr)*NL + kt + sk + 8];

    for (int it = 0; it < 8; it++) {
        __syncthreads();
        *(uint4*)&Ks[sr][sk] = ka;  *(uint4*)&Ks[sr][sk+8] = kb2;
        *(uint4*)&Vs[sr][sk] = va;  *(uint4*)&Vs[sr][sk+8] = vb2;
        __syncthreads();
        if (it < 7) {
            int kn = kt + 64;
            ka  = *(const uint4*)&Kb[(size_t)(kn+sr)*512 + h*64 + sk];
            kb2 = *(const uint4*)&Kb[(size_t)(kn+sr)*512 + h*64 + sk + 8];
            va  = *(const uint4*)&Vt[(size_t)(h*64+sr)*NL + kn + sk];
            vb2 = *(const uint4*)&Vt[(size_t)(h*64+sr)*NL + kn + sk + 8];
        }
        f32x4 s[4] = {};
        #pragma unroll
        for (int nt = 0; nt < 4; nt++) {
            bf16x8 b0 = *(bf16x8*)&Ks[nt*16 + fm][fq*8];
            bf16x8 b1 = *(bf16x8*)&Ks[nt*16 + fm][32 + fq*8];
            s[nt] = __builtin_amdgcn_mfma_f32_16x16x32_bf16(qa0, b0, s[nt], 0, 0, 0);
            s[nt] = __builtin_amdgcn_mfma_f32_16x16x32_bf16(qa1, b1, s[nt], 0, 0, 0);
        }
        #pragma unroll
        for (int nt = 0; nt < 4; nt++) {
            #pragma unroll
            for (int i = 0; i < 4; i++) {
                float p = __expf(s[nt][i] - 4.0f);
                *(hbf*)&Ps[w*16 + fq*4 + i][nt*16 + fm] = __float2bfloat16(p);
            }
        }
        #pragma unroll
        for (int ks = 0; ks < 2; ks++) {
            bf16x8 a = *(bf16x8*)&Ps[w*16 + fm][ks*32 + fq*8];
            #pragma unroll
            for (int nt = 0; nt < 4; nt++) {
                bf16x8 b = *(bf16x8*)&Vs[nt*16 + fm][ks*32 + fq*8];
                o[nt] = __builtin_amdgcn_mfma_f32_16x16x32_bf16(a, b, o[nt], 0, 0, 0);
            }
            ol = __builtin_amdgcn_mfma_f32_16x16x32_bf16(a, ones, ol, 0, 0, 0);
        }
        kt += 64;
    }
    float* Op = op.p[skc];
    #pragma unroll
    for (int i = 0; i < 4; i++) {
        int row = w*16 + fq*4 + i;
        #pragma unroll
        for (int nt = 0; nt < 4; nt++)
            Op[(size_t)(q0 + row)*HH + h*64 + nt*16 + fm] = o[nt][i];
    }
    if (fm == 0) {
        #pragma unroll
        for (int i = 0; i < 4; i++)
            lsum[(size_t)(skc*4 + h)*NL + q0 + w*16 + fq*4 + i] = ol[i];
    }
}

// exact merge: O = sum_c Oc / sum_c lc
__global__ __launch_bounds__(256) void amerge_k(OPtrs op, const float* __restrict__ lsum,
                                                hbf* __restrict__ aob) {
    int row = blockIdx.x, t = threadIdx.x, h = t >> 6;
    float L = 0.0f, s = 0.0f;
    #pragma unroll
    for (int c = 0; c < 8; c++) {
        L += lsum[(size_t)(c*4 + h)*NL + row];
        s += op.p[c][(size_t)row*HH + t];
    }
    aob[(size_t)row*HH + t] = __float2bfloat16(s / L);
}

// ---------------- layernorm + fused pooling (atomic) ----------------
__global__ __launch_bounds__(256) void ln_k(const float* __restrict__ X,
                    const float* __restrict__ g, const float* __restrict__ b,
                    float* __restrict__ pooled) {
    __shared__ float red[4];
    int r = blockIdx.x, t = threadIdx.x;
    float v = X[(size_t)r*HH + t];
    float s = v;
    #pragma unroll
    for (int o = 32; o > 0; o >>= 1) s += __shfl_down(s, o);
    if ((t & 63) == 0) red[t >> 6] = s;
    __syncthreads();
    float mean = (red[0]+red[1]+red[2]+red[3]) * (1.0f/256.0f);
    float dfv = v - mean;
    float s2 = dfv*dfv;
    #pragma unroll
    for (int o = 32; o > 0; o >>= 1) s2 += __shfl_down(s2, o);
    __syncthreads();
    if ((t & 63) == 0) red[t >> 6] = s2;
    __syncthreads();
    float var = (red[0]+red[1]+red[2]+red[3]) * (1.0f/256.0f);
    float y = dfv * rsqrtf(var + 1e-5f) * g[t] + b[t];
    atomicAdd(&pooled[(r >> 9)*HH + t], y * (1.0f/512.0f));
}

// ---------------- heads: wave per output (grid 3104) ----------------
__global__ __launch_bounds__(256) void heads_k(const float* __restrict__ pooled,
        const float* cw, const float* cbh, const float* hw, const float* hb,
        const float* tw, const float* tb, const float* p1w, const float* p1b,
        const float* p2w, const float* p2b, const float* dw, const float* db,
        const float* sw, const float* sb, float* __restrict__ out)
{
    int idx = blockIdx.x*4 + (threadIdx.x >> 6);
    int lane = threadIdx.x & 63;
    if (idx >= NOUT) return;
    int b = idx / 1552, j = idx - b*1552;
    const float* w; const float* bi; int col, nc;
    if (j < 1)         { w = cw;  bi = cbh; col = j;        nc = 1;   }
    else if (j < 5)    { w = hw;  bi = hb;  col = j - 1;    nc = 4;   }
    else if (j < 8)    { w = tw;  bi = tb;  col = j - 5;    nc = 3;   }
    else if (j < 520)  { w = p1w; bi = p1b; col = j - 8;    nc = 512; }
    else if (j < 1032) { w = p2w; bi = p2b; col = j - 520;  nc = 512; }
    else if (j < 1544) { w = dw;  bi = db;  col = j - 1032; nc = 512; }
    else               { w = sw;  bi = sb;  col = j - 1544; nc = 8;   }
    const float* pl = pooled + b*HH;
    float s = 0.0f;
    #pragma unroll
    for (int k = lane; k < 256; k += 64) s = fmaf(pl[k], w[(size_t)k*nc + col], s);
    #pragma unroll
    for (int o = 32; o > 0; o >>= 1) s += __shfl_down(s, o);
    if (lane == 0) out[idx] = s + bi[col];
}

// ---------------- launcher ----------------
extern "C" void kernel_launch(void* const* d_in, const int* in_sizes, int n_in,
                              void* d_out, int out_size, void* d_ws, size_t ws_size,
                              hipStream_t stream)
{
    (void)in_sizes; (void)n_in; (void)out_size; (void)ws_size;
    const float* x      = (const float*)d_in[0];
    const int*   ei     = (const int*)  d_in[1];
    const float* W_init = (const float*)d_in[2];
    const float* b_init = (const float*)d_in[3];
    const float* g1W = (const float*)d_in[4];
    const float* g1b = (const float*)d_in[5];
    const float* g2W = (const float*)d_in[6];
    const float* g2b = (const float*)d_in[7];
    const float* inW = (const float*)d_in[8];
    const float* cW  = (const float*)d_in[9];
    const float* cb  = (const float*)d_in[10];
    const float* xpW = (const float*)d_in[11];
    const float* dtW = (const float*)d_in[12];
    const float* dtb = (const float*)d_in[13];
    const float* Alog= (const float*)d_in[14];
    const float* Dp  = (const float*)d_in[15];
    const float* outW= (const float*)d_in[16];
    const float* Wq  = (const float*)d_in[17];
    const float* bq  = (const float*)d_in[18];
    const float* Wk  = (const float*)d_in[19];
    const float* bk  = (const float*)d_in[20];
    const float* Wv  = (const float*)d_in[21];
    const float* bv  = (const float*)d_in[22];
    const float* Wo  = (const float*)d_in[23];
    const float* bo  = (const float*)d_in[24];
    const float* fusW= (const float*)d_in[25];
    const float* fusb= (const float*)d_in[26];
    const float* lng = (const float*)d_in[27];
    const float* lnb = (const float*)d_in[28];
    const float* cwp = (const float*)d_in[29];
    const float* cbp = (const float*)d_in[30];
    const float* hwp = (const float*)d_in[31];
    const float* hbp = (const float*)d_in[32];
    const float* twp = (const float*)d_in[33];
    const float* tbp = (const float*)d_in[34];
    const float* p1w = (const float*)d_in[35];
    const float* p1b = (const float*)d_in[36];
    const float* p2w = (const float*)d_in[37];
    const float* p2b = (const float*)d_in[38];
    const float* dwp = (const float*)d_in[39];
    const float* dbp = (const float*)d_in[40];
    const float* swp = (const float*)d_in[41];
    const float* sbp = (const float*)d_in[42];

    float* fw = (float*)d_ws;
    int* iw = (int*)(fw + O_INT);
    int* indeg = iw;
    int* row_start = iw + 4096;
    int* cursor = iw + 8193;
    int* csr = iw + 12289;
    float* dinv = fw + O_DINV;

    hbf* wt   = (hbf*)(fw + O_WT);
    hbf* xb   = (hbf*)(fw + O_XB);
    hbf* h0b  = (hbf*)(fw + O_H0B);
    hbf* h2b  = (hbf*)(fw + O_H2B);
    hbf* xcb  = (hbf*)(fw + O_XCB);
    hbf* dtab = (hbf*)(fw + O_DTAB);
    hbf* xzb  = (hbf*)(fw + O_XZB);
    hbf* yb   = (hbf*)(fw + O_Y);
    hbf* aob  = (hbf*)(fw + O_Y);        // after yb consumed
    hbf* catb = (hbf*)(fw + O_CATB);
    hbf* qkB  = (hbf*)(fw + O_QK);       // after Hl consumed
    hbf* vtB  = (hbf*)(fw + O_XC);       // xc dead after scan3
    float* fused = fw + O_XC;            // after vtB/op3 dead
    float* b512 = fw + O_B512;

    // scan temporaries in dead regions
    float* scanP  = fw + O_MBUF;         // after gather<1>, before attn op0
    float* scanHl = fw + O_QK;           // before qkB written
    float* scanHst= fw + O_HST;

    OPtrs op;
    op.p[0] = fw + O_MBUF;
    op.p[1] = fw + O_DELTA;
    op.p[2] = fw + O_DELTA + 1048576;
    op.p[3] = fw + O_XC + 524288;
    op.p[4] = fw + O_XZB;
    op.p[5] = fw + O_XZB + 1048576;
    op.p[6] = fw + O_XCB;
    op.p[7] = fw + O_H0B;                // spans H0B+H2B (both dead at attn)
    float* lsum = fw + O_PROJ;           // proj dead after scan3

    hbf* WtInit = wt + 0;
    hbf* WtG1   = wt + 8192;
    hbf* WtG2   = wt + 73728;
    hbf* WtIn   = wt + 139264;
    hbf* WtXp   = wt + 401408;
    hbf* WtDt   = wt + 417792;
    hbf* WtOut  = wt + 434176;
    hbf* WtQK   = wt + 565248;           // WtQ + WtK contiguous (N=512)
    hbf* WtV    = wt + 696320;
    hbf* WtO    = wt + 761856;
    hbf* WtFus  = wt + 827392;

    WSrc wsrc;
    wsrc.p[0]=W_init; wsrc.p[1]=g1W; wsrc.p[2]=g2W; wsrc.p[3]=inW; wsrc.p[4]=xpW;
    wsrc.p[5]=dtW; wsrc.p[6]=outW; wsrc.p[7]=Wq; wsrc.p[8]=Wk; wsrc.p[9]=Wv;
    wsrc.p[10]=Wo; wsrc.p[11]=fusW;
    prep_k<<<(PR_I+255)/256,256,0,stream>>>(wsrc, wt, x, xb, bq, bk, b512,
                                            fw+O_POOL, indeg);

    // graph prep
    count_k<<<256,256,0,stream>>>(ei, indeg);
    prefix_k<<<1,1024,0,stream>>>(indeg, row_start, cursor);
    scatter_k<<<256,256,0,stream>>>(ei, cursor, csr);
    dinv_k<<<16,256,0,stream>>>(indeg, dinv);

    // h0 = relu(x @ W_init + b_init) -> bf16
    mg_k<1,1><<<dim3(64,4),256,0,stream>>>((const unsigned short*)xb, (const unsigned short*)WtInit,
        b_init, h0b, 256, nullptr, 0, NL, 32, 256);
    // gcn1
    mg_k<0,0><<<dim3(64,4),256,0,stream>>>((const unsigned short*)h0b, (const unsigned short*)WtG1,
        nullptr, fw+O_MBUF, 256, nullptr, 0, NL, 256, 256);
    gather_k<0><<<4096,256,0,stream>>>(fw+O_MBUF, csr, row_start, dinv, g1b, nullptr, h0b, nullptr);
    // gcn2 (fp32 h2 + bf16 h2b + catb cols 0..255)
    mg_k<0,0><<<dim3(64,4),256,0,stream>>>((const unsigned short*)h0b, (const unsigned short*)WtG2,
        nullptr, fw+O_MBUF, 256, nullptr, 0, NL, 256, 256);
    gather_k<1><<<4096,256,0,stream>>>(fw+O_MBUF, csr, row_start, dinv, g2b, fw+O_H2, h2b, catb);

    // mamba
    mg_k<0,1><<<dim3(64,16),256,0,stream>>>((const unsigned short*)h2b, (const unsigned short*)WtIn,
        nullptr, xzb, 1024, nullptr, 0, NL, 256, 1024);
    conv_k<<<8192,256,0,stream>>>(xzb, cW, cb, fw+O_XC, xcb);
    mg_k<0,0><<<dim3(64,1),256,0,stream>>>((const unsigned short*)xcb, (const unsigned short*)WtXp,
        nullptr, fw+O_PROJ, 32, nullptr, 0, NL, 512, 32);
    cast_pad_k<<<512,256,0,stream>>>(fw+O_PROJ, dtab);
    mg_k<2,0><<<dim3(64,8),256,0,stream>>>((const unsigned short*)dtab, (const unsigned short*)WtDt,
        dtb, fw+O_DELTA, 512, nullptr, 0, NL, 32, 512);
    scan1_k<<<512,256,0,stream>>>(fw+O_DELTA, fw+O_XC, fw+O_PROJ, Alog, scanP, scanHl);
    scan2p_k<<<4096,256,0,stream>>>(scanP, scanHl, scanHst);
    scan3_k<<<512,256,0,stream>>>(fw+O_DELTA, fw+O_XC, fw+O_PROJ, Alog, scanHst, Dp, xzb, yb);
    mg_k<0,1><<<dim3(64,4),256,0,stream>>>((const unsigned short*)yb, (const unsigned short*)WtOut,
        nullptr, catb + 256, 768, nullptr, 0, NL, 512, 256);

    // attention: fused QK GEMM (Q scaled 0.125), V transposed, 8-way split-K
    mg_k<3,1><<<dim3(64,8),256,0,stream>>>((const unsigned short*)h2b, (const unsigned short*)WtQK,
        b512, qkB, 512, nullptr, 0, NL, 256, 512);
    mg_k<0,2><<<dim3(64,4),256,0,stream>>>((const unsigned short*)h2b, (const unsigned short*)WtV,
        bv, vtB, NL, nullptr, 0, NL, 256, 256);
    attn_part_k<<<dim3(64,4,8),256,0,stream>>>((const unsigned short*)qkB,
        (const unsigned short*)vtB, op, lsum);
    amerge_k<<<4096,256,0,stream>>>(op, lsum, aob);
    mg_k<0,1><<<dim3(64,4),256,0,stream>>>((const unsigned short*)aob, (const unsigned short*)WtO,
        bo, catb + 512, 768, nullptr, 0, NL, 256, 256);

    // fuse + residual + LN(+pool) + heads
    mg_k<1,0><<<dim3(64,4),256,0,stream>>>((const unsigned short*)catb, (const unsigned short*)WtFus,
        fusb, fused, 256, fw+O_H2, 256, NL, 768, 256);
    ln_k<<<4096,256,0,stream>>>(fused, lng, lnb, fw+O_POOL);
    heads_k<<<(NOUT+3)/4,256,0,stream>>>(fw+O_POOL, cwp,cbp,hwp,hbp,twp,tbp,p1w,p1b,p2w,p2b,
                                         dwp,dbp,swp,sbp, (float*)d_out);
}

// Round 12
// 391.047 us; speedup vs baseline: 5.4274x; 1.0566x over previous
//
#include <hip/hip_runtime.h>
#include <hip/hip_bf16.h>
#include <math.h>

typedef __hip_bfloat16 hbf;
typedef short bf16x8 __attribute__((ext_vector_type(8)));
typedef float f32x4 __attribute__((ext_vector_type(4)));

// ---------------- problem constants ----------------
constexpr int NL  = 4096;
constexpr int HH  = 256;
constexpr int NE  = 8192;
constexpr int DIc = 512;
constexpr int DSc = 8;
constexpr int NCH = 256;   // scan chunks
constexpr int CLc = 16;    // chunk length
constexpr int NOUT = 12416;

// ---------------- workspace layout (float offsets) ----------------
constexpr size_t O_MBUF  = 0;         // 1048576  gcn msgs; scan P; attn op0/op1(bf16)
constexpr size_t O_QK    = 1048576;   // 1048576  scan Hl; qkB bf16 [NL][512]
constexpr size_t O_H2    = 2097152;   // 1048576  h2 fp32 (live to fus resid)
constexpr size_t O_CATB  = 3145728;   // 1572864  catb bf16 [NL][768]
constexpr size_t O_XZB   = 4718592;   // 2097152  xzb bf16 [NL][1024]; op6/op7(bf16)
constexpr size_t O_XC    = 6815744;   // 2097152  xc fp32; vtB bf16@+0; fused fp32@+0
constexpr size_t O_DELTA = 8912896;   // 2097152  delta; op2..op5(bf16)
constexpr size_t O_PROJ  = 11010048;  // 131072   proj fp32; lsum after
constexpr size_t O_HST   = 11141120;  // 1048576  Hst
constexpr size_t O_Y     = 12189696;  // 1048576  yb bf16; aob bf16
constexpr size_t O_POOL  = 13238272;  // 2048
constexpr size_t O_DINV  = 13240320;  // 4096
constexpr size_t O_B768  = 13244416;  // 768
constexpr size_t O_INT   = 13245184;  // 81928 ints
constexpr size_t O_WT    = 13327112;  // 512000
constexpr size_t O_XB    = 13839112;  // 65536
constexpr size_t O_H0B   = 13904648;  // 524288
constexpr size_t O_H2B   = 14428936;  // 524288
constexpr size_t O_XCB   = 14953224;  // 1048576
constexpr size_t O_DTAB  = 16001800;  // 65536
// total 16067336 floats = 64.3 MB (ws_size = 256 MB)

// ---------------- weight transpose-cast table ----------------
constexpr int NW = 12;
__device__ __constant__ int wc_cum[NW+1] = {
    0, 8192, 73728, 139264, 401408, 417792, 434176, 565248,
    630784, 696320, 761856, 827392, 1024000 };
__device__ __constant__ int wc_K [NW] = {32,256,256,256,512,16,512,256,256,256,256,768};
__device__ __constant__ int wc_N [NW] = {256,256,256,1024,32,512,256,256,256,256,256,256};
__device__ __constant__ int wc_Kp[NW] = {32,256,256,256,512,32,512,256,256,256,256,768};
struct WSrc { const float* p[NW]; };
struct OPtrs { hbf* p[8]; };

// prep: weight transpose-cast + x cast + b768 + pooled zero + indeg zero
constexpr int PR_W = 1024000;
constexpr int PR_X = PR_W + 131072;    // 1155072
constexpr int PR_B = PR_X + 768;       // 1155840
constexpr int PR_P = PR_B + 2048;      // 1157888
constexpr int PR_I = PR_P + 4096;      // 1161984
__global__ __launch_bounds__(256) void prep_k(WSrc ws, hbf* __restrict__ wt,
        const float* __restrict__ x, hbf* __restrict__ xb,
        const float* __restrict__ bq, const float* __restrict__ bk,
        const float* __restrict__ bv,
        float* __restrict__ b768, float* __restrict__ pooled, int* __restrict__ indeg) {
    int idx = blockIdx.x*256 + threadIdx.x;
    if (idx < PR_W) {
        int lo = 0, hi = NW-1;
        while (lo < hi) { int mid = (lo+hi+1)>>1; if (idx >= wc_cum[mid]) lo = mid; else hi = mid-1; }
        int local = idx - wc_cum[lo];
        int Kp = wc_Kp[lo], K = wc_K[lo], N = wc_N[lo];
        int n = local / Kp, k = local - n*Kp;
        float v = (k < K) ? ws.p[lo][(size_t)k*N + n] : 0.0f;
        wt[idx] = __float2bfloat16(v);
    } else if (idx < PR_X) {
        int i = idx - PR_W;
        xb[i] = __float2bfloat16(x[i]);
    } else if (idx < PR_B) {
        int i = idx - PR_X;
        b768[i] = (i < 256) ? bq[i] : (i < 512 ? bk[i-256] : bv[i-512]);
    } else if (idx < PR_P) {
        pooled[idx - PR_B] = 0.0f;
    } else if (idx < PR_I) {
        indeg[idx - PR_P] = 0;
    }
}

// ---------------- graph prep ----------------
__global__ void count_k(const int* __restrict__ ei, int* __restrict__ indeg) {
    int i = blockIdx.x*256 + threadIdx.x;
    int b = i >> 13, e = i & 8191;
    int dst = ei[b*2*NE + NE + e] + (b << 9);
    atomicAdd(&indeg[dst], 1);
}

__global__ __launch_bounds__(1024) void prefix_k(const int* __restrict__ indeg,
                                                 int* __restrict__ row_start,
                                                 int* __restrict__ cursor,
                                                 float* __restrict__ dinv) {
    __shared__ int part[1024];
    int t = threadIdx.x;
    int v0[4]; int s = 0;
    #pragma unroll
    for (int i = 0; i < 4; i++) {
        int cnt = indeg[t*4 + i];
        v0[i] = s; s += cnt;
        dinv[t*4 + i] = rsqrtf(1.0f + (float)cnt);
    }
    part[t] = s;
    __syncthreads();
    for (int o = 1; o < 1024; o <<= 1) {
        int x = (t >= o) ? part[t-o] : 0;
        __syncthreads();
        part[t] += x;
        __syncthreads();
    }
    int base = (t > 0) ? part[t-1] : 0;
    #pragma unroll
    for (int i = 0; i < 4; i++) {
        int rs = base + v0[i];
        row_start[t*4+i] = rs; cursor[t*4+i] = rs;
    }
    if (t == 1023) row_start[4096] = part[1023];
}

__global__ void scatter_k(const int* __restrict__ ei, int* __restrict__ cursor,
                          int* __restrict__ csr) {
    int i = blockIdx.x*256 + threadIdx.x;
    int b = i >> 13, e = i & 8191;
    int src = ei[b*2*NE + e]       + (b << 9);
    int dst = ei[b*2*NE + NE + e]  + (b << 9);
    int pos = atomicAdd(&cursor[dst], 1);
    csr[pos] = src;
}

// gather; MODE 1 adds fp32 out + catb(cols 0..255) write
template<int MODE>
__global__ __launch_bounds__(256) void gather_k(const float* __restrict__ m,
                        const int* __restrict__ csr, const int* __restrict__ row_start,
                        const float* __restrict__ dinv, const float* __restrict__ bias,
                        float* __restrict__ out, hbf* __restrict__ outb,
                        hbf* __restrict__ catb) {
    int n = blockIdx.x, c = threadIdx.x;
    float dn = dinv[n];
    float acc = m[(size_t)n*HH + c] * dn * dn;
    int e0 = row_start[n], e1 = row_start[n+1];
    for (int e = e0; e < e1; e++) {
        int s = csr[e];
        acc += m[(size_t)s*HH + c] * (dinv[s] * dn);
    }
    float r = fmaxf(acc + bias[c], 0.0f);
    if (MODE) {
        out[(size_t)n*HH + c] = r;
        catb[(size_t)n*768 + c] = __float2bfloat16(r);
    }
    outb[(size_t)n*HH + c] = __float2bfloat16(r);
}

// ---------------- bf16 MFMA GEMM: 512 threads / 8 waves, 64x64 tile, BK=64 ----------------
// OUTM: 0 fp32, 1 bf16, 2 bf16 transposed, 3 QKV mixed (qkB + vtB), 4 proj+dtab
// ACT: 0 none, 1 relu, 2 softplus
template<int ACT, int OUTM>
__global__ __launch_bounds__(512) void mg_k(const unsigned short* __restrict__ A,
        const unsigned short* __restrict__ Bt, const float* __restrict__ bias,
        void* __restrict__ Cp, int ldc, void* __restrict__ Cp2,
        const float* __restrict__ resid, int ldr, int M, int K, int N)
{
    __shared__ __align__(16) unsigned short Asm[2][64][40];
    __shared__ __align__(16) unsigned short Bsm[2][64][40];
    int t = threadIdx.x;
    int lane = t & 63, w = t >> 6;
    int wm = w & 3, wn = w >> 2;            // 4 row strips x 2 col strips
    int row0 = blockIdx.x * 64, col0 = blockIdx.y * 64;
    int sr = t >> 3;                        // staging row 0..63
    int sk8 = (t & 7) * 8;                  // staging k offset 0..56
    int su = sk8 >> 5, so = sk8 & 31;
    f32x4 acc0 = {}, acc1 = {};
    int fr = lane & 15, fq8 = (lane >> 4) * 8;

    uint4 zz = make_uint4(0u,0u,0u,0u);
    uint4 ra = zz, rb = zz;
    bool bnv = (col0 + sr) < N;
    if (sk8 < K) {
        ra = *(const uint4*)&A[(size_t)(row0+sr)*K + sk8];
        if (bnv) rb = *(const uint4*)&Bt[(size_t)(col0+sr)*K + sk8];
    }

    for (int k0 = 0; k0 < K; k0 += 64) {
        __syncthreads();
        *(uint4*)&Asm[su][sr][so] = ra;
        *(uint4*)&Bsm[su][sr][so] = rb;
        __syncthreads();
        int kn = k0 + 64;
        if (kn < K) {
            ra = rb = zz;
            if (kn + sk8 < K) {
                ra = *(const uint4*)&A[(size_t)(row0+sr)*K + kn + sk8];
                if (bnv) rb = *(const uint4*)&Bt[(size_t)(col0+sr)*K + kn + sk8];
            }
        }
        #pragma unroll
        for (int ks = 0; ks < 2; ks++) {
            bf16x8 a  = *(bf16x8*)&Asm[ks][wm*16 + fr][fq8];
            bf16x8 b0 = *(bf16x8*)&Bsm[ks][wn*32 + fr][fq8];
            bf16x8 b1 = *(bf16x8*)&Bsm[ks][wn*32 + 16 + fr][fq8];
            acc0 = __builtin_amdgcn_mfma_f32_16x16x32_bf16(a, b0, acc0, 0, 0, 0);
            acc1 = __builtin_amdgcn_mfma_f32_16x16x32_bf16(a, b1, acc1, 0, 0, 0);
        }
    }

    int fc = lane & 15, frq = (lane >> 4) * 4;
    if constexpr (OUTM == 2) {
        __shared__ __align__(16) unsigned short Ts[64][72];
        #pragma unroll
        for (int nt = 0; nt < 2; nt++) {
            int col = col0 + wn*32 + nt*16 + fc;
            float bvv = bias ? bias[col] : 0.0f;
            f32x4& av = nt ? acc1 : acc0;
            #pragma unroll
            for (int i = 0; i < 4; i++)
                *(hbf*)&Ts[wn*32 + nt*16 + fc][wm*16 + frq + i] = __float2bfloat16(av[i] + bvv);
        }
        __syncthreads();
        int c = t >> 3, rs = (t & 7) * 8;
        if (col0 + c < N)
            *(uint4*)((hbf*)Cp + (size_t)(col0 + c)*ldc + row0 + rs) = *(uint4*)&Ts[c][rs];
    } else if constexpr (OUTM == 3) {
        // cols < 512: qkB bf16 [NL][512], scale 0.125 if col<256; cols >= 512: transposed vtB
        if (col0 < 512) {
            #pragma unroll
            for (int nt = 0; nt < 2; nt++) {
                int col = col0 + wn*32 + nt*16 + fc;
                float bvv = bias[col];
                float sc = (col < 256) ? 0.125f : 1.0f;
                f32x4& av = nt ? acc1 : acc0;
                #pragma unroll
                for (int i = 0; i < 4; i++) {
                    int row = row0 + wm*16 + frq + i;
                    ((hbf*)Cp)[(size_t)row*512 + col] = __float2bfloat16((av[i] + bvv) * sc);
                }
            }
        } else {
            __shared__ __align__(16) unsigned short Ts[64][72];
            #pragma unroll
            for (int nt = 0; nt < 2; nt++) {
                int col = col0 + wn*32 + nt*16 + fc;
                float bvv = bias[col];
                f32x4& av = nt ? acc1 : acc0;
                #pragma unroll
                for (int i = 0; i < 4; i++)
                    *(hbf*)&Ts[wn*32 + nt*16 + fc][wm*16 + frq + i] = __float2bfloat16(av[i] + bvv);
            }
            __syncthreads();
            int c = t >> 3, rs = (t & 7) * 8;
            *(uint4*)((hbf*)Cp2 + (size_t)(col0 - 512 + c)*NL + row0 + rs) = *(uint4*)&Ts[c][rs];
        }
    } else if constexpr (OUTM == 4) {
        // proj fp32 [NL][32] + dtab bf16 [NL][32] (cols 16..31 zero)
        #pragma unroll
        for (int nt = 0; nt < 2; nt++) {
            int col = col0 + wn*32 + nt*16 + fc;
            if (col >= 32) continue;
            f32x4& av = nt ? acc1 : acc0;
            #pragma unroll
            for (int i = 0; i < 4; i++) {
                int row = row0 + wm*16 + frq + i;
                float v = av[i];
                ((float*)Cp)[(size_t)row*32 + col] = v;
                ((hbf*)Cp2)[(size_t)row*32 + col] = __float2bfloat16((col < 16) ? v : 0.0f);
            }
        }
    } else {
        #pragma unroll
        for (int nt = 0; nt < 2; nt++) {
            int col = col0 + wn*32 + nt*16 + fc;
            if (col >= N) continue;
            float bvv = bias ? bias[col] : 0.0f;
            f32x4& av = nt ? acc1 : acc0;
            #pragma unroll
            for (int i = 0; i < 4; i++) {
                int row = row0 + wm*16 + frq + i;
                float v = av[i] + bvv;
                if (ACT == 1) v = fmaxf(v, 0.0f);
                if (ACT == 2) v = (v > 20.0f) ? v : log1pf(expf(v));
                if (resid) v += resid[(size_t)row*ldr + col];
                if (OUTM == 0) ((float*)Cp)[(size_t)row*ldc + col] = v;
                else           ((hbf*)Cp)[(size_t)row*ldc + col] = __float2bfloat16(v);
            }
        }
    }
}

// ---------------- mamba: conv + silu ----------------
__global__ void conv_k(const hbf* __restrict__ xzb, const float* __restrict__ cW,
                       const float* __restrict__ cb, float* __restrict__ xc2,
                       hbf* __restrict__ xcb) {
    int i = blockIdx.x*256 + threadIdx.x;
    int l = i >> 9, d = i & 511;
    float acc = cb[d];
    #pragma unroll
    for (int k = 0; k < 4; k++) {
        int ls = l - 3 + k;
        if (ls >= 0) acc += __bfloat162float(xzb[(size_t)ls*1024 + d]) * cW[d*4 + k];
    }
    float r = acc / (1.0f + __expf(-acc));
    xc2[i] = r;
    xcb[i] = __float2bfloat16(r);
}

// ---------------- mamba chunked scan (256 chunks x 16 steps) ----------------
__global__ __launch_bounds__(256) void scan1_k(const float* __restrict__ delta,
                        const float* __restrict__ xc, const float* __restrict__ proj,
                        const float* __restrict__ Alog,
                        float* __restrict__ P, float* __restrict__ Hl)
{
    int c = blockIdx.x >> 1;
    int d = ((blockIdx.x & 1) << 8) + threadIdx.x;
    float Ac[DSc], pr[DSc], h[DSc];
    #pragma unroll
    for (int s2 = 0; s2 < DSc; s2++) { Ac[s2] = -__expf(Alog[d*DSc+s2]); pr[s2]=1.0f; h[s2]=0.0f; }
    int l0 = c * CLc;
    for (int l = l0; l < l0 + CLc; l++) {
        float dl = delta[(size_t)l*DIc + d];
        float dx = dl * xc[(size_t)l*DIc + d];
        const float* pb = proj + l*32 + 16;
        #pragma unroll
        for (int s2 = 0; s2 < DSc; s2++) {
            float a = __expf(dl * Ac[s2]);
            h[s2] = a*h[s2] + dx*pb[s2];
            pr[s2] *= a;
        }
    }
    #pragma unroll
    for (int s2 = 0; s2 < DSc; s2++) {
        P [(size_t)(c*DSc+s2)*DIc + d] = pr[s2];
        Hl[(size_t)(c*DSc+s2)*DIc + d] = h[s2];
    }
}

// log-scan over 256 chunks; one series per block (grid 4096)
__global__ __launch_bounds__(256) void scan2p_k(const float* __restrict__ P,
                        const float* __restrict__ Hl, float* __restrict__ Hst) {
    __shared__ float Psh[256], Hsh[256];
    int t = threadIdx.x, series = blockIdx.x;
    size_t off = (size_t)t*4096 + series;
    float Pc = P[off], Hc = Hl[off];
    Psh[t] = Pc; Hsh[t] = Hc;
    __syncthreads();
    #pragma unroll
    for (int st = 1; st < 256; st <<= 1) {
        float p1 = 1.0f, h1 = 0.0f;
        if (t >= st) { p1 = Psh[t-st]; h1 = Hsh[t-st]; }
        __syncthreads();
        Hc = Pc*h1 + Hc;
        Pc = Pc*p1;
        Psh[t] = Pc; Hsh[t] = Hc;
        __syncthreads();
    }
    Hst[off] = (t == 0) ? 0.0f : Hsh[t-1];
}

__global__ __launch_bounds__(256) void scan3_k(const float* __restrict__ delta,
                        const float* __restrict__ xc, const float* __restrict__ proj,
                        const float* __restrict__ Alog, const float* __restrict__ Hst,
                        const float* __restrict__ Dp, const hbf* __restrict__ xzb,
                        hbf* __restrict__ Y)
{
    int c = blockIdx.x >> 1;
    int d = ((blockIdx.x & 1) << 8) + threadIdx.x;
    float Ac[DSc], h[DSc];
    #pragma unroll
    for (int s2 = 0; s2 < DSc; s2++) {
        Ac[s2] = -__expf(Alog[d*DSc+s2]);
        h[s2]  = Hst[(size_t)(c*DSc+s2)*DIc + d];
    }
    float dpv = Dp[d];
    int l0 = c * CLc;
    for (int l = l0; l < l0 + CLc; l++) {
        float dl = delta[(size_t)l*DIc + d];
        float xv = xc[(size_t)l*DIc + d];
        float dx = dl * xv;
        const float* pb = proj + l*32 + 16;
        float y = 0.0f;
        #pragma unroll
        for (int s2 = 0; s2 < DSc; s2++) {
            float a = __expf(dl * Ac[s2]);
            h[s2] = a*h[s2] + dx*pb[s2];
            y += h[s2] * pb[8+s2];
        }
        float z = __bfloat162float(xzb[(size_t)l*1024 + 512 + d]);
        float sz = z / (1.0f + __expf(-z));
        Y[(size_t)l*DIc + d] = __float2bfloat16((y + dpv*xv) * sz);
    }
}

// ---------------- split-K(8) MFMA flash attention, constant-shift softmax ----------------
__global__ __launch_bounds__(256) void attn_part_k(const unsigned short* __restrict__ QK,
                       const unsigned short* __restrict__ Vt,
                       OPtrs op, float* __restrict__ lsum)
{
    __shared__ __align__(16) unsigned short Qs[64][72];
    __shared__ __align__(16) unsigned short Ks[64][72];
    __shared__ __align__(16) unsigned short Vs[64][72];
    __shared__ __align__(16) unsigned short Ps[64][72];
    int t = threadIdx.x, lane = t & 63, w = t >> 6;
    int h = blockIdx.y, q0 = blockIdx.x * 64, skc = blockIdx.z;
    int sr = t >> 2, sk = (t & 3) * 16;
    int fm = lane & 15, fq = lane >> 4;

    *(uint4*)&Qs[sr][sk]     = *(const uint4*)&QK[(size_t)(q0+sr)*512 + h*64 + sk];
    *(uint4*)&Qs[sr][sk + 8] = *(const uint4*)&QK[(size_t)(q0+sr)*512 + h*64 + sk + 8];
    __syncthreads();
    bf16x8 qa0 = *(bf16x8*)&Qs[w*16 + fm][fq*8];
    bf16x8 qa1 = *(bf16x8*)&Qs[w*16 + fm][32 + fq*8];

    const unsigned short* Kb = QK + 256;
    bf16x8 ones;
    #pragma unroll
    for (int j = 0; j < 8; j++) ones[j] = (short)0x3F80;

    f32x4 o[4] = {};
    f32x4 ol = {};
    int kt = skc * 512;
    uint4 ka  = *(const uint4*)&Kb[(size_t)(kt+sr)*512 + h*64 + sk];
    uint4 kb2 = *(const uint4*)&Kb[(size_t)(kt+sr)*512 + h*64 + sk + 8];
    uint4 va  = *(const uint4*)&Vt[(size_t)(h*64+sr)*NL + kt + sk];
    uint4 vb2 = *(const uint4*)&Vt[(size_t)(h*64+sr)*NL + kt + sk + 8];

    for (int it = 0; it < 8; it++) {
        __syncthreads();
        *(uint4*)&Ks[sr][sk] = ka;  *(uint4*)&Ks[sr][sk+8] = kb2;
        *(uint4*)&Vs[sr][sk] = va;  *(uint4*)&Vs[sr][sk+8] = vb2;
        __syncthreads();
        if (it < 7) {
            int kn = kt + 64;
            ka  = *(const uint4*)&Kb[(size_t)(kn+sr)*512 + h*64 + sk];
            kb2 = *(const uint4*)&Kb[(size_t)(kn+sr)*512 + h*64 + sk + 8];
            va  = *(const uint4*)&Vt[(size_t)(h*64+sr)*NL + kn + sk];
            vb2 = *(const uint4*)&Vt[(size_t)(h*64+sr)*NL + kn + sk + 8];
        }
        f32x4 s[4] = {};
        #pragma unroll
        for (int nt = 0; nt < 4; nt++) {
            bf16x8 b0 = *(bf16x8*)&Ks[nt*16 + fm][fq*8];
            bf16x8 b1 = *(bf16x8*)&Ks[nt*16 + fm][32 + fq*8];
            s[nt] = __builtin_amdgcn_mfma_f32_16x16x32_bf16(qa0, b0, s[nt], 0, 0, 0);
            s[nt] = __builtin_amdgcn_mfma_f32_16x16x32_bf16(qa1, b1, s[nt], 0, 0, 0);
        }
        #pragma unroll
        for (int nt = 0; nt < 4; nt++) {
            #pragma unroll
            for (int i = 0; i < 4; i++) {
                float p = __expf(s[nt][i] - 4.0f);
                *(hbf*)&Ps[w*16 + fq*4 + i][nt*16 + fm] = __float2bfloat16(p);
            }
        }
        #pragma unroll
        for (int ks = 0; ks < 2; ks++) {
            bf16x8 a = *(bf16x8*)&Ps[w*16 + fm][ks*32 + fq*8];
            #pragma unroll
            for (int nt = 0; nt < 4; nt++) {
                bf16x8 b = *(bf16x8*)&Vs[nt*16 + fm][ks*32 + fq*8];
                o[nt] = __builtin_amdgcn_mfma_f32_16x16x32_bf16(a, b, o[nt], 0, 0, 0);
            }
            ol = __builtin_amdgcn_mfma_f32_16x16x32_bf16(a, ones, ol, 0, 0, 0);
        }
        kt += 64;
    }
    hbf* Op = op.p[skc];
    #pragma unroll
    for (int i = 0; i < 4; i++) {
        int row = w*16 + fq*4 + i;
        #pragma unroll
        for (int nt = 0; nt < 4; nt++)
            Op[(size_t)(q0 + row)*HH + h*64 + nt*16 + fm] = __float2bfloat16(o[nt][i]);
    }
    if (fm == 0) {
        #pragma unroll
        for (int i = 0; i < 4; i++)
            lsum[(size_t)(skc*4 + h)*NL + q0 + w*16 + fq*4 + i] = ol[i];
    }
}

// exact merge: O = sum_c Oc / sum_c lc
__global__ __launch_bounds__(256) void amerge_k(OPtrs op, const float* __restrict__ lsum,
                                                hbf* __restrict__ aob) {
    int row = blockIdx.x, t = threadIdx.x, h = t >> 6;
    float L = 0.0f, s = 0.0f;
    #pragma unroll
    for (int c = 0; c < 8; c++) {
        L += lsum[(size_t)(c*4 + h)*NL + row];
        s += __bfloat162float(op.p[c][(size_t)row*HH + t]);
    }
    aob[(size_t)row*HH + t] = __float2bfloat16(s / L);
}

// ---------------- layernorm + fused pooling (atomic) ----------------
__global__ __launch_bounds__(256) void ln_k(const float* __restrict__ X,
                    const float* __restrict__ g, const float* __restrict__ b,
                    float* __restrict__ pooled) {
    __shared__ float red[4];
    int r = blockIdx.x, t = threadIdx.x;
    float v = X[(size_t)r*HH + t];
    float s = v;
    #pragma unroll
    for (int o = 32; o > 0; o >>= 1) s += __shfl_down(s, o);
    if ((t & 63) == 0) red[t >> 6] = s;
    __syncthreads();
    float mean = (red[0]+red[1]+red[2]+red[3]) * (1.0f/256.0f);
    float dfv = v - mean;
    float s2 = dfv*dfv;
    #pragma unroll
    for (int o = 32; o > 0; o >>= 1) s2 += __shfl_down(s2, o);
    __syncthreads();
    if ((t & 63) == 0) red[t >> 6] = s2;
    __syncthreads();
    float var = (red[0]+red[1]+red[2]+red[3]) * (1.0f/256.0f);
    float y = dfv * rsqrtf(var + 1e-5f) * g[t] + b[t];
    atomicAdd(&pooled[(r >> 9)*HH + t], y * (1.0f/512.0f));
}

// ---------------- heads: wave per output ----------------
__global__ __launch_bounds__(256) void heads_k(const float* __restrict__ pooled,
        const float* cw, const float* cbh, const float* hw, const float* hb,
        const float* tw, const float* tb, const float* p1w, const float* p1b,
        const float* p2w, const float* p2b, const float* dw, const float* db,
        const float* sw, const float* sb, float* __restrict__ out)
{
    int idx = blockIdx.x*4 + (threadIdx.x >> 6);
    int lane = threadIdx.x & 63;
    if (idx >= NOUT) return;
    int b = idx / 1552, j = idx - b*1552;
    const float* w; const float* bi; int col, nc;
    if (j < 1)         { w = cw;  bi = cbh; col = j;        nc = 1;   }
    else if (j < 5)    { w = hw;  bi = hb;  col = j - 1;    nc = 4;   }
    else if (j < 8)    { w = tw;  bi = tb;  col = j - 5;    nc = 3;   }
    else if (j < 520)  { w = p1w; bi = p1b; col = j - 8;    nc = 512; }
    else if (j < 1032) { w = p2w; bi = p2b; col = j - 520;  nc = 512; }
    else if (j < 1544) { w = dw;  bi = db;  col = j - 1032; nc = 512; }
    else               { w = sw;  bi = sb;  col = j - 1544; nc = 8;   }
    const float* pl = pooled + b*HH;
    float s = 0.0f;
    #pragma unroll
    for (int k = lane; k < 256; k += 64) s = fmaf(pl[k], w[(size_t)k*nc + col], s);
    #pragma unroll
    for (int o = 32; o > 0; o >>= 1) s += __shfl_down(s, o);
    if (lane == 0) out[idx] = s + bi[col];
}

// ---------------- launcher ----------------
extern "C" void kernel_launch(void* const* d_in, const int* in_sizes, int n_in,
                              void* d_out, int out_size, void* d_ws, size_t ws_size,
                              hipStream_t stream)
{
    (void)in_sizes; (void)n_in; (void)out_size; (void)ws_size;
    const float* x      = (const float*)d_in[0];
    const int*   ei     = (const int*)  d_in[1];
    const float* W_init = (const float*)d_in[2];
    const float* b_init = (const float*)d_in[3];
    const float* g1W = (const float*)d_in[4];
    const float* g1b = (const float*)d_in[5];
    const float* g2W = (const float*)d_in[6];
    const float* g2b = (const float*)d_in[7];
    const float* inW = (const float*)d_in[8];
    const float* cW  = (const float*)d_in[9];
    const float* cb  = (const float*)d_in[10];
    const float* xpW = (const float*)d_in[11];
    const float* dtW = (const float*)d_in[12];
    const float* dtb = (const float*)d_in[13];
    const float* Alog= (const float*)d_in[14];
    const float* Dp  = (const float*)d_in[15];
    const float* outW= (const float*)d_in[16];
    const float* Wq  = (const float*)d_in[17];
    const float* bq  = (const float*)d_in[18];
    const float* Wk  = (const float*)d_in[19];
    const float* bk  = (const float*)d_in[20];
    const float* Wv  = (const float*)d_in[21];
    const float* bv  = (const float*)d_in[22];
    const float* Wo  = (const float*)d_in[23];
    const float* bo  = (const float*)d_in[24];
    const float* fusW= (const float*)d_in[25];
    const float* fusb= (const float*)d_in[26];
    const float* lng = (const float*)d_in[27];
    const float* lnb = (const float*)d_in[28];
    const float* cwp = (const float*)d_in[29];
    const float* cbp = (const float*)d_in[30];
    const float* hwp = (const float*)d_in[31];
    const float* hbp = (const float*)d_in[32];
    const float* twp = (const float*)d_in[33];
    const float* tbp = (const float*)d_in[34];
    const float* p1w = (const float*)d_in[35];
    const float* p1b = (const float*)d_in[36];
    const float* p2w = (const float*)d_in[37];
    const float* p2b = (const float*)d_in[38];
    const float* dwp = (const float*)d_in[39];
    const float* dbp = (const float*)d_in[40];
    const float* swp = (const float*)d_in[41];
    const float* sbp = (const float*)d_in[42];

    float* fw = (float*)d_ws;
    int* iw = (int*)(fw + O_INT);
    int* indeg = iw;
    int* row_start = iw + 4096;
    int* cursor = iw + 8193;
    int* csr = iw + 12289;
    float* dinv = fw + O_DINV;

    hbf* wt   = (hbf*)(fw + O_WT);
    hbf* xb   = (hbf*)(fw + O_XB);
    hbf* h0b  = (hbf*)(fw + O_H0B);
    hbf* h2b  = (hbf*)(fw + O_H2B);
    hbf* xcb  = (hbf*)(fw + O_XCB);
    hbf* dtab = (hbf*)(fw + O_DTAB);
    hbf* xzb  = (hbf*)(fw + O_XZB);
    hbf* yb   = (hbf*)(fw + O_Y);
    hbf* aob  = (hbf*)(fw + O_Y);
    hbf* catb = (hbf*)(fw + O_CATB);
    hbf* qkB  = (hbf*)(fw + O_QK);
    hbf* vtB  = (hbf*)(fw + O_XC);
    float* fused = fw + O_XC;
    float* b768 = fw + O_B768;

    float* scanP  = fw + O_MBUF;
    float* scanHl = fw + O_QK;
    float* scanHst= fw + O_HST;

    OPtrs op;
    op.p[0] = (hbf*)(fw + O_MBUF);
    op.p[1] = (hbf*)(fw + O_MBUF + 524288);
    op.p[2] = (hbf*)(fw + O_DELTA);
    op.p[3] = (hbf*)(fw + O_DELTA + 524288);
    op.p[4] = (hbf*)(fw + O_DELTA + 1048576);
    op.p[5] = (hbf*)(fw + O_DELTA + 1572864);
    op.p[6] = (hbf*)(fw + O_XZB);
    op.p[7] = (hbf*)(fw + O_XZB + 524288);
    float* lsum = fw + O_PROJ + 0;       // proj dead after scan3? no — lsum after scan3, proj dead then
    lsum = fw + O_HST;                   // Hst dead after scan3 (1M floats, lsum needs 131072)

    hbf* WtInit = wt + 0;
    hbf* WtG1   = wt + 8192;
    hbf* WtG2   = wt + 73728;
    hbf* WtIn   = wt + 139264;
    hbf* WtXp   = wt + 401408;
    hbf* WtDt   = wt + 417792;
    hbf* WtOut  = wt + 434176;
    hbf* WtQKV  = wt + 565248;           // WtQ|WtK|WtV contiguous (N=768)
    hbf* WtO    = wt + 761856;
    hbf* WtFus  = wt + 827392;

    WSrc wsrc;
    wsrc.p[0]=W_init; wsrc.p[1]=g1W; wsrc.p[2]=g2W; wsrc.p[3]=inW; wsrc.p[4]=xpW;
    wsrc.p[5]=dtW; wsrc.p[6]=outW; wsrc.p[7]=Wq; wsrc.p[8]=Wk; wsrc.p[9]=Wv;
    wsrc.p[10]=Wo; wsrc.p[11]=fusW;
    prep_k<<<(PR_I+255)/256,256,0,stream>>>(wsrc, wt, x, xb, bq, bk, bv, b768,
                                            fw+O_POOL, indeg);

    // graph prep
    count_k<<<256,256,0,stream>>>(ei, indeg);
    prefix_k<<<1,1024,0,stream>>>(indeg, row_start, cursor, dinv);
    scatter_k<<<256,256,0,stream>>>(ei, cursor, csr);

    // h0 = relu(x @ W_init + b_init) -> bf16
    mg_k<1,1><<<dim3(64,4),512,0,stream>>>((const unsigned short*)xb, (const unsigned short*)WtInit,
        b_init, h0b, 256, nullptr, nullptr, 0, NL, 32, 256);
    // gcn1
    mg_k<0,0><<<dim3(64,4),512,0,stream>>>((const unsigned short*)h0b, (const unsigned short*)WtG1,
        nullptr, fw+O_MBUF, 256, nullptr, nullptr, 0, NL, 256, 256);
    gather_k<0><<<4096,256,0,stream>>>(fw+O_MBUF, csr, row_start, dinv, g1b, nullptr, h0b, nullptr);
    // gcn2 (fp32 h2 + bf16 h2b + catb cols 0..255)
    mg_k<0,0><<<dim3(64,4),512,0,stream>>>((const unsigned short*)h0b, (const unsigned short*)WtG2,
        nullptr, fw+O_MBUF, 256, nullptr, nullptr, 0, NL, 256, 256);
    gather_k<1><<<4096,256,0,stream>>>(fw+O_MBUF, csr, row_start, dinv, g2b, fw+O_H2, h2b, catb);

    // mamba
    mg_k<0,1><<<dim3(64,16),512,0,stream>>>((const unsigned short*)h2b, (const unsigned short*)WtIn,
        nullptr, xzb, 1024, nullptr, nullptr, 0, NL, 256, 1024);
    conv_k<<<8192,256,0,stream>>>(xzb, cW, cb, fw+O_XC, xcb);
    mg_k<0,4><<<dim3(64,1),512,0,stream>>>((const unsigned short*)xcb, (const unsigned short*)WtXp,
        nullptr, fw+O_PROJ, 32, dtab, nullptr, 0, NL, 512, 32);
    mg_k<2,0><<<dim3(64,8),512,0,stream>>>((const unsigned short*)dtab, (const unsigned short*)WtDt,
        dtb, fw+O_DELTA, 512, nullptr, nullptr, 0, NL, 32, 512);
    scan1_k<<<512,256,0,stream>>>(fw+O_DELTA, fw+O_XC, fw+O_PROJ, Alog, scanP, scanHl);
    scan2p_k<<<4096,256,0,stream>>>(scanP, scanHl, scanHst);
    scan3_k<<<512,256,0,stream>>>(fw+O_DELTA, fw+O_XC, fw+O_PROJ, Alog, scanHst, Dp, xzb, yb);
    mg_k<0,1><<<dim3(64,4),512,0,stream>>>((const unsigned short*)yb, (const unsigned short*)WtOut,
        nullptr, catb + 256, 768, nullptr, nullptr, 0, NL, 512, 256);

    // attention: fused QKV GEMM (Q scaled, V transposed), 8-way split-K
    mg_k<0,3><<<dim3(64,12),512,0,stream>>>((const unsigned short*)h2b, (const unsigned short*)WtQKV,
        b768, qkB, 512, vtB, nullptr, 0, NL, 256, 768);
    attn_part_k<<<dim3(64,4,8),256,0,stream>>>((const unsigned short*)qkB,
        (const unsigned short*)vtB, op, lsum);
    amerge_k<<<4096,256,0,stream>>>(op, lsum, aob);
    mg_k<0,1><<<dim3(64,4),512,0,stream>>>((const unsigned short*)aob, (const unsigned short*)WtO,
        bo, catb + 512, 768, nullptr, nullptr, 0, NL, 256, 256);

    // fuse + residual + LN(+pool) + heads
    mg_k<1,0><<<dim3(64,4),512,0,stream>>>((const unsigned short*)catb, (const unsigned short*)WtFus,
        fusb, fused, 256, nullptr, fw+O_H2, 256, NL, 768, 256);
    ln_k<<<4096,256,0,stream>>>(fused, lng, lnb, fw+O_POOL);
    heads_k<<<(NOUT+3)/4,256,0,stream>>>(fw+O_POOL, cwp,cbp,hwp,hbp,twp,tbp,p1w,p1b,p2w,p2b,
                                         dwp,dbp,swp,sbp, (float*)d_out);
}

// Round 13
// 374.108 us; speedup vs baseline: 5.6731x; 1.0453x over previous
//
#include <hip/hip_runtime.h>
#include <hip/hip_bf16.h>
#include <math.h>

typedef __hip_bfloat16 hbf;
typedef short bf16x8 __attribute__((ext_vector_type(8)));
typedef float f32x4 __attribute__((ext_vector_type(4)));

// ---------------- problem constants ----------------
constexpr int NL  = 4096;
constexpr int HH  = 256;
constexpr int NE  = 8192;
constexpr int DIc = 512;
constexpr int DSc = 8;
constexpr int CLc = 16;    // scan chunk length (256 chunks)
constexpr int NOUT = 12416;

// ---------------- workspace layout (float offsets) ----------------
constexpr size_t O_MBUF  = 0;         // 1048576  gcn msgs; scan P; attn op0/op1(bf16)
constexpr size_t O_QK    = 1048576;   // 1048576  scan Hl (temp only now)
constexpr size_t O_H2    = 2097152;   // 1048576  h2 fp32 (live to fus resid)
constexpr size_t O_CATB  = 3145728;   // 1572864  catb bf16 [NL][768]
constexpr size_t O_XZB   = 4718592;   // 2097152  xzb bf16 [NL][1024]; op6/op7(bf16) after scan3
constexpr size_t O_XC    = 6815744;   // 2097152  xc fp32; fused fp32 after scans
constexpr size_t O_DELTA = 8912896;   // 2097152  delta; op2..op5(bf16) after scan3
constexpr size_t O_PROJ  = 11010048;  // 131072   proj fp32
constexpr size_t O_HST   = 11141120;  // 1048576  Hst; lsum after scan3
constexpr size_t O_Y     = 12189696;  // 1048576  yb bf16; aob bf16
constexpr size_t O_POOL  = 13238272;  // 2048
constexpr size_t O_DINV  = 13240320;  // 4096
constexpr size_t O_B768  = 13244416;  // 768
constexpr size_t O_INT   = 13245184;  // 81928 ints
constexpr size_t O_WT    = 13327112;  // 512000
constexpr size_t O_XB    = 13839112;  // 65536
constexpr size_t O_H0B   = 13904648;  // 524288
constexpr size_t O_H2B   = 14428936;  // 524288
constexpr size_t O_XCB   = 14953224;  // 1048576
constexpr size_t O_DTAB  = 16001800;  // 65536
constexpr size_t O_QKB   = 16067584;  // 1048576  qkB bf16 [NL][512] (virgin region)
constexpr size_t O_VTB   = 17116160;  // 524288   vtB bf16 [256][NL]
constexpr size_t O_PART  = 17640448;  // 262144   ln partial pools [128][2048]
// total 17902592 floats = 71.6 MB (ws = 256 MB)

// ---------------- weight transpose-cast table (reordered: in|q|k|v contiguous) ----------------
constexpr int NW = 12;
__device__ __constant__ int wc_cum[NW+1] = {
    0, 8192, 73728, 139264, 155648, 172032, 303104, 565248,
    630784, 696320, 761856, 827392, 1024000 };
__device__ __constant__ int wc_K [NW] = {32,256,256,512,16,512,256,256,256,256,256,768};
__device__ __constant__ int wc_N [NW] = {256,256,256,32,512,256,1024,256,256,256,256,256};
__device__ __constant__ int wc_Kp[NW] = {32,256,256,512,32,512,256,256,256,256,256,768};
struct WSrc { const float* p[NW]; };
struct OPtrs { hbf* p[8]; };

// prep: weight transpose-cast + x cast + b768 + part zero + indeg zero
constexpr int PR_W = 1024000;
constexpr int PR_X = PR_W + 131072;     // 1155072
constexpr int PR_B = PR_X + 768;        // 1155840
constexpr int PR_P = PR_B + 262144;     // 1417984
constexpr int PR_I = PR_P + 4096;       // 1422080
__global__ __launch_bounds__(256) void prep_k(WSrc ws, hbf* __restrict__ wt,
        const float* __restrict__ x, hbf* __restrict__ xb,
        const float* __restrict__ bq, const float* __restrict__ bk,
        const float* __restrict__ bv,
        float* __restrict__ b768, float* __restrict__ part, int* __restrict__ indeg) {
    int idx = blockIdx.x*256 + threadIdx.x;
    if (idx < PR_W) {
        int lo = 0, hi = NW-1;
        while (lo < hi) { int mid = (lo+hi+1)>>1; if (idx >= wc_cum[mid]) lo = mid; else hi = mid-1; }
        int local = idx - wc_cum[lo];
        int Kp = wc_Kp[lo], K = wc_K[lo], N = wc_N[lo];
        int n = local / Kp, k = local - n*Kp;
        float v = (k < K) ? ws.p[lo][(size_t)k*N + n] : 0.0f;
        wt[idx] = __float2bfloat16(v);
    } else if (idx < PR_X) {
        int i = idx - PR_W;
        xb[i] = __float2bfloat16(x[i]);
    } else if (idx < PR_B) {
        int i = idx - PR_X;
        b768[i] = (i < 256) ? bq[i] : (i < 512 ? bk[i-256] : bv[i-512]);
    } else if (idx < PR_P) {
        part[idx - PR_B] = 0.0f;
    } else if (idx < PR_I) {
        indeg[idx - PR_P] = 0;
    }
}

// ---------------- graph prep ----------------
__global__ void count_k(const int* __restrict__ ei, int* __restrict__ indeg) {
    int i = blockIdx.x*256 + threadIdx.x;
    int b = i >> 13, e = i & 8191;
    int dst = ei[b*2*NE + NE + e] + (b << 9);
    atomicAdd(&indeg[dst], 1);
}

__global__ __launch_bounds__(1024) void prefix_k(const int* __restrict__ indeg,
                                                 int* __restrict__ row_start,
                                                 int* __restrict__ cursor,
                                                 float* __restrict__ dinv) {
    __shared__ int part[1024];
    int t = threadIdx.x;
    int v0[4]; int s = 0;
    #pragma unroll
    for (int i = 0; i < 4; i++) {
        int cnt = indeg[t*4 + i];
        v0[i] = s; s += cnt;
        dinv[t*4 + i] = rsqrtf(1.0f + (float)cnt);
    }
    part[t] = s;
    __syncthreads();
    for (int o = 1; o < 1024; o <<= 1) {
        int x = (t >= o) ? part[t-o] : 0;
        __syncthreads();
        part[t] += x;
        __syncthreads();
    }
    int base = (t > 0) ? part[t-1] : 0;
    #pragma unroll
    for (int i = 0; i < 4; i++) {
        int rs = base + v0[i];
        row_start[t*4+i] = rs; cursor[t*4+i] = rs;
    }
    if (t == 1023) row_start[4096] = part[1023];
}

__global__ void scatter_k(const int* __restrict__ ei, int* __restrict__ cursor,
                          int* __restrict__ csr) {
    int i = blockIdx.x*256 + threadIdx.x;
    int b = i >> 13, e = i & 8191;
    int src = ei[b*2*NE + e]       + (b << 9);
    int dst = ei[b*2*NE + NE + e]  + (b << 9);
    int pos = atomicAdd(&cursor[dst], 1);
    csr[pos] = src;
}

// gather; MODE 1 adds fp32 out + catb(cols 0..255) write
template<int MODE>
__global__ __launch_bounds__(256) void gather_k(const float* __restrict__ m,
                        const int* __restrict__ csr, const int* __restrict__ row_start,
                        const float* __restrict__ dinv, const float* __restrict__ bias,
                        float* __restrict__ out, hbf* __restrict__ outb,
                        hbf* __restrict__ catb) {
    int n = blockIdx.x, c = threadIdx.x;
    float dn = dinv[n];
    float acc = m[(size_t)n*HH + c] * dn * dn;
    int e0 = row_start[n], e1 = row_start[n+1];
    for (int e = e0; e < e1; e++) {
        int s = csr[e];
        acc += m[(size_t)s*HH + c] * (dinv[s] * dn);
    }
    float r = fmaxf(acc + bias[c], 0.0f);
    if (MODE) {
        out[(size_t)n*HH + c] = r;
        catb[(size_t)n*768 + c] = __float2bfloat16(r);
    }
    outb[(size_t)n*HH + c] = __float2bfloat16(r);
}

// ---------------- bf16 MFMA GEMM: 512 threads / 8 waves, 64x64 tile, BK=64 ----------------
// OUTM: 0 fp32, 1 bf16, 4 proj+dtab, 5 fused in_proj+QKV (xzb | qkB scaled | vtB transposed)
// ACT: 0 none, 1 relu, 2 softplus
template<int ACT, int OUTM>
__global__ __launch_bounds__(512) void mg_k(const unsigned short* __restrict__ A,
        const unsigned short* __restrict__ Bt, const float* __restrict__ bias,
        void* __restrict__ Cp, int ldc, void* __restrict__ Cp2, void* __restrict__ Cp3,
        const float* __restrict__ resid, int ldr, int M, int K, int N)
{
    __shared__ __align__(16) unsigned short Asm[2][64][40];
    __shared__ __align__(16) unsigned short Bsm[2][64][40];
    int t = threadIdx.x;
    int lane = t & 63, w = t >> 6;
    int wm = w & 3, wn = w >> 2;            // 4 row strips x 2 col strips
    int row0 = blockIdx.x * 64, col0 = blockIdx.y * 64;
    int sr = t >> 3;
    int sk8 = (t & 7) * 8;
    int su = sk8 >> 5, so = sk8 & 31;
    f32x4 acc0 = {}, acc1 = {};
    int fr = lane & 15, fq8 = (lane >> 4) * 8;

    uint4 zz = make_uint4(0u,0u,0u,0u);
    uint4 ra = zz, rb = zz;
    bool bnv = (col0 + sr) < N;
    if (sk8 < K) {
        ra = *(const uint4*)&A[(size_t)(row0+sr)*K + sk8];
        if (bnv) rb = *(const uint4*)&Bt[(size_t)(col0+sr)*K + sk8];
    }

    for (int k0 = 0; k0 < K; k0 += 64) {
        __syncthreads();
        *(uint4*)&Asm[su][sr][so] = ra;
        *(uint4*)&Bsm[su][sr][so] = rb;
        __syncthreads();
        int kn = k0 + 64;
        if (kn < K) {
            ra = rb = zz;
            if (kn + sk8 < K) {
                ra = *(const uint4*)&A[(size_t)(row0+sr)*K + kn + sk8];
                if (bnv) rb = *(const uint4*)&Bt[(size_t)(col0+sr)*K + kn + sk8];
            }
        }
        #pragma unroll
        for (int ks = 0; ks < 2; ks++) {
            bf16x8 a  = *(bf16x8*)&Asm[ks][wm*16 + fr][fq8];
            bf16x8 b0 = *(bf16x8*)&Bsm[ks][wn*32 + fr][fq8];
            bf16x8 b1 = *(bf16x8*)&Bsm[ks][wn*32 + 16 + fr][fq8];
            acc0 = __builtin_amdgcn_mfma_f32_16x16x32_bf16(a, b0, acc0, 0, 0, 0);
            acc1 = __builtin_amdgcn_mfma_f32_16x16x32_bf16(a, b1, acc1, 0, 0, 0);
        }
    }

    int fc = lane & 15, frq = (lane >> 4) * 4;
    if constexpr (OUTM == 4) {
        // proj fp32 [NL][32] + dtab bf16 [NL][32] (cols 16..31 zero)
        #pragma unroll
        for (int nt = 0; nt < 2; nt++) {
            int col = col0 + wn*32 + nt*16 + fc;
            if (col >= 32) continue;
            f32x4& av = nt ? acc1 : acc0;
            #pragma unroll
            for (int i = 0; i < 4; i++) {
                int row = row0 + wm*16 + frq + i;
                float v = av[i];
                ((float*)Cp)[(size_t)row*32 + col] = v;
                ((hbf*)Cp2)[(size_t)row*32 + col] = __float2bfloat16((col < 16) ? v : 0.0f);
            }
        }
    } else if constexpr (OUTM == 5) {
        if (col0 < 1024) {
            // in_proj -> xzb bf16 [NL][1024], no bias
            #pragma unroll
            for (int nt = 0; nt < 2; nt++) {
                int col = col0 + wn*32 + nt*16 + fc;
                f32x4& av = nt ? acc1 : acc0;
                #pragma unroll
                for (int i = 0; i < 4; i++) {
                    int row = row0 + wm*16 + frq + i;
                    ((hbf*)Cp)[(size_t)row*1024 + col] = __float2bfloat16(av[i]);
                }
            }
        } else if (col0 < 1536) {
            // Q/K -> qkB bf16 [NL][512], Q cols scaled 0.125
            #pragma unroll
            for (int nt = 0; nt < 2; nt++) {
                int gcol = col0 + wn*32 + nt*16 + fc;
                int col = gcol - 1024;
                float bvv = bias[col];
                float sc = (col < 256) ? 0.125f : 1.0f;
                f32x4& av = nt ? acc1 : acc0;
                #pragma unroll
                for (int i = 0; i < 4; i++) {
                    int row = row0 + wm*16 + frq + i;
                    ((hbf*)Cp2)[(size_t)row*512 + col] = __float2bfloat16((av[i] + bvv) * sc);
                }
            }
        } else {
            // V -> vtB bf16 transposed [256][NL] via LDS
            __shared__ __align__(16) unsigned short Ts[64][72];
            #pragma unroll
            for (int nt = 0; nt < 2; nt++) {
                int gcol = col0 + wn*32 + nt*16 + fc;
                float bvv = bias[gcol - 1024];
                f32x4& av = nt ? acc1 : acc0;
                #pragma unroll
                for (int i = 0; i < 4; i++)
                    *(hbf*)&Ts[wn*32 + nt*16 + fc][wm*16 + frq + i] = __float2bfloat16(av[i] + bvv);
            }
            __syncthreads();
            int c = t >> 3, rs = (t & 7) * 8;
            *(uint4*)((hbf*)Cp3 + (size_t)(col0 - 1536 + c)*NL + row0 + rs) = *(uint4*)&Ts[c][rs];
        }
    } else {
        #pragma unroll
        for (int nt = 0; nt < 2; nt++) {
            int col = col0 + wn*32 + nt*16 + fc;
            if (col >= N) continue;
            float bvv = bias ? bias[col] : 0.0f;
            f32x4& av = nt ? acc1 : acc0;
            #pragma unroll
            for (int i = 0; i < 4; i++) {
                int row = row0 + wm*16 + frq + i;
                float v = av[i] + bvv;
                if (ACT == 1) v = fmaxf(v, 0.0f);
                if (ACT == 2) v = (v > 20.0f) ? v : log1pf(expf(v));
                if (resid) v += resid[(size_t)row*ldr + col];
                if (OUTM == 0) ((float*)Cp)[(size_t)row*ldc + col] = v;
                else           ((hbf*)Cp)[(size_t)row*ldc + col] = __float2bfloat16(v);
            }
        }
    }
}

// ---------------- mamba: conv + silu ----------------
__global__ void conv_k(const hbf* __restrict__ xzb, const float* __restrict__ cW,
                       const float* __restrict__ cb, float* __restrict__ xc2,
                       hbf* __restrict__ xcb) {
    int i = blockIdx.x*256 + threadIdx.x;
    int l = i >> 9, d = i & 511;
    float acc = cb[d];
    #pragma unroll
    for (int k = 0; k < 4; k++) {
        int ls = l - 3 + k;
        if (ls >= 0) acc += __bfloat162float(xzb[(size_t)ls*1024 + d]) * cW[d*4 + k];
    }
    float r = acc / (1.0f + __expf(-acc));
    xc2[i] = r;
    xcb[i] = __float2bfloat16(r);
}

// ---------------- mamba chunked scan (256 chunks x 16 steps) ----------------
__global__ __launch_bounds__(256) void scan1_k(const float* __restrict__ delta,
                        const float* __restrict__ xc, const float* __restrict__ proj,
                        const float* __restrict__ Alog,
                        float* __restrict__ P, float* __restrict__ Hl)
{
    int c = blockIdx.x >> 1;
    int d = ((blockIdx.x & 1) << 8) + threadIdx.x;
    float Ac[DSc], pr[DSc], h[DSc];
    #pragma unroll
    for (int s2 = 0; s2 < DSc; s2++) { Ac[s2] = -__expf(Alog[d*DSc+s2]); pr[s2]=1.0f; h[s2]=0.0f; }
    int l0 = c * CLc;
    for (int l = l0; l < l0 + CLc; l++) {
        float dl = delta[(size_t)l*DIc + d];
        float dx = dl * xc[(size_t)l*DIc + d];
        const float* pb = proj + l*32 + 16;
        #pragma unroll
        for (int s2 = 0; s2 < DSc; s2++) {
            float a = __expf(dl * Ac[s2]);
            h[s2] = a*h[s2] + dx*pb[s2];
            pr[s2] *= a;
        }
    }
    #pragma unroll
    for (int s2 = 0; s2 < DSc; s2++) {
        P [(size_t)(c*DSc+s2)*DIc + d] = pr[s2];
        Hl[(size_t)(c*DSc+s2)*DIc + d] = h[s2];
    }
}

// log-scan over 256 chunks; one series per block (grid 4096)
__global__ __launch_bounds__(256) void scan2p_k(const float* __restrict__ P,
                        const float* __restrict__ Hl, float* __restrict__ Hst) {
    __shared__ float Psh[256], Hsh[256];
    int t = threadIdx.x, series = blockIdx.x;
    size_t off = (size_t)t*4096 + series;
    float Pc = P[off], Hc = Hl[off];
    Psh[t] = Pc; Hsh[t] = Hc;
    __syncthreads();
    #pragma unroll
    for (int st = 1; st < 256; st <<= 1) {
        float p1 = 1.0f, h1 = 0.0f;
        if (t >= st) { p1 = Psh[t-st]; h1 = Hsh[t-st]; }
        __syncthreads();
        Hc = Pc*h1 + Hc;
        Pc = Pc*p1;
        Psh[t] = Pc; Hsh[t] = Hc;
        __syncthreads();
    }
    Hst[off] = (t == 0) ? 0.0f : Hsh[t-1];
}

__global__ __launch_bounds__(256) void scan3_k(const float* __restrict__ delta,
                        const float* __restrict__ xc, const float* __restrict__ proj,
                        const float* __restrict__ Alog, const float* __restrict__ Hst,
                        const float* __restrict__ Dp, const hbf* __restrict__ xzb,
                        hbf* __restrict__ Y)
{
    int c = blockIdx.x >> 1;
    int d = ((blockIdx.x & 1) << 8) + threadIdx.x;
    float Ac[DSc], h[DSc];
    #pragma unroll
    for (int s2 = 0; s2 < DSc; s2++) {
        Ac[s2] = -__expf(Alog[d*DSc+s2]);
        h[s2]  = Hst[(size_t)(c*DSc+s2)*DIc + d];
    }
    float dpv = Dp[d];
    int l0 = c * CLc;
    for (int l = l0; l < l0 + CLc; l++) {
        float dl = delta[(size_t)l*DIc + d];
        float xv = xc[(size_t)l*DIc + d];
        float dx = dl * xv;
        const float* pb = proj + l*32 + 16;
        float y = 0.0f;
        #pragma unroll
        for (int s2 = 0; s2 < DSc; s2++) {
            float a = __expf(dl * Ac[s2]);
            h[s2] = a*h[s2] + dx*pb[s2];
            y += h[s2] * pb[8+s2];
        }
        float z = __bfloat162float(xzb[(size_t)l*1024 + 512 + d]);
        float sz = z / (1.0f + __expf(-z));
        Y[(size_t)l*DIc + d] = __float2bfloat16((y + dpv*xv) * sz);
    }
}

// ---------------- split-K(8) MFMA flash attention, TQ=128, constant-shift softmax ----------------
// grid (NL/128, 4, 8). 4 waves x 32 Q-rows. Q staged once -> registers; QPs reused as P.
__global__ __launch_bounds__(256) void attn_part_k(const unsigned short* __restrict__ QK,
                       const unsigned short* __restrict__ Vt,
                       OPtrs op, float* __restrict__ lsum)
{
    __shared__ __align__(16) unsigned short QPs[128][72];
    __shared__ __align__(16) unsigned short Ks[64][72];
    __shared__ __align__(16) unsigned short Vs[64][72];
    int t = threadIdx.x, lane = t & 63, w = t >> 6;
    int h = blockIdx.y, q0 = blockIdx.x * 128, skc = blockIdx.z;
    int fm = lane & 15, fq = lane >> 4;

    // stage Q tile (128 x 64) and hoist fragments
    {
        int qr = t >> 1, qc = (t & 1) * 32;
        const unsigned short* src = &QK[(size_t)(q0+qr)*512 + h*64 + qc];
        *(uint4*)&QPs[qr][qc]      = *(const uint4*)&src[0];
        *(uint4*)&QPs[qr][qc + 8]  = *(const uint4*)&src[8];
        *(uint4*)&QPs[qr][qc + 16] = *(const uint4*)&src[16];
        *(uint4*)&QPs[qr][qc + 24] = *(const uint4*)&src[24];
    }
    __syncthreads();
    bf16x8 qa[2][2];
    #pragma unroll
    for (int rf = 0; rf < 2; rf++)
        #pragma unroll
        for (int ks = 0; ks < 2; ks++)
            qa[rf][ks] = *(bf16x8*)&QPs[w*32 + rf*16 + fm][ks*32 + fq*8];

    bf16x8 ones;
    #pragma unroll
    for (int j = 0; j < 8; j++) ones[j] = (short)0x3F80;

    f32x4 o[2][4] = {};
    f32x4 ol[2] = {};
    int sr = t >> 2, sk = (t & 3) * 16;
    const unsigned short* Kb = QK + 256;
    int kt = skc * 512;
    uint4 ka  = *(const uint4*)&Kb[(size_t)(kt+sr)*512 + h*64 + sk];
    uint4 kb2 = *(const uint4*)&Kb[(size_t)(kt+sr)*512 + h*64 + sk + 8];
    uint4 va  = *(const uint4*)&Vt[(size_t)(h*64+sr)*NL + kt + sk];
    uint4 vb2 = *(const uint4*)&Vt[(size_t)(h*64+sr)*NL + kt + sk + 8];

    for (int it = 0; it < 8; it++) {
        __syncthreads();
        *(uint4*)&Ks[sr][sk] = ka;  *(uint4*)&Ks[sr][sk+8] = kb2;
        *(uint4*)&Vs[sr][sk] = va;  *(uint4*)&Vs[sr][sk+8] = vb2;
        __syncthreads();
        if (it < 7) {
            int kn = kt + 64;
            ka  = *(const uint4*)&Kb[(size_t)(kn+sr)*512 + h*64 + sk];
            kb2 = *(const uint4*)&Kb[(size_t)(kn+sr)*512 + h*64 + sk + 8];
            va  = *(const uint4*)&Vt[(size_t)(h*64+sr)*NL + kn + sk];
            vb2 = *(const uint4*)&Vt[(size_t)(h*64+sr)*NL + kn + sk + 8];
        }
        // S = Q x K^T for both row frags (K frags read once per ks/nt)
        f32x4 s[2][4] = {};
        #pragma unroll
        for (int ks = 0; ks < 2; ks++) {
            #pragma unroll
            for (int nt = 0; nt < 4; nt++) {
                bf16x8 kb = *(bf16x8*)&Ks[nt*16 + fm][ks*32 + fq*8];
                s[0][nt] = __builtin_amdgcn_mfma_f32_16x16x32_bf16(qa[0][ks], kb, s[0][nt], 0, 0, 0);
                s[1][nt] = __builtin_amdgcn_mfma_f32_16x16x32_bf16(qa[1][ks], kb, s[1][nt], 0, 0, 0);
            }
        }
        // p = exp(s - 4) -> P (own rows only)
        #pragma unroll
        for (int rf = 0; rf < 2; rf++)
            #pragma unroll
            for (int nt = 0; nt < 4; nt++)
                #pragma unroll
                for (int i = 0; i < 4; i++) {
                    float p = __expf(s[rf][nt][i] - 4.0f);
                    *(hbf*)&QPs[w*32 + rf*16 + fq*4 + i][nt*16 + fm] = __float2bfloat16(p);
                }
        // O += P x V ; l += P x ones
        #pragma unroll
        for (int ks = 0; ks < 2; ks++) {
            bf16x8 pa0 = *(bf16x8*)&QPs[w*32 + fm][ks*32 + fq*8];
            bf16x8 pa1 = *(bf16x8*)&QPs[w*32 + 16 + fm][ks*32 + fq*8];
            #pragma unroll
            for (int nt = 0; nt < 4; nt++) {
                bf16x8 vb = *(bf16x8*)&Vs[nt*16 + fm][ks*32 + fq*8];
                o[0][nt] = __builtin_amdgcn_mfma_f32_16x16x32_bf16(pa0, vb, o[0][nt], 0, 0, 0);
                o[1][nt] = __builtin_amdgcn_mfma_f32_16x16x32_bf16(pa1, vb, o[1][nt], 0, 0, 0);
            }
            ol[0] = __builtin_amdgcn_mfma_f32_16x16x32_bf16(pa0, ones, ol[0], 0, 0, 0);
            ol[1] = __builtin_amdgcn_mfma_f32_16x16x32_bf16(pa1, ones, ol[1], 0, 0, 0);
        }
        kt += 64;
    }
    hbf* Op = op.p[skc];
    #pragma unroll
    for (int rf = 0; rf < 2; rf++)
        #pragma unroll
        for (int i = 0; i < 4; i++) {
            int row = w*32 + rf*16 + fq*4 + i;
            #pragma unroll
            for (int nt = 0; nt < 4; nt++)
                Op[(size_t)(q0 + row)*HH + h*64 + nt*16 + fm] = __float2bfloat16(o[rf][nt][i]);
        }
    if (fm == 0) {
        #pragma unroll
        for (int rf = 0; rf < 2; rf++)
            #pragma unroll
            for (int i = 0; i < 4; i++)
                lsum[(size_t)(skc*4 + h)*NL + q0 + w*32 + rf*16 + fq*4 + i] = ol[rf][i];
    }
}

// exact merge: O = sum_c Oc / sum_c lc
__global__ __launch_bounds__(256) void amerge_k(OPtrs op, const float* __restrict__ lsum,
                                                hbf* __restrict__ aob) {
    int row = blockIdx.x, t = threadIdx.x, h = t >> 6;
    float L = 0.0f, s = 0.0f;
    #pragma unroll
    for (int c = 0; c < 8; c++) {
        L += lsum[(size_t)(c*4 + h)*NL + row];
        s += __bfloat162float(op.p[c][(size_t)row*HH + t]);
    }
    aob[(size_t)row*HH + t] = __float2bfloat16(s / L);
}

// ---------------- layernorm + pooling into 128 partial pools ----------------
__global__ __launch_bounds__(256) void ln_k(const float* __restrict__ X,
                    const float* __restrict__ g, const float* __restrict__ b,
                    float* __restrict__ part) {
    __shared__ float red[4];
    int r = blockIdx.x, t = threadIdx.x;
    float v = X[(size_t)r*HH + t];
    float s = v;
    #pragma unroll
    for (int o = 32; o > 0; o >>= 1) s += __shfl_down(s, o);
    if ((t & 63) == 0) red[t >> 6] = s;
    __syncthreads();
    float mean = (red[0]+red[1]+red[2]+red[3]) * (1.0f/256.0f);
    float dfv = v - mean;
    float s2 = dfv*dfv;
    #pragma unroll
    for (int o = 32; o > 0; o >>= 1) s2 += __shfl_down(s2, o);
    __syncthreads();
    if ((t & 63) == 0) red[t >> 6] = s2;
    __syncthreads();
    float var = (red[0]+red[1]+red[2]+red[3]) * (1.0f/256.0f);
    float y = dfv * rsqrtf(var + 1e-5f) * g[t] + b[t];
    atomicAdd(&part[(size_t)(r & 127)*2048 + (r >> 9)*HH + t], y * (1.0f/512.0f));
}

__global__ void reduce_k(const float* __restrict__ part, float* __restrict__ pooled) {
    int i = blockIdx.x*256 + threadIdx.x;   // 0..2047
    float s = 0.0f;
    #pragma unroll 8
    for (int p = 0; p < 128; p++) s += part[(size_t)p*2048 + i];
    pooled[i] = s;
}

// ---------------- heads: wave per output ----------------
__global__ __launch_bounds__(256) void heads_k(const float* __restrict__ pooled,
        const float* cw, const float* cbh, const float* hw, const float* hb,
        const float* tw, const float* tb, const float* p1w, const float* p1b,
        const float* p2w, const float* p2b, const float* dw, const float* db,
        const float* sw, const float* sb, float* __restrict__ out)
{
    int idx = blockIdx.x*4 + (threadIdx.x >> 6);
    int lane = threadIdx.x & 63;
    if (idx >= NOUT) return;
    int b = idx / 1552, j = idx - b*1552;
    const float* w; const float* bi; int col, nc;
    if (j < 1)         { w = cw;  bi = cbh; col = j;        nc = 1;   }
    else if (j < 5)    { w = hw;  bi = hb;  col = j - 1;    nc = 4;   }
    else if (j < 8)    { w = tw;  bi = tb;  col = j - 5;    nc = 3;   }
    else if (j < 520)  { w = p1w; bi = p1b; col = j - 8;    nc = 512; }
    else if (j < 1032) { w = p2w; bi = p2b; col = j - 520;  nc = 512; }
    else if (j < 1544) { w = dw;  bi = db;  col = j - 1032; nc = 512; }
    else               { w = sw;  bi = sb;  col = j - 1544; nc = 8;   }
    const float* pl = pooled + b*HH;
    float s = 0.0f;
    #pragma unroll
    for (int k = lane; k < 256; k += 64) s = fmaf(pl[k], w[(size_t)k*nc + col], s);
    #pragma unroll
    for (int o = 32; o > 0; o >>= 1) s += __shfl_down(s, o);
    if (lane == 0) out[idx] = s + bi[col];
}

// ---------------- launcher ----------------
extern "C" void kernel_launch(void* const* d_in, const int* in_sizes, int n_in,
                              void* d_out, int out_size, void* d_ws, size_t ws_size,
                              hipStream_t stream)
{
    (void)in_sizes; (void)n_in; (void)out_size; (void)ws_size;
    const float* x      = (const float*)d_in[0];
    const int*   ei     = (const int*)  d_in[1];
    const float* W_init = (const float*)d_in[2];
    const float* b_init = (const float*)d_in[3];
    const float* g1W = (const float*)d_in[4];
    const float* g1b = (const float*)d_in[5];
    const float* g2W = (const float*)d_in[6];
    const float* g2b = (const float*)d_in[7];
    const float* inW = (const float*)d_in[8];
    const float* cW  = (const float*)d_in[9];
    const float* cb  = (const float*)d_in[10];
    const float* xpW = (const float*)d_in[11];
    const float* dtW = (const float*)d_in[12];
    const float* dtb = (const float*)d_in[13];
    const float* Alog= (const float*)d_in[14];
    const float* Dp  = (const float*)d_in[15];
    const float* outW= (const float*)d_in[16];
    const float* Wq  = (const float*)d_in[17];
    const float* bq  = (const float*)d_in[18];
    const float* Wk  = (const float*)d_in[19];
    const float* bk  = (const float*)d_in[20];
    const float* Wv  = (const float*)d_in[21];
    const float* bv  = (const float*)d_in[22];
    const float* Wo  = (const float*)d_in[23];
    const float* bo  = (const float*)d_in[24];
    const float* fusW= (const float*)d_in[25];
    const float* fusb= (const float*)d_in[26];
    const float* lng = (const float*)d_in[27];
    const float* lnb = (const float*)d_in[28];
    const float* cwp = (const float*)d_in[29];
    const float* cbp = (const float*)d_in[30];
    const float* hwp = (const float*)d_in[31];
    const float* hbp = (const float*)d_in[32];
    const float* twp = (const float*)d_in[33];
    const float* tbp = (const float*)d_in[34];
    const float* p1w = (const float*)d_in[35];
    const float* p1b = (const float*)d_in[36];
    const float* p2w = (const float*)d_in[37];
    const float* p2b = (const float*)d_in[38];
    const float* dwp = (const float*)d_in[39];
    const float* dbp = (const float*)d_in[40];
    const float* swp = (const float*)d_in[41];
    const float* sbp = (const float*)d_in[42];

    float* fw = (float*)d_ws;
    int* iw = (int*)(fw + O_INT);
    int* indeg = iw;
    int* row_start = iw + 4096;
    int* cursor = iw + 8193;
    int* csr = iw + 12289;
    float* dinv = fw + O_DINV;

    hbf* wt   = (hbf*)(fw + O_WT);
    hbf* xb   = (hbf*)(fw + O_XB);
    hbf* h0b  = (hbf*)(fw + O_H0B);
    hbf* h2b  = (hbf*)(fw + O_H2B);
    hbf* xcb  = (hbf*)(fw + O_XCB);
    hbf* dtab = (hbf*)(fw + O_DTAB);
    hbf* xzb  = (hbf*)(fw + O_XZB);
    hbf* yb   = (hbf*)(fw + O_Y);
    hbf* aob  = (hbf*)(fw + O_Y);
    hbf* catb = (hbf*)(fw + O_CATB);
    hbf* qkB  = (hbf*)(fw + O_QKB);
    hbf* vtB  = (hbf*)(fw + O_VTB);
    float* fused = fw + O_XC;
    float* b768 = fw + O_B768;
    float* part = fw + O_PART;

    float* scanP  = fw + O_MBUF;
    float* scanHl = fw + O_QK;
    float* scanHst= fw + O_HST;
    float* lsum   = fw + O_HST;          // Hst dead after scan3

    OPtrs op;
    op.p[0] = (hbf*)(fw + O_MBUF);
    op.p[1] = (hbf*)(fw + O_MBUF + 524288);
    op.p[2] = (hbf*)(fw + O_DELTA);
    op.p[3] = (hbf*)(fw + O_DELTA + 524288);
    op.p[4] = (hbf*)(fw + O_DELTA + 1048576);
    op.p[5] = (hbf*)(fw + O_DELTA + 1572864);
    op.p[6] = (hbf*)(fw + O_XZB);
    op.p[7] = (hbf*)(fw + O_XZB + 524288);

    hbf* WtInit  = wt + 0;
    hbf* WtG1    = wt + 8192;
    hbf* WtG2    = wt + 73728;
    hbf* WtXp    = wt + 139264;
    hbf* WtDt    = wt + 155648;
    hbf* WtOut   = wt + 172032;
    hbf* WtInQKV = wt + 303104;          // in|q|k|v contiguous (N=1792, K=256)
    hbf* WtO     = wt + 761856;
    hbf* WtFus   = wt + 827392;

    WSrc wsrc;
    wsrc.p[0]=W_init; wsrc.p[1]=g1W; wsrc.p[2]=g2W; wsrc.p[3]=xpW; wsrc.p[4]=dtW;
    wsrc.p[5]=outW; wsrc.p[6]=inW; wsrc.p[7]=Wq; wsrc.p[8]=Wk; wsrc.p[9]=Wv;
    wsrc.p[10]=Wo; wsrc.p[11]=fusW;
    prep_k<<<(PR_I+255)/256,256,0,stream>>>(wsrc, wt, x, xb, bq, bk, bv, b768,
                                            part, indeg);

    // graph prep
    count_k<<<256,256,0,stream>>>(ei, indeg);
    prefix_k<<<1,1024,0,stream>>>(indeg, row_start, cursor, dinv);
    scatter_k<<<256,256,0,stream>>>(ei, cursor, csr);

    // h0 = relu(x @ W_init + b_init) -> bf16
    mg_k<1,1><<<dim3(64,4),512,0,stream>>>((const unsigned short*)xb, (const unsigned short*)WtInit,
        b_init, h0b, 256, nullptr, nullptr, nullptr, 0, NL, 32, 256);
    // gcn1
    mg_k<0,0><<<dim3(64,4),512,0,stream>>>((const unsigned short*)h0b, (const unsigned short*)WtG1,
        nullptr, fw+O_MBUF, 256, nullptr, nullptr, nullptr, 0, NL, 256, 256);
    gather_k<0><<<4096,256,0,stream>>>(fw+O_MBUF, csr, row_start, dinv, g1b, nullptr, h0b, nullptr);
    // gcn2 (fp32 h2 + bf16 h2b + catb cols 0..255)
    mg_k<0,0><<<dim3(64,4),512,0,stream>>>((const unsigned short*)h0b, (const unsigned short*)WtG2,
        nullptr, fw+O_MBUF, 256, nullptr, nullptr, nullptr, 0, NL, 256, 256);
    gather_k<1><<<4096,256,0,stream>>>(fw+O_MBUF, csr, row_start, dinv, g2b, fw+O_H2, h2b, catb);

    // fused in_proj + QKV (N=1792): xzb | qkB (Q scaled) | vtB (transposed)
    mg_k<0,5><<<dim3(64,28),512,0,stream>>>((const unsigned short*)h2b, (const unsigned short*)WtInQKV,
        b768, xzb, 1024, qkB, vtB, nullptr, 0, NL, 256, 1792);

    // mamba
    conv_k<<<8192,256,0,stream>>>(xzb, cW, cb, fw+O_XC, xcb);
    mg_k<0,4><<<dim3(64,1),512,0,stream>>>((const unsigned short*)xcb, (const unsigned short*)WtXp,
        nullptr, fw+O_PROJ, 32, dtab, nullptr, nullptr, 0, NL, 512, 32);
    mg_k<2,0><<<dim3(64,8),512,0,stream>>>((const unsigned short*)dtab, (const unsigned short*)WtDt,
        dtb, fw+O_DELTA, 512, nullptr, nullptr, nullptr, 0, NL, 32, 512);
    scan1_k<<<512,256,0,stream>>>(fw+O_DELTA, fw+O_XC, fw+O_PROJ, Alog, scanP, scanHl);
    scan2p_k<<<4096,256,0,stream>>>(scanP, scanHl, scanHst);
    scan3_k<<<512,256,0,stream>>>(fw+O_DELTA, fw+O_XC, fw+O_PROJ, Alog, scanHst, Dp, xzb, yb);
    mg_k<0,1><<<dim3(64,4),512,0,stream>>>((const unsigned short*)yb, (const unsigned short*)WtOut,
        nullptr, catb + 256, 768, nullptr, nullptr, nullptr, 0, NL, 512, 256);

    // attention (after scan3: op buffers alias delta/xzb/mbuf, lsum aliases Hst)
    attn_part_k<<<dim3(32,4,8),256,0,stream>>>((const unsigned short*)qkB,
        (const unsigned short*)vtB, op, lsum);
    amerge_k<<<4096,256,0,stream>>>(op, lsum, aob);
    mg_k<0,1><<<dim3(64,4),512,0,stream>>>((const unsigned short*)aob, (const unsigned short*)WtO,
        bo, catb + 512, 768, nullptr, nullptr, nullptr, 0, NL, 256, 256);

    // fuse + residual + LN(+partial pool) + reduce + heads
    mg_k<1,0><<<dim3(64,4),512,0,stream>>>((const unsigned short*)catb, (const unsigned short*)WtFus,
        fusb, fused, 256, nullptr, nullptr, fw+O_H2, 256, NL, 768, 256);
    ln_k<<<4096,256,0,stream>>>(fused, lng, lnb, part);
    reduce_k<<<8,256,0,stream>>>(part, fw+O_POOL);
    heads_k<<<(NOUT+3)/4,256,0,stream>>>(fw+O_POOL, cwp,cbp,hwp,hbp,twp,tbp,p1w,p1b,p2w,p2b,
                                         dwp,dbp,swp,sbp, (float*)d_out);
}

// Round 14
// 352.554 us; speedup vs baseline: 6.0200x; 1.0611x over previous
//
#include <hip/hip_runtime.h>
#include <hip/hip_bf16.h>
#include <math.h>

typedef __hip_bfloat16 hbf;
typedef short bf16x8 __attribute__((ext_vector_type(8)));
typedef float f32x4 __attribute__((ext_vector_type(4)));

// ---------------- problem constants ----------------
constexpr int NL  = 4096;
constexpr int HH  = 256;
constexpr int NE  = 8192;
constexpr int DIc = 512;
constexpr int DSc = 8;
constexpr int CLc = 16;    // scan chunk length (256 chunks)
constexpr int NOUT = 12416;

// ---------------- workspace layout (float offsets) ----------------
constexpr size_t O_MBUF  = 0;         // 1048576  gcn msgs; scan P; attn op0/op1(bf16)
constexpr size_t O_QK    = 1048576;   // 1048576  scan Hl (temp)
constexpr size_t O_H2    = 2097152;   // 1048576  h2 fp32 (live to fus resid)
constexpr size_t O_CATB  = 3145728;   // 1572864  catb bf16 [NL][768]
constexpr size_t O_XZB   = 4718592;   // 2097152  xzb bf16 [NL][1024]; op6/op7(bf16) after scan3
constexpr size_t O_XC    = 6815744;   // 2097152  fused fp32 (epilogue region)
constexpr size_t O_DELTA = 8912896;   // 2097152  delta; op2..op5(bf16) after scan3
constexpr size_t O_PROJ  = 11010048;  // 131072   proj fp32
constexpr size_t O_HST   = 11141120;  // 1048576  Hst; lsum after scan3
constexpr size_t O_Y     = 12189696;  // 1048576  yb bf16; aob bf16
constexpr size_t O_POOL  = 13238272;  // 2048
constexpr size_t O_DINV  = 13240320;  // 4096
constexpr size_t O_B768  = 13244416;  // 768
constexpr size_t O_INT   = 13245184;  // 81928 ints
constexpr size_t O_WT    = 13327112;  // 512000
constexpr size_t O_XB    = 13839112;  // 65536
constexpr size_t O_H0B   = 13904648;  // 524288
constexpr size_t O_H2B   = 14428936;  // 524288
constexpr size_t O_XCB   = 14953224;  // 1048576
constexpr size_t O_DTAB  = 16001800;  // 65536
constexpr size_t O_QKB   = 16067584;  // 1048576  qkB bf16 [NL][512]
constexpr size_t O_VTB   = 17116160;  // 524288   vtB bf16 [256][NL]
constexpr size_t O_PART  = 17640448;  // 262144   ln partial pools [128][2048]
constexpr size_t O_HWT   = 17902592;  // 397312   transposed head weights [1552][256]
// total 18299904 floats = 73.2 MB (ws = 256 MB)

// ---------------- weight transpose-cast table (in|q|k|v contiguous) ----------------
constexpr int NW = 12;
__device__ __constant__ int wc_cum[NW+1] = {
    0, 8192, 73728, 139264, 155648, 172032, 303104, 565248,
    630784, 696320, 761856, 827392, 1024000 };
__device__ __constant__ int wc_K [NW] = {32,256,256,512,16,512,256,256,256,256,256,768};
__device__ __constant__ int wc_N [NW] = {256,256,256,32,512,256,1024,256,256,256,256,256};
__device__ __constant__ int wc_Kp[NW] = {32,256,256,512,32,512,256,256,256,256,256,768};
struct WSrc { const float* p[NW]; };
struct HSrc { const float* p[7]; };
struct OPtrs { hbf* p[8]; };

__device__ __constant__ int hw_b[8]  = {0,1,5,8,520,1032,1544,1552};
__device__ __constant__ int hw_nc[7] = {1,4,3,512,512,512,8};

// prep: weight transpose-cast + x cast + b768 + part zero + indeg zero + head-w transpose
constexpr int PR_W = 1024000;
constexpr int PR_X = PR_W + 131072;     // 1155072
constexpr int PR_B = PR_X + 768;        // 1155840
constexpr int PR_P = PR_B + 262144;     // 1417984
constexpr int PR_I = PR_P + 4096;       // 1422080
constexpr int PR_H = PR_I + 397312;     // 1819392
__global__ __launch_bounds__(256) void prep_k(WSrc ws, hbf* __restrict__ wt,
        const float* __restrict__ x, hbf* __restrict__ xb,
        const float* __restrict__ bq, const float* __restrict__ bk,
        const float* __restrict__ bv,
        float* __restrict__ b768, float* __restrict__ part, int* __restrict__ indeg,
        HSrc hs, float* __restrict__ hwt) {
    int idx = blockIdx.x*256 + threadIdx.x;
    if (idx < PR_W) {
        int lo = 0, hi = NW-1;
        while (lo < hi) { int mid = (lo+hi+1)>>1; if (idx >= wc_cum[mid]) lo = mid; else hi = mid-1; }
        int local = idx - wc_cum[lo];
        int Kp = wc_Kp[lo], K = wc_K[lo], N = wc_N[lo];
        int n = local / Kp, k = local - n*Kp;
        float v = (k < K) ? ws.p[lo][(size_t)k*N + n] : 0.0f;
        wt[idx] = __float2bfloat16(v);
    } else if (idx < PR_X) {
        int i = idx - PR_W;
        xb[i] = __float2bfloat16(x[i]);
    } else if (idx < PR_B) {
        int i = idx - PR_X;
        b768[i] = (i < 256) ? bq[i] : (i < 512 ? bk[i-256] : bv[i-512]);
    } else if (idx < PR_P) {
        part[idx - PR_B] = 0.0f;
    } else if (idx < PR_I) {
        indeg[idx - PR_P] = 0;
    } else if (idx < PR_H) {
        int i = idx - PR_I;
        int j = i >> 8, k = i & 255;
        int seg = 0;
        while (j >= hw_b[seg+1]) seg++;
        int col = j - hw_b[seg], nc = hw_nc[seg];
        hwt[(size_t)j*256 + k] = hs.p[seg][(size_t)k*nc + col];
    }
}

// ---------------- graph prep ----------------
__global__ void count_k(const int* __restrict__ ei, int* __restrict__ indeg) {
    int i = blockIdx.x*256 + threadIdx.x;
    int b = i >> 13, e = i & 8191;
    int dst = ei[b*2*NE + NE + e] + (b << 9);
    atomicAdd(&indeg[dst], 1);
}

__global__ __launch_bounds__(1024) void prefix_k(const int* __restrict__ indeg,
                                                 int* __restrict__ row_start,
                                                 int* __restrict__ cursor,
                                                 float* __restrict__ dinv) {
    __shared__ int part[1024];
    int t = threadIdx.x;
    int v0[4]; int s = 0;
    #pragma unroll
    for (int i = 0; i < 4; i++) {
        int cnt = indeg[t*4 + i];
        v0[i] = s; s += cnt;
        dinv[t*4 + i] = rsqrtf(1.0f + (float)cnt);
    }
    part[t] = s;
    __syncthreads();
    for (int o = 1; o < 1024; o <<= 1) {
        int x = (t >= o) ? part[t-o] : 0;
        __syncthreads();
        part[t] += x;
        __syncthreads();
    }
    int base = (t > 0) ? part[t-1] : 0;
    #pragma unroll
    for (int i = 0; i < 4; i++) {
        int rs = base + v0[i];
        row_start[t*4+i] = rs; cursor[t*4+i] = rs;
    }
    if (t == 1023) row_start[4096] = part[1023];
}

__global__ void scatter_k(const int* __restrict__ ei, int* __restrict__ cursor,
                          int* __restrict__ csr) {
    int i = blockIdx.x*256 + threadIdx.x;
    int b = i >> 13, e = i & 8191;
    int src = ei[b*2*NE + e]       + (b << 9);
    int dst = ei[b*2*NE + NE + e]  + (b << 9);
    int pos = atomicAdd(&cursor[dst], 1);
    csr[pos] = src;
}

// gather; MODE 1 adds fp32 out + catb(cols 0..255) write
template<int MODE>
__global__ __launch_bounds__(256) void gather_k(const float* __restrict__ m,
                        const int* __restrict__ csr, const int* __restrict__ row_start,
                        const float* __restrict__ dinv, const float* __restrict__ bias,
                        float* __restrict__ out, hbf* __restrict__ outb,
                        hbf* __restrict__ catb) {
    int n = blockIdx.x, c = threadIdx.x;
    float dn = dinv[n];
    float acc = m[(size_t)n*HH + c] * dn * dn;
    int e0 = row_start[n], e1 = row_start[n+1];
    for (int e = e0; e < e1; e++) {
        int s = csr[e];
        acc += m[(size_t)s*HH + c] * (dinv[s] * dn);
    }
    float r = fmaxf(acc + bias[c], 0.0f);
    if (MODE) {
        out[(size_t)n*HH + c] = r;
        catb[(size_t)n*768 + c] = __float2bfloat16(r);
    }
    outb[(size_t)n*HH + c] = __float2bfloat16(r);
}

// ---------------- bf16 MFMA GEMM: 512 threads / 8 waves, 64x64 tile, BK=64 ----------------
// OUTM: 0 fp32, 1 bf16, 4 proj+dtab, 5 fused in_proj+QKV (xzb | qkB scaled | vtB transposed)
// ACT: 0 none, 1 relu, 2 softplus
template<int ACT, int OUTM>
__global__ __launch_bounds__(512) void mg_k(const unsigned short* __restrict__ A,
        const unsigned short* __restrict__ Bt, const float* __restrict__ bias,
        void* __restrict__ Cp, int ldc, void* __restrict__ Cp2, void* __restrict__ Cp3,
        const float* __restrict__ resid, int ldr, int M, int K, int N)
{
    __shared__ __align__(16) unsigned short Asm[2][64][40];
    __shared__ __align__(16) unsigned short Bsm[2][64][40];
    int t = threadIdx.x;
    int lane = t & 63, w = t >> 6;
    int wm = w & 3, wn = w >> 2;
    int row0 = blockIdx.x * 64, col0 = blockIdx.y * 64;
    int sr = t >> 3;
    int sk8 = (t & 7) * 8;
    int su = sk8 >> 5, so = sk8 & 31;
    f32x4 acc0 = {}, acc1 = {};
    int fr = lane & 15, fq8 = (lane >> 4) * 8;

    uint4 zz = make_uint4(0u,0u,0u,0u);
    uint4 ra = zz, rb = zz;
    bool bnv = (col0 + sr) < N;
    if (sk8 < K) {
        ra = *(const uint4*)&A[(size_t)(row0+sr)*K + sk8];
        if (bnv) rb = *(const uint4*)&Bt[(size_t)(col0+sr)*K + sk8];
    }

    for (int k0 = 0; k0 < K; k0 += 64) {
        __syncthreads();
        *(uint4*)&Asm[su][sr][so] = ra;
        *(uint4*)&Bsm[su][sr][so] = rb;
        __syncthreads();
        int kn = k0 + 64;
        if (kn < K) {
            ra = rb = zz;
            if (kn + sk8 < K) {
                ra = *(const uint4*)&A[(size_t)(row0+sr)*K + kn + sk8];
                if (bnv) rb = *(const uint4*)&Bt[(size_t)(col0+sr)*K + kn + sk8];
            }
        }
        #pragma unroll
        for (int ks = 0; ks < 2; ks++) {
            bf16x8 a  = *(bf16x8*)&Asm[ks][wm*16 + fr][fq8];
            bf16x8 b0 = *(bf16x8*)&Bsm[ks][wn*32 + fr][fq8];
            bf16x8 b1 = *(bf16x8*)&Bsm[ks][wn*32 + 16 + fr][fq8];
            acc0 = __builtin_amdgcn_mfma_f32_16x16x32_bf16(a, b0, acc0, 0, 0, 0);
            acc1 = __builtin_amdgcn_mfma_f32_16x16x32_bf16(a, b1, acc1, 0, 0, 0);
        }
    }

    int fc = lane & 15, frq = (lane >> 4) * 4;
    if constexpr (OUTM == 4) {
        #pragma unroll
        for (int nt = 0; nt < 2; nt++) {
            int col = col0 + wn*32 + nt*16 + fc;
            if (col >= 32) continue;
            f32x4& av = nt ? acc1 : acc0;
            #pragma unroll
            for (int i = 0; i < 4; i++) {
                int row = row0 + wm*16 + frq + i;
                float v = av[i];
                ((float*)Cp)[(size_t)row*32 + col] = v;
                ((hbf*)Cp2)[(size_t)row*32 + col] = __float2bfloat16((col < 16) ? v : 0.0f);
            }
        }
    } else if constexpr (OUTM == 5) {
        if (col0 < 1024) {
            #pragma unroll
            for (int nt = 0; nt < 2; nt++) {
                int col = col0 + wn*32 + nt*16 + fc;
                f32x4& av = nt ? acc1 : acc0;
                #pragma unroll
                for (int i = 0; i < 4; i++) {
                    int row = row0 + wm*16 + frq + i;
                    ((hbf*)Cp)[(size_t)row*1024 + col] = __float2bfloat16(av[i]);
                }
            }
        } else if (col0 < 1536) {
            #pragma unroll
            for (int nt = 0; nt < 2; nt++) {
                int gcol = col0 + wn*32 + nt*16 + fc;
                int col = gcol - 1024;
                float bvv = bias[col];
                float sc = (col < 256) ? 0.125f : 1.0f;
                f32x4& av = nt ? acc1 : acc0;
                #pragma unroll
                for (int i = 0; i < 4; i++) {
                    int row = row0 + wm*16 + frq + i;
                    ((hbf*)Cp2)[(size_t)row*512 + col] = __float2bfloat16((av[i] + bvv) * sc);
                }
            }
        } else {
            __shared__ __align__(16) unsigned short Ts[64][72];
            #pragma unroll
            for (int nt = 0; nt < 2; nt++) {
                int gcol = col0 + wn*32 + nt*16 + fc;
                float bvv = bias[gcol - 1024];
                f32x4& av = nt ? acc1 : acc0;
                #pragma unroll
                for (int i = 0; i < 4; i++)
                    *(hbf*)&Ts[wn*32 + nt*16 + fc][wm*16 + frq + i] = __float2bfloat16(av[i] + bvv);
            }
            __syncthreads();
            int c = t >> 3, rs = (t & 7) * 8;
            *(uint4*)((hbf*)Cp3 + (size_t)(col0 - 1536 + c)*NL + row0 + rs) = *(uint4*)&Ts[c][rs];
        }
    } else {
        #pragma unroll
        for (int nt = 0; nt < 2; nt++) {
            int col = col0 + wn*32 + nt*16 + fc;
            if (col >= N) continue;
            float bvv = bias ? bias[col] : 0.0f;
            f32x4& av = nt ? acc1 : acc0;
            #pragma unroll
            for (int i = 0; i < 4; i++) {
                int row = row0 + wm*16 + frq + i;
                float v = av[i] + bvv;
                if (ACT == 1) v = fmaxf(v, 0.0f);
                if (ACT == 2) v = (v > 20.0f) ? v : log1pf(expf(v));
                if (resid) v += resid[(size_t)row*ldr + col];
                if (OUTM == 0) ((float*)Cp)[(size_t)row*ldc + col] = v;
                else           ((hbf*)Cp)[(size_t)row*ldc + col] = __float2bfloat16(v);
            }
        }
    }
}

// ---------------- mamba: conv + silu (bf16 in/out) ----------------
__global__ void conv_k(const hbf* __restrict__ xzb, const float* __restrict__ cW,
                       const float* __restrict__ cb, hbf* __restrict__ xcb) {
    int i = blockIdx.x*256 + threadIdx.x;
    int l = i >> 9, d = i & 511;
    float acc = cb[d];
    #pragma unroll
    for (int k = 0; k < 4; k++) {
        int ls = l - 3 + k;
        if (ls >= 0) acc += __bfloat162float(xzb[(size_t)ls*1024 + d]) * cW[d*4 + k];
    }
    float r = acc / (1.0f + __expf(-acc));
    xcb[i] = __float2bfloat16(r);
}

// ---------------- mamba chunked scan (256 chunks x 16 steps) ----------------
__global__ __launch_bounds__(256) void scan1_k(const float* __restrict__ delta,
                        const hbf* __restrict__ xc, const float* __restrict__ proj,
                        const float* __restrict__ Alog,
                        float* __restrict__ P, float* __restrict__ Hl)
{
    int c = blockIdx.x >> 1;
    int d = ((blockIdx.x & 1) << 8) + threadIdx.x;
    float Ac[DSc], pr[DSc], h[DSc];
    #pragma unroll
    for (int s2 = 0; s2 < DSc; s2++) { Ac[s2] = -__expf(Alog[d*DSc+s2]); pr[s2]=1.0f; h[s2]=0.0f; }
    int l0 = c * CLc;
    for (int l = l0; l < l0 + CLc; l++) {
        float dl = delta[(size_t)l*DIc + d];
        float dx = dl * __bfloat162float(xc[(size_t)l*DIc + d]);
        const float* pb = proj + l*32 + 16;
        #pragma unroll
        for (int s2 = 0; s2 < DSc; s2++) {
            float a = __expf(dl * Ac[s2]);
            h[s2] = a*h[s2] + dx*pb[s2];
            pr[s2] *= a;
        }
    }
    #pragma unroll
    for (int s2 = 0; s2 < DSc; s2++) {
        P [(size_t)(c*DSc+s2)*DIc + d] = pr[s2];
        Hl[(size_t)(c*DSc+s2)*DIc + d] = h[s2];
    }
}

// coalesced middle scan: block = 16 consecutive series, LDS tile [256 chunks][16 series]
__global__ __launch_bounds__(256) void scan2t_k(const float* __restrict__ P,
                        const float* __restrict__ Hl, float* __restrict__ Hst) {
    __shared__ float Ps[256][17], Hs[256][17];
    int t = threadIdx.x, sg = blockIdx.x;
    int si = t & 15, cb = t >> 4;
    #pragma unroll
    for (int it = 0; it < 16; it++) {
        int c = it*16 + cb;
        size_t off = (size_t)c*4096 + sg*16 + si;
        Ps[c][si] = P[off];
        Hs[c][si] = Hl[off];
    }
    __syncthreads();
    int si2 = t >> 4, g = t & 15;
    int lane = t & 63;
    // group fold (chunks g*16 .. g*16+15)
    float Pg = 1.0f, Hg = 0.0f;
    #pragma unroll
    for (int j = 0; j < 16; j++) {
        int c = g*16 + j;
        float pc = Ps[c][si2], hc = Hs[c][si2];
        Hg = hc + pc*Hg;
        Pg = pc*Pg;
    }
    // inclusive Hillis-Steele over 16 groups (16-lane windows = fixed series)
    #pragma unroll
    for (int off = 1; off < 16; off <<= 1) {
        float Pp = __shfl(Pg, lane - off);
        float Hp = __shfl(Hg, lane - off);
        if (g >= off) { Hg = Hg + Pg*Hp; Pg = Pg*Pp; }
    }
    float carry = __shfl(Hg, lane - 1);
    if (g == 0) carry = 0.0f;
    // apply: write exclusive prefix per chunk into Hs (own entries only)
    float h = carry;
    #pragma unroll
    for (int j = 0; j < 16; j++) {
        int c = g*16 + j;
        float pc = Ps[c][si2], hc = Hs[c][si2];
        Hs[c][si2] = h;
        h = hc + pc*h;
    }
    __syncthreads();
    #pragma unroll
    for (int it = 0; it < 16; it++) {
        int c = it*16 + cb;
        Hst[(size_t)c*4096 + sg*16 + si] = Hs[c][si];
    }
}

__global__ __launch_bounds__(256) void scan3_k(const float* __restrict__ delta,
                        const hbf* __restrict__ xc, const float* __restrict__ proj,
                        const float* __restrict__ Alog, const float* __restrict__ Hst,
                        const float* __restrict__ Dp, const hbf* __restrict__ xzb,
                        hbf* __restrict__ Y)
{
    int c = blockIdx.x >> 1;
    int d = ((blockIdx.x & 1) << 8) + threadIdx.x;
    float Ac[DSc], h[DSc];
    #pragma unroll
    for (int s2 = 0; s2 < DSc; s2++) {
        Ac[s2] = -__expf(Alog[d*DSc+s2]);
        h[s2]  = Hst[(size_t)(c*DSc+s2)*DIc + d];
    }
    float dpv = Dp[d];
    int l0 = c * CLc;
    for (int l = l0; l < l0 + CLc; l++) {
        float dl = delta[(size_t)l*DIc + d];
        float xv = __bfloat162float(xc[(size_t)l*DIc + d]);
        float dx = dl * xv;
        const float* pb = proj + l*32 + 16;
        float y = 0.0f;
        #pragma unroll
        for (int s2 = 0; s2 < DSc; s2++) {
            float a = __expf(dl * Ac[s2]);
            h[s2] = a*h[s2] + dx*pb[s2];
            y += h[s2] * pb[8+s2];
        }
        float z = __bfloat162float(xzb[(size_t)l*1024 + 512 + d]);
        float sz = z / (1.0f + __expf(-z));
        Y[(size_t)l*DIc + d] = __float2bfloat16((y + dpv*xv) * sz);
    }
}

// ---------------- split-K(8) MFMA flash attention, TQ=128, constant-shift softmax ----------------
__global__ __launch_bounds__(256) void attn_part_k(const unsigned short* __restrict__ QK,
                       const unsigned short* __restrict__ Vt,
                       OPtrs op, float* __restrict__ lsum)
{
    __shared__ __align__(16) unsigned short QPs[128][72];
    __shared__ __align__(16) unsigned short Ks[64][72];
    __shared__ __align__(16) unsigned short Vs[64][72];
    int t = threadIdx.x, lane = t & 63, w = t >> 6;
    int h = blockIdx.y, q0 = blockIdx.x * 128, skc = blockIdx.z;
    int fm = lane & 15, fq = lane >> 4;

    {
        int qr = t >> 1, qc = (t & 1) * 32;
        const unsigned short* src = &QK[(size_t)(q0+qr)*512 + h*64 + qc];
        *(uint4*)&QPs[qr][qc]      = *(const uint4*)&src[0];
        *(uint4*)&QPs[qr][qc + 8]  = *(const uint4*)&src[8];
        *(uint4*)&QPs[qr][qc + 16] = *(const uint4*)&src[16];
        *(uint4*)&QPs[qr][qc + 24] = *(const uint4*)&src[24];
    }
    __syncthreads();
    bf16x8 qa[2][2];
    #pragma unroll
    for (int rf = 0; rf < 2; rf++)
        #pragma unroll
        for (int ks = 0; ks < 2; ks++)
            qa[rf][ks] = *(bf16x8*)&QPs[w*32 + rf*16 + fm][ks*32 + fq*8];

    bf16x8 ones;
    #pragma unroll
    for (int j = 0; j < 8; j++) ones[j] = (short)0x3F80;

    f32x4 o[2][4] = {};
    f32x4 ol[2] = {};
    int sr = t >> 2, sk = (t & 3) * 16;
    const unsigned short* Kb = QK + 256;
    int kt = skc * 512;
    uint4 ka  = *(const uint4*)&Kb[(size_t)(kt+sr)*512 + h*64 + sk];
    uint4 kb2 = *(const uint4*)&Kb[(size_t)(kt+sr)*512 + h*64 + sk + 8];
    uint4 va  = *(const uint4*)&Vt[(size_t)(h*64+sr)*NL + kt + sk];
    uint4 vb2 = *(const uint4*)&Vt[(size_t)(h*64+sr)*NL + kt + sk + 8];

    for (int it = 0; it < 8; it++) {
        __syncthreads();
        *(uint4*)&Ks[sr][sk] = ka;  *(uint4*)&Ks[sr][sk+8] = kb2;
        *(uint4*)&Vs[sr][sk] = va;  *(uint4*)&Vs[sr][sk+8] = vb2;
        __syncthreads();
        if (it < 7) {
            int kn = kt + 64;
            ka  = *(const uint4*)&Kb[(size_t)(kn+sr)*512 + h*64 + sk];
            kb2 = *(const uint4*)&Kb[(size_t)(kn+sr)*512 + h*64 + sk + 8];
            va  = *(const uint4*)&Vt[(size_t)(h*64+sr)*NL + kn + sk];
            vb2 = *(const uint4*)&Vt[(size_t)(h*64+sr)*NL + kn + sk + 8];
        }
        f32x4 s[2][4] = {};
        #pragma unroll
        for (int ks = 0; ks < 2; ks++) {
            #pragma unroll
            for (int nt = 0; nt < 4; nt++) {
                bf16x8 kb = *(bf16x8*)&Ks[nt*16 + fm][ks*32 + fq*8];
                s[0][nt] = __builtin_amdgcn_mfma_f32_16x16x32_bf16(qa[0][ks], kb, s[0][nt], 0, 0, 0);
                s[1][nt] = __builtin_amdgcn_mfma_f32_16x16x32_bf16(qa[1][ks], kb, s[1][nt], 0, 0, 0);
            }
        }
        #pragma unroll
        for (int rf = 0; rf < 2; rf++)
            #pragma unroll
            for (int nt = 0; nt < 4; nt++)
                #pragma unroll
                for (int i = 0; i < 4; i++) {
                    float p = __expf(s[rf][nt][i] - 4.0f);
                    *(hbf*)&QPs[w*32 + rf*16 + fq*4 + i][nt*16 + fm] = __float2bfloat16(p);
                }
        #pragma unroll
        for (int ks = 0; ks < 2; ks++) {
            bf16x8 pa0 = *(bf16x8*)&QPs[w*32 + fm][ks*32 + fq*8];
            bf16x8 pa1 = *(bf16x8*)&QPs[w*32 + 16 + fm][ks*32 + fq*8];
            #pragma unroll
            for (int nt = 0; nt < 4; nt++) {
                bf16x8 vb = *(bf16x8*)&Vs[nt*16 + fm][ks*32 + fq*8];
                o[0][nt] = __builtin_amdgcn_mfma_f32_16x16x32_bf16(pa0, vb, o[0][nt], 0, 0, 0);
                o[1][nt] = __builtin_amdgcn_mfma_f32_16x16x32_bf16(pa1, vb, o[1][nt], 0, 0, 0);
            }
            ol[0] = __builtin_amdgcn_mfma_f32_16x16x32_bf16(pa0, ones, ol[0], 0, 0, 0);
            ol[1] = __builtin_amdgcn_mfma_f32_16x16x32_bf16(pa1, ones, ol[1], 0, 0, 0);
        }
        kt += 64;
    }
    hbf* Op = op.p[skc];
    #pragma unroll
    for (int rf = 0; rf < 2; rf++)
        #pragma unroll
        for (int i = 0; i < 4; i++) {
            int row = w*32 + rf*16 + fq*4 + i;
            #pragma unroll
            for (int nt = 0; nt < 4; nt++)
                Op[(size_t)(q0 + row)*HH + h*64 + nt*16 + fm] = __float2bfloat16(o[rf][nt][i]);
        }
    if (fm == 0) {
        #pragma unroll
        for (int rf = 0; rf < 2; rf++)
            #pragma unroll
            for (int i = 0; i < 4; i++)
                lsum[(size_t)(skc*4 + h)*NL + q0 + w*32 + rf*16 + fq*4 + i] = ol[rf][i];
    }
}

// exact merge: O = sum_c Oc / sum_c lc
__global__ __launch_bounds__(256) void amerge_k(OPtrs op, const float* __restrict__ lsum,
                                                hbf* __restrict__ aob) {
    int row = blockIdx.x, t = threadIdx.x, h = t >> 6;
    float L = 0.0f, s = 0.0f;
    #pragma unroll
    for (int c = 0; c < 8; c++) {
        L += lsum[(size_t)(c*4 + h)*NL + row];
        s += __bfloat162float(op.p[c][(size_t)row*HH + t]);
    }
    aob[(size_t)row*HH + t] = __float2bfloat16(s / L);
}

// ---------------- layernorm + pooling into 128 partial pools ----------------
__global__ __launch_bounds__(256) void ln_k(const float* __restrict__ X,
                    const float* __restrict__ g, const float* __restrict__ b,
                    float* __restrict__ part) {
    __shared__ float red[4];
    int r = blockIdx.x, t = threadIdx.x;
    float v = X[(size_t)r*HH + t];
    float s = v;
    #pragma unroll
    for (int o = 32; o > 0; o >>= 1) s += __shfl_down(s, o);
    if ((t & 63) == 0) red[t >> 6] = s;
    __syncthreads();
    float mean = (red[0]+red[1]+red[2]+red[3]) * (1.0f/256.0f);
    float dfv = v - mean;
    float s2 = dfv*dfv;
    #pragma unroll
    for (int o = 32; o > 0; o >>= 1) s2 += __shfl_down(s2, o);
    __syncthreads();
    if ((t & 63) == 0) red[t >> 6] = s2;
    __syncthreads();
    float var = (red[0]+red[1]+red[2]+red[3]) * (1.0f/256.0f);
    float y = dfv * rsqrtf(var + 1e-5f) * g[t] + b[t];
    atomicAdd(&part[(size_t)(r & 127)*2048 + (r >> 9)*HH + t], y * (1.0f/512.0f));
}

__global__ void reduce_k(const float* __restrict__ part, float* __restrict__ pooled) {
    int i = blockIdx.x*256 + threadIdx.x;
    float s = 0.0f;
    #pragma unroll 8
    for (int p = 0; p < 128; p++) s += part[(size_t)p*2048 + i];
    pooled[i] = s;
}

// ---------------- heads: wave per output, transposed weights ----------------
__global__ __launch_bounds__(256) void heads_k(const float* __restrict__ pooled,
        const float* __restrict__ hwt,
        const float* cbh, const float* hb, const float* tb, const float* p1b,
        const float* p2b, const float* db, const float* sb, float* __restrict__ out)
{
    int idx = blockIdx.x*4 + (threadIdx.x >> 6);
    int lane = threadIdx.x & 63;
    if (idx >= NOUT) return;
    int b = idx / 1552, j = idx - b*1552;
    const float* bi; int col;
    if (j < 1)         { bi = cbh; col = j;        }
    else if (j < 5)    { bi = hb;  col = j - 1;    }
    else if (j < 8)    { bi = tb;  col = j - 5;    }
    else if (j < 520)  { bi = p1b; col = j - 8;    }
    else if (j < 1032) { bi = p2b; col = j - 520;  }
    else if (j < 1544) { bi = db;  col = j - 1032; }
    else               { bi = sb;  col = j - 1544; }
    const float* pl = pooled + b*HH;
    const float* wr = hwt + (size_t)j*256;
    float s = 0.0f;
    #pragma unroll
    for (int k = lane; k < 256; k += 64) s = fmaf(pl[k], wr[k], s);
    #pragma unroll
    for (int o = 32; o > 0; o >>= 1) s += __shfl_down(s, o);
    if (lane == 0) out[idx] = s + bi[col];
}

// ---------------- launcher ----------------
extern "C" void kernel_launch(void* const* d_in, const int* in_sizes, int n_in,
                              void* d_out, int out_size, void* d_ws, size_t ws_size,
                              hipStream_t stream)
{
    (void)in_sizes; (void)n_in; (void)out_size; (void)ws_size;
    const float* x      = (const float*)d_in[0];
    const int*   ei     = (const int*)  d_in[1];
    const float* W_init = (const float*)d_in[2];
    const float* b_init = (const float*)d_in[3];
    const float* g1W = (const float*)d_in[4];
    const float* g1b = (const float*)d_in[5];
    const float* g2W = (const float*)d_in[6];
    const float* g2b = (const float*)d_in[7];
    const float* inW = (const float*)d_in[8];
    const float* cW  = (const float*)d_in[9];
    const float* cb  = (const float*)d_in[10];
    const float* xpW = (const float*)d_in[11];
    const float* dtW = (const float*)d_in[12];
    const float* dtb = (const float*)d_in[13];
    const float* Alog= (const float*)d_in[14];
    const float* Dp  = (const float*)d_in[15];
    const float* outW= (const float*)d_in[16];
    const float* Wq  = (const float*)d_in[17];
    const float* bq  = (const float*)d_in[18];
    const float* Wk  = (const float*)d_in[19];
    const float* bk  = (const float*)d_in[20];
    const float* Wv  = (const float*)d_in[21];
    const float* bv  = (const float*)d_in[22];
    const float* Wo  = (const float*)d_in[23];
    const float* bo  = (const float*)d_in[24];
    const float* fusW= (const float*)d_in[25];
    const float* fusb= (const float*)d_in[26];
    const float* lng = (const float*)d_in[27];
    const float* lnb = (const float*)d_in[28];
    const float* cwp = (const float*)d_in[29];
    const float* cbp = (const float*)d_in[30];
    const float* hwp = (const float*)d_in[31];
    const float* hbp = (const float*)d_in[32];
    const float* twp = (const float*)d_in[33];
    const float* tbp = (const float*)d_in[34];
    const float* p1w = (const float*)d_in[35];
    const float* p1b = (const float*)d_in[36];
    const float* p2w = (const float*)d_in[37];
    const float* p2b = (const float*)d_in[38];
    const float* dwp = (const float*)d_in[39];
    const float* dbp = (const float*)d_in[40];
    const float* swp = (const float*)d_in[41];
    const float* sbp = (const float*)d_in[42];

    float* fw = (float*)d_ws;
    int* iw = (int*)(fw + O_INT);
    int* indeg = iw;
    int* row_start = iw + 4096;
    int* cursor = iw + 8193;
    int* csr = iw + 12289;
    float* dinv = fw + O_DINV;

    hbf* wt   = (hbf*)(fw + O_WT);
    hbf* xb   = (hbf*)(fw + O_XB);
    hbf* h0b  = (hbf*)(fw + O_H0B);
    hbf* h2b  = (hbf*)(fw + O_H2B);
    hbf* xcb  = (hbf*)(fw + O_XCB);
    hbf* dtab = (hbf*)(fw + O_DTAB);
    hbf* xzb  = (hbf*)(fw + O_XZB);
    hbf* yb   = (hbf*)(fw + O_Y);
    hbf* aob  = (hbf*)(fw + O_Y);
    hbf* catb = (hbf*)(fw + O_CATB);
    hbf* qkB  = (hbf*)(fw + O_QKB);
    hbf* vtB  = (hbf*)(fw + O_VTB);
    float* fused = fw + O_XC;
    float* b768 = fw + O_B768;
    float* part = fw + O_PART;
    float* hwt  = fw + O_HWT;

    float* scanP  = fw + O_MBUF;
    float* scanHl = fw + O_QK;
    float* scanHst= fw + O_HST;
    float* lsum   = fw + O_HST;          // Hst dead after scan3

    OPtrs op;
    op.p[0] = (hbf*)(fw + O_MBUF);
    op.p[1] = (hbf*)(fw + O_MBUF + 524288);
    op.p[2] = (hbf*)(fw + O_DELTA);
    op.p[3] = (hbf*)(fw + O_DELTA + 524288);
    op.p[4] = (hbf*)(fw + O_DELTA + 1048576);
    op.p[5] = (hbf*)(fw + O_DELTA + 1572864);
    op.p[6] = (hbf*)(fw + O_XZB);
    op.p[7] = (hbf*)(fw + O_XZB + 524288);

    hbf* WtInit  = wt + 0;
    hbf* WtG1    = wt + 8192;
    hbf* WtG2    = wt + 73728;
    hbf* WtXp    = wt + 139264;
    hbf* WtDt    = wt + 155648;
    hbf* WtOut   = wt + 172032;
    hbf* WtInQKV = wt + 303104;
    hbf* WtO     = wt + 761856;
    hbf* WtFus   = wt + 827392;

    WSrc wsrc;
    wsrc.p[0]=W_init; wsrc.p[1]=g1W; wsrc.p[2]=g2W; wsrc.p[3]=xpW; wsrc.p[4]=dtW;
    wsrc.p[5]=outW; wsrc.p[6]=inW; wsrc.p[7]=Wq; wsrc.p[8]=Wk; wsrc.p[9]=Wv;
    wsrc.p[10]=Wo; wsrc.p[11]=fusW;
    HSrc hsrc;
    hsrc.p[0]=cwp; hsrc.p[1]=hwp; hsrc.p[2]=twp; hsrc.p[3]=p1w;
    hsrc.p[4]=p2w; hsrc.p[5]=dwp; hsrc.p[6]=swp;
    prep_k<<<(PR_H+255)/256,256,0,stream>>>(wsrc, wt, x, xb, bq, bk, bv, b768,
                                            part, indeg, hsrc, hwt);

    // graph prep
    count_k<<<256,256,0,stream>>>(ei, indeg);
    prefix_k<<<1,1024,0,stream>>>(indeg, row_start, cursor, dinv);
    scatter_k<<<256,256,0,stream>>>(ei, cursor, csr);

    // h0 = relu(x @ W_init + b_init) -> bf16
    mg_k<1,1><<<dim3(64,4),512,0,stream>>>((const unsigned short*)xb, (const unsigned short*)WtInit,
        b_init, h0b, 256, nullptr, nullptr, nullptr, 0, NL, 32, 256);
    // gcn1
    mg_k<0,0><<<dim3(64,4),512,0,stream>>>((const unsigned short*)h0b, (const unsigned short*)WtG1,
        nullptr, fw+O_MBUF, 256, nullptr, nullptr, nullptr, 0, NL, 256, 256);
    gather_k<0><<<4096,256,0,stream>>>(fw+O_MBUF, csr, row_start, dinv, g1b, nullptr, h0b, nullptr);
    // gcn2 (fp32 h2 + bf16 h2b + catb cols 0..255)
    mg_k<0,0><<<dim3(64,4),512,0,stream>>>((const unsigned short*)h0b, (const unsigned short*)WtG2,
        nullptr, fw+O_MBUF, 256, nullptr, nullptr, nullptr, 0, NL, 256, 256);
    gather_k<1><<<4096,256,0,stream>>>(fw+O_MBUF, csr, row_start, dinv, g2b, fw+O_H2, h2b, catb);

    // fused in_proj + QKV (N=1792): xzb | qkB (Q scaled) | vtB (transposed)
    mg_k<0,5><<<dim3(64,28),512,0,stream>>>((const unsigned short*)h2b, (const unsigned short*)WtInQKV,
        b768, xzb, 1024, qkB, vtB, nullptr, 0, NL, 256, 1792);

    // mamba
    conv_k<<<8192,256,0,stream>>>(xzb, cW, cb, xcb);
    mg_k<0,4><<<dim3(64,1),512,0,stream>>>((const unsigned short*)xcb, (const unsigned short*)WtXp,
        nullptr, fw+O_PROJ, 32, dtab, nullptr, nullptr, 0, NL, 512, 32);
    mg_k<2,0><<<dim3(64,8),512,0,stream>>>((const unsigned short*)dtab, (const unsigned short*)WtDt,
        dtb, fw+O_DELTA, 512, nullptr, nullptr, nullptr, 0, NL, 32, 512);
    scan1_k<<<512,256,0,stream>>>(fw+O_DELTA, xcb, fw+O_PROJ, Alog, scanP, scanHl);
    scan2t_k<<<256,256,0,stream>>>(scanP, scanHl, scanHst);
    scan3_k<<<512,256,0,stream>>>(fw+O_DELTA, xcb, fw+O_PROJ, Alog, scanHst, Dp, xzb, yb);
    mg_k<0,1><<<dim3(64,4),512,0,stream>>>((const unsigned short*)yb, (const unsigned short*)WtOut,
        nullptr, catb + 256, 768, nullptr, nullptr, nullptr, 0, NL, 512, 256);

    // attention
    attn_part_k<<<dim3(32,4,8),256,0,stream>>>((const unsigned short*)qkB,
        (const unsigned short*)vtB, op, lsum);
    amerge_k<<<4096,256,0,stream>>>(op, lsum, aob);
    mg_k<0,1><<<dim3(64,4),512,0,stream>>>((const unsigned short*)aob, (const unsigned short*)WtO,
        bo, catb + 512, 768, nullptr, nullptr, nullptr, 0, NL, 256, 256);

    // fuse + residual + LN(+partial pool) + reduce + heads
    mg_k<1,0><<<dim3(64,4),512,0,stream>>>((const unsigned short*)catb, (const unsigned short*)WtFus,
        fusb, fused, 256, nullptr, nullptr, fw+O_H2, 256, NL, 768, 256);
    ln_k<<<4096,256,0,stream>>>(fused, lng, lnb, part);
    reduce_k<<<8,256,0,stream>>>(part, fw+O_POOL);
    heads_k<<<(NOUT+3)/4,256,0,stream>>>(fw+O_POOL, hwt, cbp,hbp,tbp,p1b,p2b,dbp,sbp,
                                         (float*)d_out);
}